// Round 1
// baseline (18721.635 us; speedup 1.0000x reference)
//
#include <hip/hip_runtime.h>
#include <hip/hip_bf16.h>

// ---------------- problem constants ----------------
#define B8 8
#define KNN 32

// ---------------- KNN ----------------
__global__ __launch_bounds__(256) void knn_kernel(const float* __restrict__ pcd,
                                                  int N, int M, int* __restrict__ idxout) {
  __shared__ float4 pts[1024];
  const int t = threadIdx.x;
  const int b = blockIdx.y;
  const int m = blockIdx.x * 256 + t;
  const float* base = pcd + (size_t)b * 4096 * 3;
  float qx = 0.f, qy = 0.f, qz = 0.f;
  if (m < M) { qx = base[m*3]; qy = base[m*3+1]; qz = base[m*3+2]; }
  const float ax = -2.f*qx, ay = -2.f*qy, az = -2.f*qz;
  float d[KNN]; int id[KNN];
#pragma unroll
  for (int j = 0; j < KNN; ++j) { d[j] = 3.4e38f; id[j] = 0; }
  for (int n0 = 0; n0 < N; n0 += 1024) {
    __syncthreads();
    for (int i = t; i < 1024; i += 256) {
      const float* p = base + (size_t)(n0 + i) * 3;
      float x = p[0], y = p[1], z = p[2];
      pts[i] = make_float4(x, y, z, x*x + y*y + z*z);
    }
    __syncthreads();
    for (int i = 0; i < 1024; ++i) {
      float4 p = pts[i];
      float r = fmaf(ax, p.x, fmaf(ay, p.y, fmaf(az, p.z, p.w)));
      if (r < d[KNN-1]) {
        int ni = n0 + i;
#pragma unroll
        for (int j = KNN-1; j > 0; --j) {
          bool sh  = d[j-1] > r;
          bool ins = (!sh) && (d[j] > r);
          float dn = sh ? d[j-1] : (ins ? r : d[j]);
          int   in_= sh ? id[j-1] : (ins ? ni : id[j]);
          d[j] = dn; id[j] = in_;
        }
        if (d[0] > r) { id[0] = ni; d[0] = r; }
      }
    }
  }
  if (m < M) {
    int* o = idxout + ((size_t)b * M + m) * KNN;
#pragma unroll
    for (int j = 0; j < KNN; ++j) o[j] = id[j];
  }
}

// ---------------- weight transform: WA = Wa[:, :C2], WB = Wa[:, C2:] - Wa[:, :C2] ----------------
__global__ void prep_w(const float* __restrict__ W, float* __restrict__ WA, float* __restrict__ WB,
                       int cm, int c2, int c2p) {
  int i = blockIdx.x * 256 + threadIdx.x;
  if (i < cm * c2) {
    int o = i / c2, c = i - o * c2;
    float w1 = W[o * 2 * c2 + c];
    float w2 = W[o * 2 * c2 + c2 + c];
    WA[o * c2p + c] = w1;
    WB[o * c2p + c] = w2 - w1;
  }
}

__global__ void zero_red(float* __restrict__ red) {
  int i = blockIdx.x * 256 + threadIdx.x;
  if (i < 8192) red[i] = 0.f;
}

// ---------------- fused EdgeConv (3 modes) ----------------
// MODE 0: conv_a -> stats1 atomics
// MODE 1: conv_a -> bn1/relu -> conv_b -> stats2 atomics
// MODE 2: conv_a -> bn1/relu -> conv_b -> bn2/relu -> max_k -> fout
template<int C2, int CM, int MODE>
__global__ __launch_bounds__(256) void conv_fused(
    const float* __restrict__ f, int fstride, size_t fbstride,
    const int* __restrict__ idx,
    const float* __restrict__ WA, const float* __restrict__ WB, const float* __restrict__ ba,
    const float* __restrict__ Wb, const float* __restrict__ bb,
    const float* __restrict__ sc1, const float* __restrict__ sh1,
    const float* __restrict__ sc2, const float* __restrict__ sh2,
    float* red_s, float* red_q,
    float* __restrict__ fout, int fostride, size_t fobstride, int M) {
  constexpr int C2P = (C2 + 3) & ~3;
  __shared__ float fm[C2];
  __shared__ int   ji[KNN];
  __shared__ float fk[KNN * C2];
  __shared__ float tb[CM];
  __shared__ float h1n[CM * KNN];

  const int t = threadIdx.x;
  const int m = blockIdx.x, b = blockIdx.y;
  const float* fb = f + (size_t)b * fbstride;

  if (t < KNN) ji[t] = idx[((size_t)b * M + m) * KNN + t];
  for (int i = t; i < C2; i += 256) fm[i] = fb[(size_t)m * fstride + i];
  __syncthreads();

  for (int i = t; i < KNN * C2; i += 256) {
    int kk = i / C2, c = i - kk * C2;
    fk[i] = fb[(size_t)ji[kk] * fstride + c];
  }
  if (t < CM) {
    float a = ba[t];
    const float* wrow = WB + t * C2P;
#pragma unroll 4
    for (int c = 0; c < C2; ++c) a = fmaf(fm[c], wrow[c], a);
    tb[t] = a;
  }
  __syncthreads();

  const int k = t & 31, og = t >> 5;
  constexpr int NOI = CM / 32;
  const float* fkr = fk + k * C2;

#pragma unroll
  for (int oi = 0; oi < NOI; ++oi) {
    const int o0 = og * (CM / 8) + oi * 4;
    float aa[4] = { tb[o0], tb[o0+1], tb[o0+2], tb[o0+3] };
    const float* w0 = WA + (size_t)o0 * C2P;
#pragma unroll 4
    for (int c = 0; c < C2; ++c) {
      float v = fkr[c];
      aa[0] = fmaf(v, w0[c],        aa[0]);
      aa[1] = fmaf(v, w0[C2P + c],  aa[1]);
      aa[2] = fmaf(v, w0[2*C2P + c],aa[2]);
      aa[3] = fmaf(v, w0[3*C2P + c],aa[3]);
    }
    if (MODE == 0) {
#pragma unroll
      for (int j = 0; j < 4; ++j) {
        float s = aa[j], q = aa[j] * aa[j];
#pragma unroll
        for (int off = 1; off < 32; off <<= 1) { s += __shfl_xor(s, off); q += __shfl_xor(q, off); }
        if (k == 0) {
          int sh = (m & 15) * 256;
          atomicAdd(&red_s[sh + o0 + j], s);
          atomicAdd(&red_q[sh + o0 + j], q);
        }
      }
    } else {
#pragma unroll
      for (int j = 0; j < 4; ++j) {
        float sc = sc1[o0 + j], sf = sh1[o0 + j];
        h1n[(o0 + j) * KNN + k] = fmaxf(0.f, fmaf(aa[j], sc, sf));
      }
    }
  }
  if (MODE == 0) return;

  __syncthreads();

#pragma unroll
  for (int oi = 0; oi < NOI; ++oi) {
    const int o0 = og * (CM / 8) + oi * 4;
    float a[4] = { bb[o0], bb[o0+1], bb[o0+2], bb[o0+3] };
    const float* wr = Wb + (size_t)o0 * CM;
#pragma unroll 4
    for (int c = 0; c < CM; ++c) {
      float v = h1n[c * KNN + k];
      a[0] = fmaf(v, wr[c],          a[0]);
      a[1] = fmaf(v, wr[CM + c],     a[1]);
      a[2] = fmaf(v, wr[2*CM + c],   a[2]);
      a[3] = fmaf(v, wr[3*CM + c],   a[3]);
    }
    if (MODE == 1) {
#pragma unroll
      for (int j = 0; j < 4; ++j) {
        float s = a[j], q = a[j] * a[j];
#pragma unroll
        for (int off = 1; off < 32; off <<= 1) { s += __shfl_xor(s, off); q += __shfl_xor(q, off); }
        if (k == 0) {
          int sh = (m & 15) * 256;
          atomicAdd(&red_s[sh + o0 + j], s);
          atomicAdd(&red_q[sh + o0 + j], q);
        }
      }
    } else {
#pragma unroll
      for (int j = 0; j < 4; ++j) {
        float z = fmaxf(0.f, fmaf(a[j], sc2[o0 + j], sh2[o0 + j]));
#pragma unroll
        for (int off = 1; off < 32; off <<= 1) z = fmaxf(z, __shfl_xor(z, off));
        if (k == 0) fout[(size_t)b * fobstride + (size_t)m * fostride + (o0 + j)] = z;
      }
    }
  }
}

// ---------------- BN finalize: scale/shift from accumulated stats; re-zero stats ----------------
__global__ void bn_finalize(float* __restrict__ red_s, float* __restrict__ red_q,
                            const float* __restrict__ g, const float* __restrict__ be,
                            float* __restrict__ sc, float* __restrict__ sh,
                            int cm, float invcnt) {
  int o = threadIdx.x;
  if (o < cm) {
    float s = 0.f, q = 0.f;
    for (int i = 0; i < 16; ++i) { s += red_s[i * 256 + o]; q += red_q[i * 256 + o]; }
    float mu  = s * invcnt;
    float var = fmaxf(q * invcnt - mu * mu, 0.f);
    float scv = g[o] * rsqrtf(var + 1e-5f);
    sc[o] = scv;
    sh[o] = fmaf(-mu, scv, be[o]);
  }
  __syncthreads();
  for (int i = threadIdx.x; i < 16 * 256; i += 256) { red_s[i] = 0.f; red_q[i] = 0.f; }
}

// ---------------- append xyz columns to feature buffer ----------------
__global__ void append_xyz(const float* __restrict__ pcd, float* __restrict__ fbuf,
                           int nrows, int stride, int coff) {
  int i = blockIdx.x * 256 + threadIdx.x;
  if (i < B8 * nrows) {
    int b = i / nrows, n = i - b * nrows;
    const float* p = pcd + ((size_t)b * 4096 + n) * 3;
    float* dd = fbuf + ((size_t)b * nrows + n) * stride + coff;
    dd[0] = p[0]; dd[1] = p[1]; dd[2] = p[2];
  }
}

// ---------------- final FC + feat transpose ----------------
__global__ __launch_bounds__(256) void fc_out(const float* __restrict__ f4,
                                              const float* __restrict__ fcW, const float* __restrict__ fcb,
                                              float* __restrict__ out1, float* __restrict__ out3) {
  __shared__ float tile[32 * 257];
  const int t = threadIdx.x, b = blockIdx.x, n0 = blockIdx.y * 32;
  for (int i = t; i < 32 * 256; i += 256) {
    int n = i >> 8, c = i & 255;
    tile[n * 257 + c] = f4[((size_t)b * 1024 + n0 + n) * 256 + c];
  }
  __syncthreads();
  const int n = t & 31, og = t >> 5;
#pragma unroll
  for (int ci = 0; ci < 32; ++ci) {
    int c = og * 32 + ci;
    out3[((size_t)b * 256 + c) * 1024 + n0 + n] = tile[n * 257 + c];
  }
#pragma unroll
  for (int oi = 0; oi < 16; ++oi) {
    int o = og * 16 + oi;
    float acc = fcb[o];
    const float* w = fcW + (size_t)o * 256;
#pragma unroll 4
    for (int c = 0; c < 256; ++c) acc = fmaf(tile[n * 257 + c], w[c], acc);
    out1[((size_t)b * 128 + o) * 1024 + n0 + n] = acc;
  }
}

__global__ void out_xyz_idx(const float* __restrict__ pcd, float* __restrict__ out0,
                            float* __restrict__ out2) {
  int i = blockIdx.x * 256 + threadIdx.x;
  if (i < B8 * 1024) {
    int b = i >> 10, n = i & 1023;
    const float* p = pcd + ((size_t)b * 4096 + n) * 3;
    float* o = out0 + (size_t)i * 3;
    o[0] = p[0]; o[1] = p[1]; o[2] = p[2];
    out2[i] = (float)n;
  }
}

// ---------------- host ----------------
extern "C" void kernel_launch(void* const* d_in, const int* in_sizes, int n_in,
                              void* d_out, int out_size, void* d_ws, size_t ws_size,
                              hipStream_t stream) {
  (void)in_sizes; (void)n_in; (void)out_size; (void)ws_size;
  const float* pcd = (const float*)d_in[0];
  const float* W1a = (const float*)d_in[1];  const float* b1a = (const float*)d_in[2];
  const float* g1a = (const float*)d_in[3];  const float* be1a= (const float*)d_in[4];
  const float* W1b = (const float*)d_in[5];  const float* b1b = (const float*)d_in[6];
  const float* g1b = (const float*)d_in[7];  const float* be1b= (const float*)d_in[8];
  const float* W2a = (const float*)d_in[9];  const float* b2a = (const float*)d_in[10];
  const float* g2a = (const float*)d_in[11]; const float* be2a= (const float*)d_in[12];
  const float* W2b = (const float*)d_in[13]; const float* b2b = (const float*)d_in[14];
  const float* g2b = (const float*)d_in[15]; const float* be2b= (const float*)d_in[16];
  const float* W3a = (const float*)d_in[17]; const float* b3a = (const float*)d_in[18];
  const float* g3a = (const float*)d_in[19]; const float* be3a= (const float*)d_in[20];
  const float* W3b = (const float*)d_in[21]; const float* b3b = (const float*)d_in[22];
  const float* g3b = (const float*)d_in[23]; const float* be3b= (const float*)d_in[24];
  const float* fcW = (const float*)d_in[25]; const float* fcb = (const float*)d_in[26];

  // workspace layout (floats)
  float* wsf = (float*)d_ws;
  const size_t SB2 = (size_t)8 * 4096 * 67;
  const size_t SB3 = (size_t)8 * 2048 * 131;
  const size_t SB4 = (size_t)8 * 1024 * 256;
  float* FB2 = wsf;
  float* FB3 = FB2 + SB2;
  float* FB4 = FB3 + SB3;
  float* WAb = FB4 + SB4;           // 256*132
  float* WBb = WAb + 256 * 132;     // 256*132
  float* RED = WBb + 256 * 132;     // 8192 (red_s, red_q)
  float* red_s = RED, *red_q = RED + 4096;
  float* SC1 = RED + 8192; float* SH1 = SC1 + 256;
  float* SC2 = SH1 + 256;  float* SH2 = SC2 + 256;
  int* IDX1 = (int*)(SH2 + 256);
  int* IDX2 = IDX1 + (size_t)8 * 4096 * 32;
  int* IDX3 = IDX2 + (size_t)8 * 2048 * 32;

  float* out0 = (float*)d_out;                 // xyz  8x1024x3
  float* out1 = out0 + 24576;                  // out_feat 8x128x1024
  float* out2 = out1 + 1048576;                // idx  8x1024
  float* out3 = out2 + 8192;                   // feat 8x256x1024

  zero_red<<<32, 256, 0, stream>>>(RED);

  // ---------------- Layer 1: C2=3, CM=64, M=4096, N=4096, f=pcd ----------------
  knn_kernel<<<dim3(16, 8), 256, 0, stream>>>(pcd, 4096, 4096, IDX1);
  prep_w<<<1, 256, 0, stream>>>(W1a, WAb, WBb, 64, 3, 4);
  {
    dim3 g(4096, 8);
    conv_fused<3,64,0><<<g,256,0,stream>>>(pcd,3,(size_t)12288,IDX1,WAb,WBb,b1a,W1b,b1b,
        SC1,SH1,SC2,SH2,red_s,red_q,FB2,67,(size_t)274432,4096);
    bn_finalize<<<1,256,0,stream>>>(red_s,red_q,g1a,be1a,SC1,SH1,64,1.f/1048576.f);
    conv_fused<3,64,1><<<g,256,0,stream>>>(pcd,3,(size_t)12288,IDX1,WAb,WBb,b1a,W1b,b1b,
        SC1,SH1,SC2,SH2,red_s,red_q,FB2,67,(size_t)274432,4096);
    bn_finalize<<<1,256,0,stream>>>(red_s,red_q,g1b,be1b,SC2,SH2,64,1.f/1048576.f);
    conv_fused<3,64,2><<<g,256,0,stream>>>(pcd,3,(size_t)12288,IDX1,WAb,WBb,b1a,W1b,b1b,
        SC1,SH1,SC2,SH2,red_s,red_q,FB2,67,(size_t)274432,4096);
  }
  append_xyz<<<128, 256, 0, stream>>>(pcd, FB2, 4096, 67, 64);

  // ---------------- Layer 2: C2=67, CM=128, M=2048, N=4096, f=FB2 ----------------
  knn_kernel<<<dim3(8, 8), 256, 0, stream>>>(pcd, 4096, 2048, IDX2);
  prep_w<<<34, 256, 0, stream>>>(W2a, WAb, WBb, 128, 67, 68);
  {
    dim3 g(2048, 8);
    conv_fused<67,128,0><<<g,256,0,stream>>>(FB2,67,(size_t)274432,IDX2,WAb,WBb,b2a,W2b,b2b,
        SC1,SH1,SC2,SH2,red_s,red_q,FB3,131,(size_t)268288,2048);
    bn_finalize<<<1,256,0,stream>>>(red_s,red_q,g2a,be2a,SC1,SH1,128,1.f/524288.f);
    conv_fused<67,128,1><<<g,256,0,stream>>>(FB2,67,(size_t)274432,IDX2,WAb,WBb,b2a,W2b,b2b,
        SC1,SH1,SC2,SH2,red_s,red_q,FB3,131,(size_t)268288,2048);
    bn_finalize<<<1,256,0,stream>>>(red_s,red_q,g2b,be2b,SC2,SH2,128,1.f/524288.f);
    conv_fused<67,128,2><<<g,256,0,stream>>>(FB2,67,(size_t)274432,IDX2,WAb,WBb,b2a,W2b,b2b,
        SC1,SH1,SC2,SH2,red_s,red_q,FB3,131,(size_t)268288,2048);
  }
  append_xyz<<<64, 256, 0, stream>>>(pcd, FB3, 2048, 131, 128);

  // ---------------- Layer 3: C2=131, CM=256, M=1024, N=2048, f=FB3 ----------------
  knn_kernel<<<dim3(4, 8), 256, 0, stream>>>(pcd, 2048, 1024, IDX3);
  prep_w<<<131, 256, 0, stream>>>(W3a, WAb, WBb, 256, 131, 132);
  {
    dim3 g(1024, 8);
    conv_fused<131,256,0><<<g,256,0,stream>>>(FB3,131,(size_t)268288,IDX3,WAb,WBb,b3a,W3b,b3b,
        SC1,SH1,SC2,SH2,red_s,red_q,FB4,256,(size_t)262144,1024);
    bn_finalize<<<1,256,0,stream>>>(red_s,red_q,g3a,be3a,SC1,SH1,256,1.f/262144.f);
    conv_fused<131,256,1><<<g,256,0,stream>>>(FB3,131,(size_t)268288,IDX3,WAb,WBb,b3a,W3b,b3b,
        SC1,SH1,SC2,SH2,red_s,red_q,FB4,256,(size_t)262144,1024);
    bn_finalize<<<1,256,0,stream>>>(red_s,red_q,g3b,be3b,SC2,SH2,256,1.f/262144.f);
    conv_fused<131,256,2><<<g,256,0,stream>>>(FB3,131,(size_t)268288,IDX3,WAb,WBb,b3a,W3b,b3b,
        SC1,SH1,SC2,SH2,red_s,red_q,FB4,256,(size_t)262144,1024);
  }

  // ---------------- outputs ----------------
  fc_out<<<dim3(8, 32), 256, 0, stream>>>(FB4, fcW, fcb, out1, out3);
  out_xyz_idx<<<32, 256, 0, stream>>>(pcd, out0, out2);
}

// Round 2
// 7275.465 us; speedup vs baseline: 2.5733x; 2.5733x over previous
//
#include <hip/hip_runtime.h>
#include <hip/hip_bf16.h>

#define B8 8
#define KNN 32
typedef unsigned short u16;
typedef unsigned int u32;

static __device__ __forceinline__ float bf2f(u16 u) {
  union { u32 i; float f; } v; v.i = ((u32)u) << 16; return v.f;
}
static __device__ __forceinline__ u16 f2bf(float f) {
  union { u32 i; float f; } v; v.f = f;
  u32 r = v.i + 0x7fff + ((v.i >> 16) & 1);
  return (u16)(r >> 16);
}

// ---------------- KNN (unchanged from round 1, verified) ----------------
__global__ __launch_bounds__(256) void knn_kernel(const float* __restrict__ pcd,
                                                  int N, int M, int* __restrict__ idxout) {
  __shared__ float4 pts[1024];
  const int t = threadIdx.x;
  const int b = blockIdx.y;
  const int m = blockIdx.x * 256 + t;
  const float* base = pcd + (size_t)b * 4096 * 3;
  float qx = 0.f, qy = 0.f, qz = 0.f;
  if (m < M) { qx = base[m*3]; qy = base[m*3+1]; qz = base[m*3+2]; }
  const float ax = -2.f*qx, ay = -2.f*qy, az = -2.f*qz;
  float d[KNN]; int id[KNN];
#pragma unroll
  for (int j = 0; j < KNN; ++j) { d[j] = 3.4e38f; id[j] = 0; }
  for (int n0 = 0; n0 < N; n0 += 1024) {
    __syncthreads();
    for (int i = t; i < 1024; i += 256) {
      const float* p = base + (size_t)(n0 + i) * 3;
      float x = p[0], y = p[1], z = p[2];
      pts[i] = make_float4(x, y, z, x*x + y*y + z*z);
    }
    __syncthreads();
    for (int i = 0; i < 1024; ++i) {
      float4 p = pts[i];
      float r = fmaf(ax, p.x, fmaf(ay, p.y, fmaf(az, p.z, p.w)));
      if (r < d[KNN-1]) {
        int ni = n0 + i;
#pragma unroll
        for (int j = KNN-1; j > 0; --j) {
          bool sh  = d[j-1] > r;
          bool ins = (!sh) && (d[j] > r);
          float dn = sh ? d[j-1] : (ins ? r : d[j]);
          int   in_= sh ? id[j-1] : (ins ? ni : id[j]);
          d[j] = dn; id[j] = in_;
        }
        if (d[0] > r) { id[0] = ni; d[0] = r; }
      }
    }
  }
  if (m < M) {
    int* o = idxout + ((size_t)b * M + m) * KNN;
#pragma unroll
    for (int j = 0; j < KNN; ++j) o[j] = id[j];
  }
}

// ---------------- weight prep: conv_a -> WAt/WBt c-major [KP][CM]; conv_b transpose ----------------
__global__ void prep_wa(const float* __restrict__ W, float* __restrict__ WAt, float* __restrict__ WBt,
                        int cm, int c2, int kp) {
  int i = blockIdx.x * 256 + threadIdx.x;
  if (i >= kp * cm) return;
  int c = i / cm, o = i - c * cm;
  float w1 = 0.f, w2 = 0.f;
  if (c < c2) { w1 = W[o * 2 * c2 + c]; w2 = W[o * 2 * c2 + c2 + c]; }
  WAt[c * cm + o] = w1;
  WBt[c * cm + o] = w2 - w1;
}
__global__ void prep_wb(const float* __restrict__ W, float* __restrict__ Wt, int cm) {
  int i = blockIdx.x * 256 + threadIdx.x;
  if (i >= cm * cm) return;
  int c = i / cm, o = i - c * cm;
  Wt[c * cm + o] = W[o * cm + c];
}

__global__ void zero_red(float* __restrict__ red) {
  int i = blockIdx.x * 256 + threadIdx.x;
  if (i < 8192) red[i] = 0.f;
}

// ---------------- conv_a GEMM ----------------
// MODE 0: T-pass. rows=M, A row = F[b][row], weights=WBt, init=bias, out=T fp32
// MODE 1: edge pass. rows=M*32, A row = F[b][idx[b][r/32][r%32]], weights=WAt, init=T, out=H bf16
template<int C2, int CM, int MODE>
__global__ __launch_bounds__(256) void conv_a_gemm(
    const float* __restrict__ F, size_t fbstride,
    const int* __restrict__ idx,
    const float* __restrict__ Wt,
    const float* __restrict__ bias,
    const float* __restrict__ T,
    float* __restrict__ Tout,
    u16* __restrict__ Hout,
    int M)
{
  constexpr int KP = (C2 + 3) & ~3;
  __shared__ float At[KP][68];
  __shared__ float Wts[KP][68];
  const int t = threadIdx.x;
  const int rt = blockIdx.x, ot = blockIdx.y, b = blockIdx.z;
  const int R0 = rt * 64;
  const int oc0 = ot * 64;
  const float* Fb = F + (size_t)b * fbstride;

  // stage W tile [KP][64] (c-major source => coalesced, conflict-free LDS writes)
  for (int i = t; i < KP * 64; i += 256) {
    int c = i >> 6, o = i & 63;
    Wts[c][o] = Wt[c * CM + oc0 + o];
  }
  // stage A rows, transposed into LDS
  for (int i = t; i < 64 * KP; i += 256) {
    int r = i / KP, c = i - r * KP;
    int gr = R0 + r;
    float v = 0.f;
    if (c < C2) {
      int src = (MODE == 0) ? gr : idx[((size_t)b * M + (gr >> 5)) * KNN + (gr & 31)];
      v = Fb[(size_t)src * C2 + c];
    }
    At[c][r] = v;
  }
  __syncthreads();

  const int cg = t & 15, rg = t >> 4;
  const int r0 = rg * 4, c0 = cg * 4;
  float acc[4][4];
  if (MODE == 0) {
#pragma unroll
    for (int j = 0; j < 4; ++j) {
      float bv = bias[oc0 + c0 + j];
#pragma unroll
      for (int i = 0; i < 4; ++i) acc[i][j] = bv;
    }
  } else {
#pragma unroll
    for (int i = 0; i < 4; ++i) {
      const float* tp = T + ((size_t)b * M + (size_t)((R0 + r0 + i) >> 5)) * CM + oc0 + c0;
      acc[i][0] = tp[0]; acc[i][1] = tp[1]; acc[i][2] = tp[2]; acc[i][3] = tp[3];
    }
  }

#pragma unroll 4
  for (int c = 0; c < KP; ++c) {
    const float4 a4 = *(const float4*)&At[c][r0];
    const float4 w4 = *(const float4*)&Wts[c][c0];
    acc[0][0]=fmaf(a4.x,w4.x,acc[0][0]); acc[0][1]=fmaf(a4.x,w4.y,acc[0][1]);
    acc[0][2]=fmaf(a4.x,w4.z,acc[0][2]); acc[0][3]=fmaf(a4.x,w4.w,acc[0][3]);
    acc[1][0]=fmaf(a4.y,w4.x,acc[1][0]); acc[1][1]=fmaf(a4.y,w4.y,acc[1][1]);
    acc[1][2]=fmaf(a4.y,w4.z,acc[1][2]); acc[1][3]=fmaf(a4.y,w4.w,acc[1][3]);
    acc[2][0]=fmaf(a4.z,w4.x,acc[2][0]); acc[2][1]=fmaf(a4.z,w4.y,acc[2][1]);
    acc[2][2]=fmaf(a4.z,w4.z,acc[2][2]); acc[2][3]=fmaf(a4.z,w4.w,acc[2][3]);
    acc[3][0]=fmaf(a4.w,w4.x,acc[3][0]); acc[3][1]=fmaf(a4.w,w4.y,acc[3][1]);
    acc[3][2]=fmaf(a4.w,w4.z,acc[3][2]); acc[3][3]=fmaf(a4.w,w4.w,acc[3][3]);
  }

  if (MODE == 0) {
    float* op = Tout + ((size_t)b * M + R0) * (size_t)CM + oc0;
#pragma unroll
    for (int i = 0; i < 4; ++i) {
      float* p = op + (size_t)(r0 + i) * CM + c0;
      p[0]=acc[i][0]; p[1]=acc[i][1]; p[2]=acc[i][2]; p[3]=acc[i][3];
    }
  } else {
    u16* hp = Hout + ((size_t)b * M * KNN + R0) * (size_t)CM + oc0;
#pragma unroll
    for (int i = 0; i < 4; ++i) {
      ushort4 s;
      s.x = f2bf(acc[i][0]); s.y = f2bf(acc[i][1]); s.z = f2bf(acc[i][2]); s.w = f2bf(acc[i][3]);
      *(ushort4*)(hp + (size_t)(r0 + i) * CM + c0) = s;
    }
  }
}

// ---------------- conv_b GEMM, in-place H: h2 = Wb . relu(bn1(h1)) ----------------
template<int CM, int TR, int TC>
__global__ __launch_bounds__(256) void conv_b_gemm(
    u16* __restrict__ H,
    const float* __restrict__ Wt,      // Wbt [CM][CM] c-major
    const float* __restrict__ bb,
    const float* __restrict__ sc1, const float* __restrict__ sh1,
    int Mrows)                          // rows per batch = M*32
{
  __shared__ float At[32][68];
  __shared__ float Wts[32][CM];
  __shared__ float scs[CM], shs[CM];
  const int t = threadIdx.x;
  const int rt = blockIdx.x, b = blockIdx.y;
  u16* Hb = H + ((size_t)b * Mrows + (size_t)rt * 64) * CM;

  for (int i = t; i < CM; i += 256) { scs[i] = sc1[i]; shs[i] = sh1[i]; }

  constexpr int NCG = CM / TC;
  const int cg = t % NCG, rg = t / NCG;
  float acc[TR][TC];
#pragma unroll
  for (int j = 0; j < TC; ++j) {
    float bv = bb[cg * TC + j];
#pragma unroll
    for (int i = 0; i < TR; ++i) acc[i][j] = bv;
  }
  __syncthreads();

  for (int c0 = 0; c0 < CM; c0 += 32) {
    // stage A chunk (64 rows x 32 cols), bn1+relu applied
    for (int i = t; i < 64 * 16; i += 256) {
      int r = i >> 4, cp = i & 15;
      u32 u = *(const u32*)(Hb + (size_t)r * CM + c0 + cp * 2);
      int c = c0 + cp * 2;
      At[cp*2][r]   = fmaxf(0.f, fmaf(bf2f((u16)u),        scs[c],   shs[c]));
      At[cp*2+1][r] = fmaxf(0.f, fmaf(bf2f((u16)(u >> 16)), scs[c+1], shs[c+1]));
    }
    // stage W chunk [32][CM] (contiguous c-major)
    {
      const float4* src = (const float4*)(Wt + (size_t)c0 * CM);
      float4* dst = (float4*)&Wts[0][0];
      for (int i = t; i < 32 * CM / 4; i += 256) dst[i] = src[i];
    }
    __syncthreads();

#pragma unroll 8
    for (int c = 0; c < 32; ++c) {
      float av[TR], wv[TC];
#pragma unroll
      for (int i = 0; i < TR; i += 4) {
        float4 a4 = *(const float4*)&At[c][rg * TR + i];
        av[i]=a4.x; av[i+1]=a4.y; av[i+2]=a4.z; av[i+3]=a4.w;
      }
#pragma unroll
      for (int j = 0; j < TC; j += 4) {
        float4 w4 = *(const float4*)&Wts[c][cg * TC + j];
        wv[j]=w4.x; wv[j+1]=w4.y; wv[j+2]=w4.z; wv[j+3]=w4.w;
      }
#pragma unroll
      for (int i = 0; i < TR; ++i)
#pragma unroll
        for (int j = 0; j < TC; ++j) acc[i][j] = fmaf(av[i], wv[j], acc[i][j]);
    }
    __syncthreads();
  }

  // epilogue: write h2 bf16 in-place (block owns all its rows' columns)
#pragma unroll
  for (int i = 0; i < TR; ++i) {
    u16* p = Hb + (size_t)(rg * TR + i) * CM + cg * TC;
#pragma unroll
    for (int j = 0; j < TC; j += 4) {
      ushort4 s;
      s.x = f2bf(acc[i][j]);   s.y = f2bf(acc[i][j+1]);
      s.z = f2bf(acc[i][j+2]); s.w = f2bf(acc[i][j+3]);
      *(ushort4*)(p + j) = s;
    }
  }
}

// ---------------- stats sweep over H ----------------
template<int CM>
__global__ __launch_bounds__(256) void stats_pass(const u16* __restrict__ H, size_t nrows,
                                                  float* __restrict__ red_s, float* __restrict__ red_q) {
  constexpr int CP = CM / 2;
  constexpr int RL = 256 / CP;
  const int t = threadIdx.x;
  const int cp = t % CP, rl = t / CP;
  float s0=0.f, q0=0.f, s1=0.f, q1=0.f;
  for (size_t r = (size_t)blockIdx.x * RL + rl; r < nrows; r += (size_t)gridDim.x * RL) {
    u32 u = *(const u32*)(H + r * CM + cp * 2);
    float v0 = bf2f((u16)u), v1 = bf2f((u16)(u >> 16));
    s0 += v0; q0 += v0 * v0; s1 += v1; q1 += v1 * v1;
  }
  __shared__ float red[256][4];
  red[t][0]=s0; red[t][1]=q0; red[t][2]=s1; red[t][3]=q1;
#pragma unroll
  for (int g = RL >> 1; g > 0; g >>= 1) {
    __syncthreads();
    if (rl < g) {
#pragma unroll
      for (int j = 0; j < 4; ++j) red[t][j] += red[t + g * CP][j];
    }
  }
  if (rl == 0) {
    int sh = (blockIdx.x & 15) * 256;
    atomicAdd(&red_s[sh + 2*cp],     red[t][0]);
    atomicAdd(&red_q[sh + 2*cp],     red[t][1]);
    atomicAdd(&red_s[sh + 2*cp + 1], red[t][2]);
    atomicAdd(&red_q[sh + 2*cp + 1], red[t][3]);
  }
}

// ---------------- BN finalize ----------------
__global__ void bn_finalize(float* __restrict__ red_s, float* __restrict__ red_q,
                            const float* __restrict__ g, const float* __restrict__ be,
                            float* __restrict__ sc, float* __restrict__ sh,
                            int cm, float invcnt) {
  int o = threadIdx.x;
  if (o < cm) {
    float s = 0.f, q = 0.f;
    for (int i = 0; i < 16; ++i) { s += red_s[i * 256 + o]; q += red_q[i * 256 + o]; }
    float mu  = s * invcnt;
    float var = fmaxf(q * invcnt - mu * mu, 0.f);
    float scv = g[o] * rsqrtf(var + 1e-5f);
    sc[o] = scv;
    sh[o] = fmaf(-mu, scv, be[o]);
  }
  __syncthreads();
  for (int i = threadIdx.x; i < 16 * 256; i += 256) { red_s[i] = 0.f; red_q[i] = 0.f; }
}

// ---------------- bn2 + relu + max over k ----------------
template<int CM>
__global__ __launch_bounds__(256) void bn_max_k(const u16* __restrict__ H,
    const float* __restrict__ sc2, const float* __restrict__ sh2,
    float* __restrict__ fout, int fostride, size_t fobstride, int M) {
  constexpr int PPB = 256 / CM;
  const int t = threadIdx.x;
  const int o = t % CM, pl = t / CM;
  const int b = blockIdx.y;
  const int m = blockIdx.x * PPB + pl;
  const u16* hp = H + ((size_t)b * M + m) * (size_t)KNN * CM + o;
  float sc = sc2[o], sh = sh2[o];
  float mx = 0.f;
#pragma unroll 8
  for (int k = 0; k < KNN; ++k) {
    float v = fmaf(bf2f(hp[(size_t)k * CM]), sc, sh);
    mx = fmaxf(mx, v);
  }
  fout[(size_t)b * fobstride + (size_t)m * fostride + o] = mx;
}

// ---------------- append xyz, FC, outputs (unchanged) ----------------
__global__ void append_xyz(const float* __restrict__ pcd, float* __restrict__ fbuf,
                           int nrows, int stride, int coff) {
  int i = blockIdx.x * 256 + threadIdx.x;
  if (i < B8 * nrows) {
    int b = i / nrows, n = i - b * nrows;
    const float* p = pcd + ((size_t)b * 4096 + n) * 3;
    float* dd = fbuf + ((size_t)b * nrows + n) * stride + coff;
    dd[0] = p[0]; dd[1] = p[1]; dd[2] = p[2];
  }
}

__global__ __launch_bounds__(256) void fc_out(const float* __restrict__ f4,
                                              const float* __restrict__ fcW, const float* __restrict__ fcb,
                                              float* __restrict__ out1, float* __restrict__ out3) {
  __shared__ float tile[32 * 257];
  const int t = threadIdx.x, b = blockIdx.x, n0 = blockIdx.y * 32;
  for (int i = t; i < 32 * 256; i += 256) {
    int n = i >> 8, c = i & 255;
    tile[n * 257 + c] = f4[((size_t)b * 1024 + n0 + n) * 256 + c];
  }
  __syncthreads();
  const int n = t & 31, og = t >> 5;
#pragma unroll
  for (int ci = 0; ci < 32; ++ci) {
    int c = og * 32 + ci;
    out3[((size_t)b * 256 + c) * 1024 + n0 + n] = tile[n * 257 + c];
  }
#pragma unroll
  for (int oi = 0; oi < 16; ++oi) {
    int o = og * 16 + oi;
    float acc = fcb[o];
    const float* w = fcW + (size_t)o * 256;
#pragma unroll 4
    for (int c = 0; c < 256; ++c) acc = fmaf(tile[n * 257 + c], w[c], acc);
    out1[((size_t)b * 128 + o) * 1024 + n0 + n] = acc;
  }
}

__global__ void out_xyz_idx(const float* __restrict__ pcd, float* __restrict__ out0,
                            float* __restrict__ out2) {
  int i = blockIdx.x * 256 + threadIdx.x;
  if (i < B8 * 1024) {
    int b = i >> 10, n = i & 1023;
    const float* p = pcd + ((size_t)b * 4096 + n) * 3;
    float* o = out0 + (size_t)i * 3;
    o[0] = p[0]; o[1] = p[1]; o[2] = p[2];
    out2[i] = (float)n;
  }
}

// ---------------- host ----------------
extern "C" void kernel_launch(void* const* d_in, const int* in_sizes, int n_in,
                              void* d_out, int out_size, void* d_ws, size_t ws_size,
                              hipStream_t stream) {
  (void)in_sizes; (void)n_in; (void)out_size; (void)ws_size;
  const float* pcd = (const float*)d_in[0];
  const float* W1a = (const float*)d_in[1];  const float* b1a = (const float*)d_in[2];
  const float* g1a = (const float*)d_in[3];  const float* be1a= (const float*)d_in[4];
  const float* W1b = (const float*)d_in[5];  const float* b1b = (const float*)d_in[6];
  const float* g1b = (const float*)d_in[7];  const float* be1b= (const float*)d_in[8];
  const float* W2a = (const float*)d_in[9];  const float* b2a = (const float*)d_in[10];
  const float* g2a = (const float*)d_in[11]; const float* be2a= (const float*)d_in[12];
  const float* W2b = (const float*)d_in[13]; const float* b2b = (const float*)d_in[14];
  const float* g2b = (const float*)d_in[15]; const float* be2b= (const float*)d_in[16];
  const float* W3a = (const float*)d_in[17]; const float* b3a = (const float*)d_in[18];
  const float* g3a = (const float*)d_in[19]; const float* be3a= (const float*)d_in[20];
  const float* W3b = (const float*)d_in[21]; const float* b3b = (const float*)d_in[22];
  const float* g3b = (const float*)d_in[23]; const float* be3b= (const float*)d_in[24];
  const float* fcW = (const float*)d_in[25]; const float* fcb = (const float*)d_in[26];

  float* wsf = (float*)d_ws;
  float* FB2 = wsf;                         // 8*4096*67 = 2,195,456
  float* FB3 = FB2 + 2195456;               // 8*2048*131 = 2,146,304
  float* FB4 = FB3 + 2146304;               // 8*1024*256 = 2,097,152
  float* WAT = FB4 + 2097152;               // 132*256 max = 33,792
  float* WBT = WAT + 33792;                 // 33,792
  float* WBB = WBT + 33792;                 // 256*256 = 65,536
  float* TBUF= WBB + 65536;                 // 8*4096*64 = 2,097,152 (same all layers)
  float* RED = TBUF + 2097152;              // 8,192
  float* red_s = RED, *red_q = RED + 4096;
  float* SC1 = RED + 8192;  float* SH1 = SC1 + 256;
  float* SC2 = SH1 + 256;   float* SH2 = SC2 + 256;
  int* IDX1 = (int*)(SH2 + 256);            // 8*4096*32
  int* IDX2 = IDX1 + (size_t)8 * 4096 * 32; // 8*2048*32
  int* IDX3 = IDX2 + (size_t)8 * 2048 * 32; // 8*1024*32
  u16* H    = (u16*)(IDX3 + (size_t)8 * 1024 * 32); // 67,108,864 bf16 = 134 MB

  float* out0 = (float*)d_out;
  float* out1 = out0 + 24576;
  float* out2 = out1 + 1048576;
  float* out3 = out2 + 8192;

  zero_red<<<32, 256, 0, stream>>>(RED);

  // ================ Layer 1: C2=3 (KP=4), CM=64, M=4096, N=4096, F=pcd ================
  knn_kernel<<<dim3(16, 8), 256, 0, stream>>>(pcd, 4096, 4096, IDX1);
  prep_wa<<<1, 256, 0, stream>>>(W1a, WAT, WBT, 64, 3, 4);
  prep_wb<<<16, 256, 0, stream>>>(W1b, WBB, 64);
  conv_a_gemm<3,64,0><<<dim3(64,1,8),256,0,stream>>>(pcd,(size_t)12288,nullptr,WBT,b1a,nullptr,TBUF,nullptr,4096);
  conv_a_gemm<3,64,1><<<dim3(2048,1,8),256,0,stream>>>(pcd,(size_t)12288,IDX1,WAT,nullptr,TBUF,nullptr,H,4096);
  stats_pass<64><<<256,256,0,stream>>>(H,(size_t)8*4096*32,red_s,red_q);
  bn_finalize<<<1,256,0,stream>>>(red_s,red_q,g1a,be1a,SC1,SH1,64,1.f/1048576.f);
  conv_b_gemm<64,4,4><<<dim3(2048,8),256,0,stream>>>(H,WBB,b1b,SC1,SH1,4096*32);
  stats_pass<64><<<256,256,0,stream>>>(H,(size_t)8*4096*32,red_s,red_q);
  bn_finalize<<<1,256,0,stream>>>(red_s,red_q,g1b,be1b,SC2,SH2,64,1.f/1048576.f);
  bn_max_k<64><<<dim3(1024,8),256,0,stream>>>(H,SC2,SH2,FB2,67,(size_t)274432,4096);
  append_xyz<<<128, 256, 0, stream>>>(pcd, FB2, 4096, 67, 64);

  // ================ Layer 2: C2=67 (KP=68), CM=128, M=2048, N=4096, F=FB2 ================
  knn_kernel<<<dim3(8, 8), 256, 0, stream>>>(pcd, 4096, 2048, IDX2);
  prep_wa<<<34, 256, 0, stream>>>(W2a, WAT, WBT, 128, 67, 68);
  prep_wb<<<64, 256, 0, stream>>>(W2b, WBB, 128);
  conv_a_gemm<67,128,0><<<dim3(32,2,8),256,0,stream>>>(FB2,(size_t)274432,nullptr,WBT,b2a,nullptr,TBUF,nullptr,2048);
  conv_a_gemm<67,128,1><<<dim3(1024,2,8),256,0,stream>>>(FB2,(size_t)274432,IDX2,WAT,nullptr,TBUF,nullptr,H,2048);
  stats_pass<128><<<256,256,0,stream>>>(H,(size_t)8*2048*32,red_s,red_q);
  bn_finalize<<<1,256,0,stream>>>(red_s,red_q,g2a,be2a,SC1,SH1,128,1.f/524288.f);
  conv_b_gemm<128,8,4><<<dim3(1024,8),256,0,stream>>>(H,WBB,b2b,SC1,SH1,2048*32);
  stats_pass<128><<<256,256,0,stream>>>(H,(size_t)8*2048*32,red_s,red_q);
  bn_finalize<<<1,256,0,stream>>>(red_s,red_q,g2b,be2b,SC2,SH2,128,1.f/524288.f);
  bn_max_k<128><<<dim3(1024,8),256,0,stream>>>(H,SC2,SH2,FB3,131,(size_t)268288,2048);
  append_xyz<<<64, 256, 0, stream>>>(pcd, FB3, 2048, 131, 128);

  // ================ Layer 3: C2=131 (KP=132), CM=256, M=1024, N=2048, F=FB3 ================
  knn_kernel<<<dim3(4, 8), 256, 0, stream>>>(pcd, 2048, 1024, IDX3);
  prep_wa<<<132, 256, 0, stream>>>(W3a, WAT, WBT, 256, 131, 132);
  prep_wb<<<256, 256, 0, stream>>>(W3b, WBB, 256);
  conv_a_gemm<131,256,0><<<dim3(16,4,8),256,0,stream>>>(FB3,(size_t)268288,nullptr,WBT,b3a,nullptr,TBUF,nullptr,1024);
  conv_a_gemm<131,256,1><<<dim3(512,4,8),256,0,stream>>>(FB3,(size_t)268288,IDX3,WAT,nullptr,TBUF,nullptr,H,1024);
  stats_pass<256><<<256,256,0,stream>>>(H,(size_t)8*1024*32,red_s,red_q);
  bn_finalize<<<1,256,0,stream>>>(red_s,red_q,g3a,be3a,SC1,SH1,256,1.f/262144.f);
  conv_b_gemm<256,8,8><<<dim3(512,8),256,0,stream>>>(H,WBB,b3b,SC1,SH1,1024*32);
  stats_pass<256><<<256,256,0,stream>>>(H,(size_t)8*1024*32,red_s,red_q);
  bn_finalize<<<1,256,0,stream>>>(red_s,red_q,g3b,be3b,SC2,SH2,256,1.f/262144.f);
  bn_max_k<256><<<dim3(1024,8),256,0,stream>>>(H,SC2,SH2,FB4,256,(size_t)262144,1024);

  // ================ outputs ================
  fc_out<<<dim3(8, 32), 256, 0, stream>>>(FB4, fcW, fcb, out1, out3);
  out_xyz_idx<<<32, 256, 0, stream>>>(pcd, out0, out2);
}

// Round 3
// 2785.908 us; speedup vs baseline: 6.7201x; 2.6115x over previous
//
#include <hip/hip_runtime.h>
#include <hip/hip_bf16.h>

#define B8 8
#define KNN 32
typedef unsigned short u16;
typedef unsigned int u32;

static __device__ __forceinline__ float bf2f(u16 u) {
  union { u32 i; float f; } v; v.i = ((u32)u) << 16; return v.f;
}
static __device__ __forceinline__ u16 f2bf(float f) {
  union { u32 i; float f; } v; v.f = f;
  u32 r = v.i + 0x7fff + ((v.i >> 16) & 1);
  return (u16)(r >> 16);
}

// ---------------- KNN: one wave per query, wave-sorted top-32 ----------------
__global__ __launch_bounds__(256) void knn_kernel(const float* __restrict__ pcd,
                                                  int N, int M, int* __restrict__ idxout) {
  __shared__ float4 pts[1024];
  const int t = threadIdx.x;
  const int lane = t & 63, w = t >> 6;
  const int b = blockIdx.y;
  const int m = blockIdx.x * 4 + w;
  const float* base = pcd + (size_t)b * 4096 * 3;
  const float qx = base[m*3], qy = base[m*3+1], qz = base[m*3+2];
  const float ax = -2.f*qx, ay = -2.f*qy, az = -2.f*qz;

  float hd = 3.4e38f;   // held distance (ascending across lanes)
  int   hi_ = 0;        // held id
  float tau = 3.4e38f;  // 32nd best (lane 31)

  for (int n0 = 0; n0 < N; n0 += 1024) {
    __syncthreads();
    for (int i = t; i < 1024; i += 256) {
      const float* p = base + (size_t)(n0 + i) * 3;
      float x = p[0], y = p[1], z = p[2];
      pts[i] = make_float4(x, y, z, x*x + y*y + z*z);
    }
    __syncthreads();
    for (int c = 0; c < 1024; c += 64) {
      float4 p = pts[c + lane];
      float r = fmaf(ax, p.x, fmaf(ay, p.y, fmaf(az, p.z, p.w)));
      unsigned long long mask = __ballot(r < tau);
      while (mask) {
        int l = __ffsll((unsigned long long)mask) - 1;
        mask &= mask - 1;
        float rv = __shfl(r, l);
        if (rv < tau) {                       // wave-uniform recheck
          int pos = __popcll(__ballot(hd <= rv));
          float hs = __shfl_up(hd, 1);
          int   is = __shfl_up(hi_, 1);
          bool ins = (lane == pos), shf = (lane > pos);
          hd  = ins ? rv           : (shf ? hs : hd);
          hi_ = ins ? (n0 + c + l) : (shf ? is : hi_);
          tau = __shfl(hd, 31);
        }
      }
    }
  }
  if (lane < KNN) idxout[((size_t)b * M + m) * KNN + lane] = hi_;
}

// ---------------- weight prep ----------------
__global__ void prep_wa(const float* __restrict__ W, float* __restrict__ WAt, float* __restrict__ WBt,
                        int cm, int c2, int kp) {
  int i = blockIdx.x * 256 + threadIdx.x;
  if (i >= kp * cm) return;
  int c = i / cm, o = i - c * cm;
  float w1 = 0.f, w2 = 0.f;
  if (c < c2) { w1 = W[o * 2 * c2 + c]; w2 = W[o * 2 * c2 + c2 + c]; }
  WAt[c * cm + o] = w1;
  WBt[c * cm + o] = w2 - w1;
}
__global__ void prep_wb(const float* __restrict__ W, float* __restrict__ Wt, int cm) {
  int i = blockIdx.x * 256 + threadIdx.x;
  if (i >= cm * cm) return;
  int c = i / cm, o = i - c * cm;
  Wt[c * cm + o] = W[o * cm + c];
}

__global__ void zero_red(float* __restrict__ red) {
  int i = blockIdx.x * 256 + threadIdx.x;
  if (i < 8192) red[i] = 0.f;
}

// ---------------- conv_a GEMM (K-tiled, row-major At) ----------------
// MODE 0: T-pass. rows=M, src row = row, weights=WBt, init=bias, out=T fp32
// MODE 1: edge pass. rows=M*32, src row = idx[...], weights=WAt, init=T, out=H bf16
template<int C2, int CM, int MODE>
__global__ __launch_bounds__(256) void conv_a_gemm(
    const float* __restrict__ F, size_t fbstride,
    const int* __restrict__ idx,
    const float* __restrict__ Wt,
    const float* __restrict__ bias,
    const float* __restrict__ T,
    float* __restrict__ Tout,
    u16* __restrict__ Hout,
    int M)
{
  constexpr int KP = (C2 + 3) & ~3;
  constexpr int KC = (KP <= 68) ? KP : 44;   // 132 = 3*44
  __shared__ float At[64][KC];
  __shared__ float Wts[KC][64];
  __shared__ int ji[64];
  const int t = threadIdx.x;
  const int rt = blockIdx.x, ot = blockIdx.y, b = blockIdx.z;
  const int R0 = rt * 64, oc0 = ot * 64;
  const float* Fb = F + (size_t)b * fbstride;

  if (t < 64) {
    int gr = R0 + t;
    ji[t] = (MODE == 0) ? gr : idx[((size_t)b * M + (gr >> 5)) * KNN + (gr & 31)];
  }

  const int cg = t & 15, rg = t >> 4;
  const int r0 = rg * 4, c0 = cg * 4;
  float acc[4][4];
  if (MODE == 0) {
#pragma unroll
    for (int j = 0; j < 4; ++j) {
      float bv = bias[oc0 + c0 + j];
#pragma unroll
      for (int i = 0; i < 4; ++i) acc[i][j] = bv;
    }
  } else {
#pragma unroll
    for (int i = 0; i < 4; ++i) {
      const float* tp = T + ((size_t)b * M + (size_t)((R0 + r0 + i) >> 5)) * CM + oc0 + c0;
      acc[i][0] = tp[0]; acc[i][1] = tp[1]; acc[i][2] = tp[2]; acc[i][3] = tp[3];
    }
  }
  __syncthreads();

  for (int k0 = 0; k0 < KP; k0 += KC) {
    if (k0) __syncthreads();
    // stage W tile [KC][64]: coalesced global, conflict-free LDS
    for (int i = t; i < KC * 64; i += 256) {
      int c = i >> 6, o = i & 63;
      Wts[c][o] = Wt[(size_t)(k0 + c) * CM + oc0 + o];
    }
    // stage A tile [64][KC]: float4 coalesced global, b128 LDS writes
    if constexpr (C2 == 3) {
      for (int i = t; i < 64 * 4; i += 256) {
        int r = i >> 2, c = i & 3;
        At[r][c] = (c < 3) ? Fb[(size_t)ji[r] * 3 + c] : 0.f;
      }
    } else {
      constexpr int C4 = KC / 4;
      for (int i = t; i < 64 * C4; i += 256) {
        int r = i / C4, c4 = i - r * C4;
        *(float4*)&At[r][c4 * 4] = *(const float4*)&Fb[(size_t)ji[r] * KP + k0 + c4 * 4];
      }
    }
    __syncthreads();

#pragma unroll 4
    for (int k = 0; k < KC; ++k) {
      const float4 w4 = *(const float4*)&Wts[k][c0];
      float a0 = At[r0][k], a1 = At[r0+1][k], a2 = At[r0+2][k], a3 = At[r0+3][k];
      acc[0][0]=fmaf(a0,w4.x,acc[0][0]); acc[0][1]=fmaf(a0,w4.y,acc[0][1]);
      acc[0][2]=fmaf(a0,w4.z,acc[0][2]); acc[0][3]=fmaf(a0,w4.w,acc[0][3]);
      acc[1][0]=fmaf(a1,w4.x,acc[1][0]); acc[1][1]=fmaf(a1,w4.y,acc[1][1]);
      acc[1][2]=fmaf(a1,w4.z,acc[1][2]); acc[1][3]=fmaf(a1,w4.w,acc[1][3]);
      acc[2][0]=fmaf(a2,w4.x,acc[2][0]); acc[2][1]=fmaf(a2,w4.y,acc[2][1]);
      acc[2][2]=fmaf(a2,w4.z,acc[2][2]); acc[2][3]=fmaf(a2,w4.w,acc[2][3]);
      acc[3][0]=fmaf(a3,w4.x,acc[3][0]); acc[3][1]=fmaf(a3,w4.y,acc[3][1]);
      acc[3][2]=fmaf(a3,w4.z,acc[3][2]); acc[3][3]=fmaf(a3,w4.w,acc[3][3]);
    }
  }

  if (MODE == 0) {
    float* op = Tout + ((size_t)b * M + R0) * (size_t)CM + oc0;
#pragma unroll
    for (int i = 0; i < 4; ++i) {
      float* p = op + (size_t)(r0 + i) * CM + c0;
      p[0]=acc[i][0]; p[1]=acc[i][1]; p[2]=acc[i][2]; p[3]=acc[i][3];
    }
  } else {
    u16* hp = Hout + ((size_t)b * M * KNN + R0) * (size_t)CM + oc0;
#pragma unroll
    for (int i = 0; i < 4; ++i) {
      ushort4 s;
      s.x = f2bf(acc[i][0]); s.y = f2bf(acc[i][1]); s.z = f2bf(acc[i][2]); s.w = f2bf(acc[i][3]);
      *(ushort4*)(hp + (size_t)(r0 + i) * CM + c0) = s;
    }
  }
}

// ---------------- conv_b GEMM, in-place H: h2 = Wb . relu(bn1(h1)) ----------------
template<int CM, int TR, int TC>
__global__ __launch_bounds__(256) void conv_b_gemm(
    u16* __restrict__ H,
    const float* __restrict__ Wt,
    const float* __restrict__ bb,
    const float* __restrict__ sc1, const float* __restrict__ sh1,
    int Mrows)
{
  __shared__ float At[32][68];
  __shared__ float Wts[32][CM];
  __shared__ float scs[CM], shs[CM];
  const int t = threadIdx.x;
  const int rt = blockIdx.x, b = blockIdx.y;
  u16* Hb = H + ((size_t)b * Mrows + (size_t)rt * 64) * CM;

  for (int i = t; i < CM; i += 256) { scs[i] = sc1[i]; shs[i] = sh1[i]; }

  constexpr int NCG = CM / TC;
  const int cg = t % NCG, rg = t / NCG;
  float acc[TR][TC];
#pragma unroll
  for (int j = 0; j < TC; ++j) {
    float bv = bb[cg * TC + j];
#pragma unroll
    for (int i = 0; i < TR; ++i) acc[i][j] = bv;
  }
  __syncthreads();

  for (int c0 = 0; c0 < CM; c0 += 32) {
    for (int i = t; i < 64 * 16; i += 256) {
      int r = i >> 4, cp = i & 15;
      u32 u = *(const u32*)(Hb + (size_t)r * CM + c0 + cp * 2);
      int c = c0 + cp * 2;
      At[cp*2][r]   = fmaxf(0.f, fmaf(bf2f((u16)u),        scs[c],   shs[c]));
      At[cp*2+1][r] = fmaxf(0.f, fmaf(bf2f((u16)(u >> 16)), scs[c+1], shs[c+1]));
    }
    {
      const float4* src = (const float4*)(Wt + (size_t)c0 * CM);
      float4* dst = (float4*)&Wts[0][0];
      for (int i = t; i < 32 * CM / 4; i += 256) dst[i] = src[i];
    }
    __syncthreads();

#pragma unroll 8
    for (int c = 0; c < 32; ++c) {
      float av[TR], wv[TC];
#pragma unroll
      for (int i = 0; i < TR; i += 4) {
        float4 a4 = *(const float4*)&At[c][rg * TR + i];
        av[i]=a4.x; av[i+1]=a4.y; av[i+2]=a4.z; av[i+3]=a4.w;
      }
#pragma unroll
      for (int j = 0; j < TC; j += 4) {
        float4 w4 = *(const float4*)&Wts[c][cg * TC + j];
        wv[j]=w4.x; wv[j+1]=w4.y; wv[j+2]=w4.z; wv[j+3]=w4.w;
      }
#pragma unroll
      for (int i = 0; i < TR; ++i)
#pragma unroll
        for (int j = 0; j < TC; ++j) acc[i][j] = fmaf(av[i], wv[j], acc[i][j]);
    }
    __syncthreads();
  }

#pragma unroll
  for (int i = 0; i < TR; ++i) {
    u16* p = Hb + (size_t)(rg * TR + i) * CM + cg * TC;
#pragma unroll
    for (int j = 0; j < TC; j += 4) {
      ushort4 s;
      s.x = f2bf(acc[i][j]);   s.y = f2bf(acc[i][j+1]);
      s.z = f2bf(acc[i][j+2]); s.w = f2bf(acc[i][j+3]);
      *(ushort4*)(p + j) = s;
    }
  }
}

// ---------------- stats sweep over H ----------------
template<int CM>
__global__ __launch_bounds__(256) void stats_pass(const u16* __restrict__ H, size_t nrows,
                                                  float* __restrict__ red_s, float* __restrict__ red_q) {
  constexpr int CP = CM / 2;
  constexpr int RL = 256 / CP;
  const int t = threadIdx.x;
  const int cp = t % CP, rl = t / CP;
  float s0=0.f, q0=0.f, s1=0.f, q1=0.f;
  for (size_t r = (size_t)blockIdx.x * RL + rl; r < nrows; r += (size_t)gridDim.x * RL) {
    u32 u = *(const u32*)(H + r * CM + cp * 2);
    float v0 = bf2f((u16)u), v1 = bf2f((u16)(u >> 16));
    s0 += v0; q0 += v0 * v0; s1 += v1; q1 += v1 * v1;
  }
  __shared__ float red[256][4];
  red[t][0]=s0; red[t][1]=q0; red[t][2]=s1; red[t][3]=q1;
#pragma unroll
  for (int g = RL >> 1; g > 0; g >>= 1) {
    __syncthreads();
    if (rl < g) {
#pragma unroll
      for (int j = 0; j < 4; ++j) red[t][j] += red[t + g * CP][j];
    }
  }
  if (rl == 0) {
    int sh = (blockIdx.x & 15) * 256;
    atomicAdd(&red_s[sh + 2*cp],     red[t][0]);
    atomicAdd(&red_q[sh + 2*cp],     red[t][1]);
    atomicAdd(&red_s[sh + 2*cp + 1], red[t][2]);
    atomicAdd(&red_q[sh + 2*cp + 1], red[t][3]);
  }
}

// ---------------- BN finalize ----------------
__global__ void bn_finalize(float* __restrict__ red_s, float* __restrict__ red_q,
                            const float* __restrict__ g, const float* __restrict__ be,
                            float* __restrict__ sc, float* __restrict__ sh,
                            int cm, float invcnt) {
  int o = threadIdx.x;
  if (o < cm) {
    float s = 0.f, q = 0.f;
    for (int i = 0; i < 16; ++i) { s += red_s[i * 256 + o]; q += red_q[i * 256 + o]; }
    float mu  = s * invcnt;
    float var = fmaxf(q * invcnt - mu * mu, 0.f);
    float scv = g[o] * rsqrtf(var + 1e-5f);
    sc[o] = scv;
    sh[o] = fmaf(-mu, scv, be[o]);
  }
  __syncthreads();
  for (int i = threadIdx.x; i < 16 * 256; i += 256) { red_s[i] = 0.f; red_q[i] = 0.f; }
}

// ---------------- bn2 + relu + max over k ----------------
template<int CM>
__global__ __launch_bounds__(256) void bn_max_k(const u16* __restrict__ H,
    const float* __restrict__ sc2, const float* __restrict__ sh2,
    float* __restrict__ fout, int fostride, size_t fobstride, int M) {
  constexpr int PPB = 256 / CM;
  const int t = threadIdx.x;
  const int o = t % CM, pl = t / CM;
  const int b = blockIdx.y;
  const int m = blockIdx.x * PPB + pl;
  const u16* hp = H + ((size_t)b * M + m) * (size_t)KNN * CM + o;
  float sc = sc2[o], sh = sh2[o];
  float mx = 0.f;
#pragma unroll 8
  for (int k = 0; k < KNN; ++k) {
    float v = fmaf(bf2f(hp[(size_t)k * CM]), sc, sh);
    mx = fmaxf(mx, v);
  }
  fout[(size_t)b * fobstride + (size_t)m * fostride + o] = mx;
}

// ---------------- append xyz (+ zero pad col) ----------------
__global__ void append_xyz(const float* __restrict__ pcd, float* __restrict__ fbuf,
                           int nrows, int stride, int coff) {
  int i = blockIdx.x * 256 + threadIdx.x;
  if (i < B8 * nrows) {
    int b = i / nrows, n = i - b * nrows;
    const float* p = pcd + ((size_t)b * 4096 + n) * 3;
    float* dd = fbuf + ((size_t)b * nrows + n) * stride + coff;
    dd[0] = p[0]; dd[1] = p[1]; dd[2] = p[2]; dd[3] = 0.f;
  }
}

// ---------------- final FC + feat transpose ----------------
__global__ __launch_bounds__(256) void fc_out(const float* __restrict__ f4,
                                              const float* __restrict__ fcW, const float* __restrict__ fcb,
                                              float* __restrict__ out1, float* __restrict__ out3) {
  __shared__ float tile[32 * 257];
  const int t = threadIdx.x, b = blockIdx.x, n0 = blockIdx.y * 32;
  for (int i = t; i < 32 * 256; i += 256) {
    int n = i >> 8, c = i & 255;
    tile[n * 257 + c] = f4[((size_t)b * 1024 + n0 + n) * 256 + c];
  }
  __syncthreads();
  const int n = t & 31, og = t >> 5;
#pragma unroll
  for (int ci = 0; ci < 32; ++ci) {
    int c = og * 32 + ci;
    out3[((size_t)b * 256 + c) * 1024 + n0 + n] = tile[n * 257 + c];
  }
#pragma unroll
  for (int oi = 0; oi < 16; ++oi) {
    int o = og * 16 + oi;
    float acc = fcb[o];
    const float* w = fcW + (size_t)o * 256;
#pragma unroll 4
    for (int c = 0; c < 256; ++c) acc = fmaf(tile[n * 257 + c], w[c], acc);
    out1[((size_t)b * 128 + o) * 1024 + n0 + n] = acc;
  }
}

__global__ void out_xyz_idx(const float* __restrict__ pcd, float* __restrict__ out0,
                            float* __restrict__ out2) {
  int i = blockIdx.x * 256 + threadIdx.x;
  if (i < B8 * 1024) {
    int b = i >> 10, n = i & 1023;
    const float* p = pcd + ((size_t)b * 4096 + n) * 3;
    float* o = out0 + (size_t)i * 3;
    o[0] = p[0]; o[1] = p[1]; o[2] = p[2];
    out2[i] = (float)n;
  }
}

// ---------------- host ----------------
extern "C" void kernel_launch(void* const* d_in, const int* in_sizes, int n_in,
                              void* d_out, int out_size, void* d_ws, size_t ws_size,
                              hipStream_t stream) {
  (void)in_sizes; (void)n_in; (void)out_size; (void)ws_size;
  const float* pcd = (const float*)d_in[0];
  const float* W1a = (const float*)d_in[1];  const float* b1a = (const float*)d_in[2];
  const float* g1a = (const float*)d_in[3];  const float* be1a= (const float*)d_in[4];
  const float* W1b = (const float*)d_in[5];  const float* b1b = (const float*)d_in[6];
  const float* g1b = (const float*)d_in[7];  const float* be1b= (const float*)d_in[8];
  const float* W2a = (const float*)d_in[9];  const float* b2a = (const float*)d_in[10];
  const float* g2a = (const float*)d_in[11]; const float* be2a= (const float*)d_in[12];
  const float* W2b = (const float*)d_in[13]; const float* b2b = (const float*)d_in[14];
  const float* g2b = (const float*)d_in[15]; const float* be2b= (const float*)d_in[16];
  const float* W3a = (const float*)d_in[17]; const float* b3a = (const float*)d_in[18];
  const float* g3a = (const float*)d_in[19]; const float* be3a= (const float*)d_in[20];
  const float* W3b = (const float*)d_in[21]; const float* b3b = (const float*)d_in[22];
  const float* g3b = (const float*)d_in[23]; const float* be3b= (const float*)d_in[24];
  const float* fcW = (const float*)d_in[25]; const float* fcb = (const float*)d_in[26];

  float* wsf = (float*)d_ws;
  float* FB2 = wsf;                         // 8*4096*68 = 2,228,224 (stride 68, pad col 67)
  float* FB3 = FB2 + 2228224;               // 8*2048*132 = 2,162,688 (stride 132, pad col 131)
  float* FB4 = FB3 + 2162688;               // 8*1024*256 = 2,097,152
  float* WAT = FB4 + 2097152;               // 132*256 max
  float* WBT = WAT + 33792;
  float* WBB = WBT + 33792;                 // 256*256
  float* TBUF= WBB + 65536;                 // 8*4096*64 = 2,097,152 (reused all layers)
  float* RED = TBUF + 2097152;              // 8,192
  float* red_s = RED, *red_q = RED + 4096;
  float* SC1 = RED + 8192;  float* SH1 = SC1 + 256;
  float* SC2 = SH1 + 256;   float* SH2 = SC2 + 256;
  int* IDX1 = (int*)(SH2 + 256);
  int* IDX2 = IDX1 + (size_t)8 * 4096 * 32;
  int* IDX3 = IDX2 + (size_t)8 * 2048 * 32;
  u16* H    = (u16*)(IDX3 + (size_t)8 * 1024 * 32); // 67,108,864 bf16

  float* out0 = (float*)d_out;
  float* out1 = out0 + 24576;
  float* out2 = out1 + 1048576;
  float* out3 = out2 + 8192;

  zero_red<<<32, 256, 0, stream>>>(RED);

  // ================ Layer 1: C2=3 (KP=4), CM=64, M=4096, N=4096 ================
  knn_kernel<<<dim3(1024, 8), 256, 0, stream>>>(pcd, 4096, 4096, IDX1);
  prep_wa<<<1, 256, 0, stream>>>(W1a, WAT, WBT, 64, 3, 4);
  prep_wb<<<16, 256, 0, stream>>>(W1b, WBB, 64);
  conv_a_gemm<3,64,0><<<dim3(64,1,8),256,0,stream>>>(pcd,(size_t)12288,nullptr,WBT,b1a,nullptr,TBUF,nullptr,4096);
  conv_a_gemm<3,64,1><<<dim3(2048,1,8),256,0,stream>>>(pcd,(size_t)12288,IDX1,WAT,nullptr,TBUF,nullptr,H,4096);
  stats_pass<64><<<256,256,0,stream>>>(H,(size_t)8*4096*32,red_s,red_q);
  bn_finalize<<<1,256,0,stream>>>(red_s,red_q,g1a,be1a,SC1,SH1,64,1.f/1048576.f);
  conv_b_gemm<64,4,4><<<dim3(2048,8),256,0,stream>>>(H,WBB,b1b,SC1,SH1,4096*32);
  stats_pass<64><<<256,256,0,stream>>>(H,(size_t)8*4096*32,red_s,red_q);
  bn_finalize<<<1,256,0,stream>>>(red_s,red_q,g1b,be1b,SC2,SH2,64,1.f/1048576.f);
  bn_max_k<64><<<dim3(1024,8),256,0,stream>>>(H,SC2,SH2,FB2,68,(size_t)278528,4096);
  append_xyz<<<128, 256, 0, stream>>>(pcd, FB2, 4096, 68, 64);

  // ================ Layer 2: C2=67 (KP=68), CM=128, M=2048, N=4096 ================
  knn_kernel<<<dim3(512, 8), 256, 0, stream>>>(pcd, 4096, 2048, IDX2);
  prep_wa<<<34, 256, 0, stream>>>(W2a, WAT, WBT, 128, 67, 68);
  prep_wb<<<64, 256, 0, stream>>>(W2b, WBB, 128);
  conv_a_gemm<67,128,0><<<dim3(32,2,8),256,0,stream>>>(FB2,(size_t)278528,nullptr,WBT,b2a,nullptr,TBUF,nullptr,2048);
  conv_a_gemm<67,128,1><<<dim3(1024,2,8),256,0,stream>>>(FB2,(size_t)278528,IDX2,WAT,nullptr,TBUF,nullptr,H,2048);
  stats_pass<128><<<256,256,0,stream>>>(H,(size_t)8*2048*32,red_s,red_q);
  bn_finalize<<<1,256,0,stream>>>(red_s,red_q,g2a,be2a,SC1,SH1,128,1.f/524288.f);
  conv_b_gemm<128,8,4><<<dim3(1024,8),256,0,stream>>>(H,WBB,b2b,SC1,SH1,2048*32);
  stats_pass<128><<<256,256,0,stream>>>(H,(size_t)8*2048*32,red_s,red_q);
  bn_finalize<<<1,256,0,stream>>>(red_s,red_q,g2b,be2b,SC2,SH2,128,1.f/524288.f);
  bn_max_k<128><<<dim3(1024,8),256,0,stream>>>(H,SC2,SH2,FB3,132,(size_t)270336,2048);
  append_xyz<<<64, 256, 0, stream>>>(pcd, FB3, 2048, 132, 128);

  // ================ Layer 3: C2=131 (KP=132), CM=256, M=1024, N=2048 ================
  knn_kernel<<<dim3(256, 8), 256, 0, stream>>>(pcd, 2048, 1024, IDX3);
  prep_wa<<<132, 256, 0, stream>>>(W3a, WAT, WBT, 256, 131, 132);
  prep_wb<<<256, 256, 0, stream>>>(W3b, WBB, 256);
  conv_a_gemm<131,256,0><<<dim3(16,4,8),256,0,stream>>>(FB3,(size_t)270336,nullptr,WBT,b3a,nullptr,TBUF,nullptr,1024);
  conv_a_gemm<131,256,1><<<dim3(512,4,8),256,0,stream>>>(FB3,(size_t)270336,IDX3,WAT,nullptr,TBUF,nullptr,H,1024);
  stats_pass<256><<<256,256,0,stream>>>(H,(size_t)8*1024*32,red_s,red_q);
  bn_finalize<<<1,256,0,stream>>>(red_s,red_q,g3a,be3a,SC1,SH1,256,1.f/262144.f);
  conv_b_gemm<256,8,8><<<dim3(512,8),256,0,stream>>>(H,WBB,b3b,SC1,SH1,1024*32);
  stats_pass<256><<<256,256,0,stream>>>(H,(size_t)8*1024*32,red_s,red_q);
  bn_finalize<<<1,256,0,stream>>>(red_s,red_q,g3b,be3b,SC2,SH2,256,1.f/262144.f);
  bn_max_k<256><<<dim3(1024,8),256,0,stream>>>(H,SC2,SH2,FB4,256,(size_t)262144,1024);

  // ================ outputs ================
  fc_out<<<dim3(8, 32), 256, 0, stream>>>(FB4, fcW, fcb, out1, out3);
  out_xyz_idx<<<32, 256, 0, stream>>>(pcd, out0, out2);
}

// Round 4
// 2056.028 us; speedup vs baseline: 9.1057x; 1.3550x over previous
//
#include <hip/hip_runtime.h>
#include <hip/hip_bf16.h>

#define B8 8
#define KNN 32
typedef unsigned short u16;
typedef unsigned int u32;

typedef __attribute__((ext_vector_type(8))) _Float16 half8;
typedef __attribute__((ext_vector_type(4))) float f32x4;

static __device__ __forceinline__ u16 f2h_u(float f) {
  _Float16 h = (_Float16)f; u16 u; __builtin_memcpy(&u, &h, 2); return u;
}
static __device__ __forceinline__ float h2f_u(u16 u) {
  _Float16 h; __builtin_memcpy(&h, &u, 2); return (float)h;
}

// ---------------- KNN: one wave per query, wave-sorted top-32 ----------------
__global__ __launch_bounds__(256) void knn_kernel(const float* __restrict__ pcd,
                                                  int N, int M, int* __restrict__ idxout) {
  __shared__ float4 pts[1024];
  const int t = threadIdx.x;
  const int lane = t & 63, w = t >> 6;
  const int b = blockIdx.y;
  const int m = blockIdx.x * 4 + w;
  const float* base = pcd + (size_t)b * 4096 * 3;
  const float qx = base[m*3], qy = base[m*3+1], qz = base[m*3+2];
  const float ax = -2.f*qx, ay = -2.f*qy, az = -2.f*qz;

  float hd = 3.4e38f;
  int   hi_ = 0;
  float tau = 3.4e38f;

  for (int n0 = 0; n0 < N; n0 += 1024) {
    __syncthreads();
    for (int i = t; i < 1024; i += 256) {
      const float* p = base + (size_t)(n0 + i) * 3;
      float x = p[0], y = p[1], z = p[2];
      pts[i] = make_float4(x, y, z, x*x + y*y + z*z);
    }
    __syncthreads();
    for (int c = 0; c < 1024; c += 64) {
      float4 p = pts[c + lane];
      float r = fmaf(ax, p.x, fmaf(ay, p.y, fmaf(az, p.z, p.w)));
      unsigned long long mask = __ballot(r < tau);
      while (mask) {
        int l = __ffsll((unsigned long long)mask) - 1;
        mask &= mask - 1;
        float rv = __shfl(r, l);
        if (rv < tau) {
          int pos = __popcll(__ballot(hd <= rv));
          float hs = __shfl_up(hd, 1);
          int   is = __shfl_up(hi_, 1);
          bool ins = (lane == pos), shf = (lane > pos);
          hd  = ins ? rv           : (shf ? hs : hd);
          hi_ = ins ? (n0 + c + l) : (shf ? is : hi_);
          tau = __shfl(hd, 31);
        }
      }
    }
  }
  if (lane < KNN) idxout[((size_t)b * M + m) * KNN + lane] = hi_;
}

// ---------------- weight prep ----------------
// fp32 c-major WA/WB for L1 edge + all T-passes
__global__ void prep_wa(const float* __restrict__ W, float* __restrict__ WAt, float* __restrict__ WBt,
                        int cm, int c2, int kp) {
  int i = blockIdx.x * 256 + threadIdx.x;
  if (i >= kp * cm) return;
  int c = i / cm, o = i - c * cm;
  float w1 = 0.f, w2 = 0.f;
  if (c < c2) { w1 = W[o * 2 * c2 + c]; w2 = W[o * 2 * c2 + c2 + c]; }
  WAt[c * cm + o] = w1;
  WBt[c * cm + o] = w2 - w1;
}
// f16 [o][kpad] first-half weights (conv_a MFMA B operand)
__global__ void prep_wah(const float* __restrict__ W, u16* __restrict__ WH,
                         int cm, int c2, int kpad) {
  int i = blockIdx.x * 256 + threadIdx.x;
  if (i >= cm * kpad) return;
  int o = i / kpad, k = i - o * kpad;
  WH[i] = (k < c2) ? f2h_u(W[o * 2 * c2 + k]) : (u16)0;
}
// f16 copy of conv_b weights, original [o][c] layout
__global__ void prep_whalf(const float* __restrict__ W, u16* __restrict__ WH, int n) {
  int i = blockIdx.x * 256 + threadIdx.x;
  if (i < n) WH[i] = f2h_u(W[i]);
}

__global__ void zero_red(float* __restrict__ red) {
  int i = blockIdx.x * 256 + threadIdx.x;
  if (i < 8192) red[i] = 0.f;
}

// ---------------- conv_a VALU GEMM (L1 edge + all T-passes) ----------------
template<int C2, int CM, int MODE>
__global__ __launch_bounds__(256) void conv_a_gemm(
    const float* __restrict__ F, size_t fbstride,
    const int* __restrict__ idx,
    const float* __restrict__ Wt,
    const float* __restrict__ bias,
    const float* __restrict__ T,
    float* __restrict__ Tout,
    u16* __restrict__ Hout,
    int M)
{
  constexpr int KP = (C2 + 3) & ~3;
  constexpr int KC = (KP <= 68) ? KP : 44;
  __shared__ float At[64][KC];
  __shared__ float Wts[KC][64];
  __shared__ int ji[64];
  const int t = threadIdx.x;
  const int rt = blockIdx.x, ot = blockIdx.y, b = blockIdx.z;
  const int R0 = rt * 64, oc0 = ot * 64;
  const float* Fb = F + (size_t)b * fbstride;

  if (t < 64) {
    int gr = R0 + t;
    ji[t] = (MODE == 0) ? gr : idx[((size_t)b * M + (gr >> 5)) * KNN + (gr & 31)];
  }

  const int cg = t & 15, rg = t >> 4;
  const int r0 = rg * 4, c0 = cg * 4;
  float acc[4][4];
  if (MODE == 0) {
#pragma unroll
    for (int j = 0; j < 4; ++j) {
      float bv = bias[oc0 + c0 + j];
#pragma unroll
      for (int i = 0; i < 4; ++i) acc[i][j] = bv;
    }
  } else {
#pragma unroll
    for (int i = 0; i < 4; ++i) {
      const float* tp = T + ((size_t)b * M + (size_t)((R0 + r0 + i) >> 5)) * CM + oc0 + c0;
      acc[i][0] = tp[0]; acc[i][1] = tp[1]; acc[i][2] = tp[2]; acc[i][3] = tp[3];
    }
  }
  __syncthreads();

  for (int k0 = 0; k0 < KP; k0 += KC) {
    if (k0) __syncthreads();
    for (int i = t; i < KC * 64; i += 256) {
      int c = i >> 6, o = i & 63;
      Wts[c][o] = Wt[(size_t)(k0 + c) * CM + oc0 + o];
    }
    if constexpr (C2 == 3) {
      for (int i = t; i < 64 * 4; i += 256) {
        int r = i >> 2, c = i & 3;
        At[r][c] = (c < 3) ? Fb[(size_t)ji[r] * 3 + c] : 0.f;
      }
    } else {
      constexpr int C4 = KC / 4;
      for (int i = t; i < 64 * C4; i += 256) {
        int r = i / C4, c4 = i - r * C4;
        *(float4*)&At[r][c4 * 4] = *(const float4*)&Fb[(size_t)ji[r] * KP + k0 + c4 * 4];
      }
    }
    __syncthreads();

#pragma unroll 4
    for (int k = 0; k < KC; ++k) {
      const float4 w4 = *(const float4*)&Wts[k][c0];
      float a0 = At[r0][k], a1 = At[r0+1][k], a2 = At[r0+2][k], a3 = At[r0+3][k];
      acc[0][0]=fmaf(a0,w4.x,acc[0][0]); acc[0][1]=fmaf(a0,w4.y,acc[0][1]);
      acc[0][2]=fmaf(a0,w4.z,acc[0][2]); acc[0][3]=fmaf(a0,w4.w,acc[0][3]);
      acc[1][0]=fmaf(a1,w4.x,acc[1][0]); acc[1][1]=fmaf(a1,w4.y,acc[1][1]);
      acc[1][2]=fmaf(a1,w4.z,acc[1][2]); acc[1][3]=fmaf(a1,w4.w,acc[1][3]);
      acc[2][0]=fmaf(a2,w4.x,acc[2][0]); acc[2][1]=fmaf(a2,w4.y,acc[2][1]);
      acc[2][2]=fmaf(a2,w4.z,acc[2][2]); acc[2][3]=fmaf(a2,w4.w,acc[2][3]);
      acc[3][0]=fmaf(a3,w4.x,acc[3][0]); acc[3][1]=fmaf(a3,w4.y,acc[3][1]);
      acc[3][2]=fmaf(a3,w4.z,acc[3][2]); acc[3][3]=fmaf(a3,w4.w,acc[3][3]);
    }
  }

  if (MODE == 0) {
    float* op = Tout + ((size_t)b * M + R0) * (size_t)CM + oc0;
#pragma unroll
    for (int i = 0; i < 4; ++i) {
      float* p = op + (size_t)(r0 + i) * CM + c0;
      p[0]=acc[i][0]; p[1]=acc[i][1]; p[2]=acc[i][2]; p[3]=acc[i][3];
    }
  } else {
    u16* hp = Hout + ((size_t)b * M * KNN + R0) * (size_t)CM + oc0;
#pragma unroll
    for (int i = 0; i < 4; ++i) {
      ushort4 s;
      s.x = f2h_u(acc[i][0]); s.y = f2h_u(acc[i][1]); s.z = f2h_u(acc[i][2]); s.w = f2h_u(acc[i][3]);
      *(ushort4*)(hp + (size_t)(r0 + i) * CM + c0) = s;
    }
  }
}

// ---------------- conv_a MFMA (layers 2/3 edge pass) ----------------
// h1[row][o] = sum_k F[ji[row]][k] * WA[o][k] + T[m(row)][o]  -> H f16
template<int CM, int KPAD>
__global__ __launch_bounds__(256) void conv_a_mfma(
    const float* __restrict__ F, int fstride, size_t fbstride,
    const int* __restrict__ idx,
    const u16* __restrict__ Wh,     // [CM][KPAD] f16
    const float* __restrict__ T,    // [b][M][CM] fp32
    u16* __restrict__ Hout,
    int M)
{
  constexpr int FC = CM / 32;
  __shared__ u16 Alds[64][72];
  __shared__ u16 Wlds[CM][72];
  __shared__ int ji[64];
  const int t = threadIdx.x;
  const int lane = t & 63, w = t >> 6;
  const int wr = w >> 1, wc = w & 1;
  const int cl = lane & 15, rq = lane >> 4;
  const int rt = blockIdx.x, b = blockIdx.y;
  const int R0 = rt * 64;
  const float* Fb = F + (size_t)b * fbstride;

  if (t < 64) ji[t] = idx[((size_t)b * M + ((R0 + t) >> 5)) * KNN + ((R0 + t) & 31)];

  f32x4 acc[2][FC];
#pragma unroll
  for (int fr = 0; fr < 2; ++fr)
#pragma unroll
    for (int fc = 0; fc < FC; ++fc) {
      int col = wc * (CM/2) + fc * 16 + cl;
#pragma unroll
      for (int r = 0; r < 4; ++r) {
        int row = R0 + wr*32 + fr*16 + rq*4 + r;
        acc[fr][fc][r] = T[((size_t)b * M + (row >> 5)) * CM + col];
      }
    }
  __syncthreads();

  for (int k0 = 0; k0 < KPAD; k0 += 64) {
    if (k0) __syncthreads();
    // A: gather rows, fp32->f16
    for (int i = t; i < 64 * 16; i += 256) {
      int r = i >> 4, seg = i & 15;
      int k = k0 + seg * 4;
      ushort4 s = {0,0,0,0};
      if (k < fstride) {
        float4 v = *(const float4*)&Fb[(size_t)ji[r] * fstride + k];
        s.x = f2h_u(v.x); s.y = f2h_u(v.y); s.z = f2h_u(v.z); s.w = f2h_u(v.w);
      }
      *(ushort4*)&Alds[r][seg * 4] = s;
    }
    // W chunk
    for (int i = t; i < CM * 8; i += 256) {
      int o = i >> 3, seg = i & 7;
      *(float4*)&Wlds[o][seg * 8] = *(const float4*)&Wh[(size_t)o * KPAD + k0 + seg * 8];
    }
    __syncthreads();

#pragma unroll
    for (int kk = 0; kk < 2; ++kk) {
      half8 af[2], bf[FC];
#pragma unroll
      for (int fr = 0; fr < 2; ++fr)
        af[fr] = *(const half8*)&Alds[wr*32 + fr*16 + cl][kk*32 + rq*8];
#pragma unroll
      for (int fc = 0; fc < FC; ++fc)
        bf[fc] = *(const half8*)&Wlds[wc*(CM/2) + fc*16 + cl][kk*32 + rq*8];
#pragma unroll
      for (int fr = 0; fr < 2; ++fr)
#pragma unroll
        for (int fc = 0; fc < FC; ++fc)
          acc[fr][fc] = __builtin_amdgcn_mfma_f32_16x16x32_f16(af[fr], bf[fc], acc[fr][fc], 0, 0, 0);
    }
  }

  u16* Hb = Hout + ((size_t)b * (size_t)M * KNN + R0) * CM;
#pragma unroll
  for (int fr = 0; fr < 2; ++fr)
#pragma unroll
    for (int fc = 0; fc < FC; ++fc) {
      int col = wc*(CM/2) + fc*16 + cl;
#pragma unroll
      for (int r = 0; r < 4; ++r) {
        int row = wr*32 + fr*16 + rq*4 + r;
        Hb[(size_t)row * CM + col] = f2h_u(acc[fr][fc][r]);
      }
    }
}

// ---------------- conv_b MFMA, in-place H: h2 = Wb . relu(bn1(h1)) + bb ----------------
template<int CM>
__global__ __launch_bounds__(256) void conv_b_mfma(
    u16* __restrict__ H,
    const u16* __restrict__ Wh,     // [o][c] f16, original layout
    const float* __restrict__ bb,
    const float* __restrict__ sc1, const float* __restrict__ sh1,
    int Mrows)
{
  constexpr int FC = CM / 32;
  __shared__ u16 Alds[64][72];
  __shared__ u16 Wlds[CM][72];
  __shared__ float scs[CM], shs[CM];
  const int t = threadIdx.x;
  const int lane = t & 63, w = t >> 6;
  const int wr = w >> 1, wc = w & 1;
  const int cl = lane & 15, rq = lane >> 4;
  const int rt = blockIdx.x, b = blockIdx.y;
  u16* Hb = H + ((size_t)b * Mrows + (size_t)rt * 64) * CM;

  for (int i = t; i < CM; i += 256) { scs[i] = sc1[i]; shs[i] = sh1[i]; }

  f32x4 acc[2][FC];
#pragma unroll
  for (int fr = 0; fr < 2; ++fr)
#pragma unroll
    for (int fc = 0; fc < FC; ++fc) {
      float bv = bb[wc * (CM/2) + fc * 16 + cl];
#pragma unroll
      for (int r = 0; r < 4; ++r) acc[fr][fc][r] = bv;
    }
  __syncthreads();

  for (int k0 = 0; k0 < CM; k0 += 64) {
    if (k0) __syncthreads();
    // A: bn1 + relu + f16, from H
    for (int i = t; i < 64 * 8; i += 256) {
      int r = i >> 3, seg = i & 7;
      half8 hv = *(const half8*)&Hb[(size_t)r * CM + k0 + seg * 8];
      half8 ov;
#pragma unroll
      for (int j = 0; j < 8; ++j) {
        int c = k0 + seg * 8 + j;
        float v = fmaxf(0.f, fmaf((float)hv[j], scs[c], shs[c]));
        ov[j] = (_Float16)v;
      }
      *(half8*)&Alds[r][seg * 8] = ov;
    }
    // W chunk
    for (int i = t; i < CM * 8; i += 256) {
      int o = i >> 3, seg = i & 7;
      *(float4*)&Wlds[o][seg * 8] = *(const float4*)&Wh[(size_t)o * CM + k0 + seg * 8];
    }
    __syncthreads();

#pragma unroll
    for (int kk = 0; kk < 2; ++kk) {
      half8 af[2], bf[FC];
#pragma unroll
      for (int fr = 0; fr < 2; ++fr)
        af[fr] = *(const half8*)&Alds[wr*32 + fr*16 + cl][kk*32 + rq*8];
#pragma unroll
      for (int fc = 0; fc < FC; ++fc)
        bf[fc] = *(const half8*)&Wlds[wc*(CM/2) + fc*16 + cl][kk*32 + rq*8];
#pragma unroll
      for (int fr = 0; fr < 2; ++fr)
#pragma unroll
        for (int fc = 0; fc < FC; ++fc)
          acc[fr][fc] = __builtin_amdgcn_mfma_f32_16x16x32_f16(af[fr], bf[fc], acc[fr][fc], 0, 0, 0);
    }
  }

#pragma unroll
  for (int fr = 0; fr < 2; ++fr)
#pragma unroll
    for (int fc = 0; fc < FC; ++fc) {
      int col = wc*(CM/2) + fc*16 + cl;
#pragma unroll
      for (int r = 0; r < 4; ++r) {
        int row = wr*32 + fr*16 + rq*4 + r;
        Hb[(size_t)row * CM + col] = f2h_u(acc[fr][fc][r]);
      }
    }
}

// ---------------- stats sweep over H (f16) ----------------
template<int CM>
__global__ __launch_bounds__(256) void stats_pass(const u16* __restrict__ H, size_t nrows,
                                                  float* __restrict__ red_s, float* __restrict__ red_q) {
  constexpr int CP = CM / 2;
  constexpr int RL = 256 / CP;
  const int t = threadIdx.x;
  const int cp = t % CP, rl = t / CP;
  float s0=0.f, q0=0.f, s1=0.f, q1=0.f;
  for (size_t r = (size_t)blockIdx.x * RL + rl; r < nrows; r += (size_t)gridDim.x * RL) {
    u32 u = *(const u32*)(H + r * CM + cp * 2);
    float v0 = h2f_u((u16)u), v1 = h2f_u((u16)(u >> 16));
    s0 += v0; q0 += v0 * v0; s1 += v1; q1 += v1 * v1;
  }
  __shared__ float red[256][4];
  red[t][0]=s0; red[t][1]=q0; red[t][2]=s1; red[t][3]=q1;
#pragma unroll
  for (int g = RL >> 1; g > 0; g >>= 1) {
    __syncthreads();
    if (rl < g) {
#pragma unroll
      for (int j = 0; j < 4; ++j) red[t][j] += red[t + g * CP][j];
    }
  }
  if (rl == 0) {
    int sh = (blockIdx.x & 15) * 256;
    atomicAdd(&red_s[sh + 2*cp],     red[t][0]);
    atomicAdd(&red_q[sh + 2*cp],     red[t][1]);
    atomicAdd(&red_s[sh + 2*cp + 1], red[t][2]);
    atomicAdd(&red_q[sh + 2*cp + 1], red[t][3]);
  }
}

// ---------------- BN finalize ----------------
__global__ void bn_finalize(float* __restrict__ red_s, float* __restrict__ red_q,
                            const float* __restrict__ g, const float* __restrict__ be,
                            float* __restrict__ sc, float* __restrict__ sh,
                            int cm, float invcnt) {
  int o = threadIdx.x;
  if (o < cm) {
    float s = 0.f, q = 0.f;
    for (int i = 0; i < 16; ++i) { s += red_s[i * 256 + o]; q += red_q[i * 256 + o]; }
    float mu  = s * invcnt;
    float var = fmaxf(q * invcnt - mu * mu, 0.f);
    float scv = g[o] * rsqrtf(var + 1e-5f);
    sc[o] = scv;
    sh[o] = fmaf(-mu, scv, be[o]);
  }
  __syncthreads();
  for (int i = threadIdx.x; i < 16 * 256; i += 256) { red_s[i] = 0.f; red_q[i] = 0.f; }
}

// ---------------- bn2 + relu + max over k ----------------
template<int CM>
__global__ __launch_bounds__(256) void bn_max_k(const u16* __restrict__ H,
    const float* __restrict__ sc2, const float* __restrict__ sh2,
    float* __restrict__ fout, int fostride, size_t fobstride, int M) {
  constexpr int PPB = 256 / CM;
  const int t = threadIdx.x;
  const int o = t % CM, pl = t / CM;
  const int b = blockIdx.y;
  const int m = blockIdx.x * PPB + pl;
  const u16* hp = H + ((size_t)b * M + m) * (size_t)KNN * CM + o;
  float sc = sc2[o], sh = sh2[o];
  float mx = 0.f;
#pragma unroll 8
  for (int k = 0; k < KNN; ++k) {
    float v = fmaf(h2f_u(hp[(size_t)k * CM]), sc, sh);
    mx = fmaxf(mx, v);
  }
  fout[(size_t)b * fobstride + (size_t)m * fostride + o] = mx;
}

// ---------------- append xyz (+ zero pad col) ----------------
__global__ void append_xyz(const float* __restrict__ pcd, float* __restrict__ fbuf,
                           int nrows, int stride, int coff) {
  int i = blockIdx.x * 256 + threadIdx.x;
  if (i < B8 * nrows) {
    int b = i / nrows, n = i - b * nrows;
    const float* p = pcd + ((size_t)b * 4096 + n) * 3;
    float* dd = fbuf + ((size_t)b * nrows + n) * stride + coff;
    dd[0] = p[0]; dd[1] = p[1]; dd[2] = p[2]; dd[3] = 0.f;
  }
}

// ---------------- final FC + feat transpose ----------------
__global__ __launch_bounds__(256) void fc_out(const float* __restrict__ f4,
                                              const float* __restrict__ fcW, const float* __restrict__ fcb,
                                              float* __restrict__ out1, float* __restrict__ out3) {
  __shared__ float tile[32 * 257];
  const int t = threadIdx.x, b = blockIdx.x, n0 = blockIdx.y * 32;
  for (int i = t; i < 32 * 256; i += 256) {
    int n = i >> 8, c = i & 255;
    tile[n * 257 + c] = f4[((size_t)b * 1024 + n0 + n) * 256 + c];
  }
  __syncthreads();
  const int n = t & 31, og = t >> 5;
#pragma unroll
  for (int ci = 0; ci < 32; ++ci) {
    int c = og * 32 + ci;
    out3[((size_t)b * 256 + c) * 1024 + n0 + n] = tile[n * 257 + c];
  }
#pragma unroll
  for (int oi = 0; oi < 16; ++oi) {
    int o = og * 16 + oi;
    float acc = fcb[o];
    const float* w = fcW + (size_t)o * 256;
#pragma unroll 4
    for (int c = 0; c < 256; ++c) acc = fmaf(tile[n * 257 + c], w[c], acc);
    out1[((size_t)b * 128 + o) * 1024 + n0 + n] = acc;
  }
}

__global__ void out_xyz_idx(const float* __restrict__ pcd, float* __restrict__ out0,
                            float* __restrict__ out2) {
  int i = blockIdx.x * 256 + threadIdx.x;
  if (i < B8 * 1024) {
    int b = i >> 10, n = i & 1023;
    const float* p = pcd + ((size_t)b * 4096 + n) * 3;
    float* o = out0 + (size_t)i * 3;
    o[0] = p[0]; o[1] = p[1]; o[2] = p[2];
    out2[i] = (float)n;
  }
}

// ---------------- host ----------------
extern "C" void kernel_launch(void* const* d_in, const int* in_sizes, int n_in,
                              void* d_out, int out_size, void* d_ws, size_t ws_size,
                              hipStream_t stream) {
  (void)in_sizes; (void)n_in; (void)out_size; (void)ws_size;
  const float* pcd = (const float*)d_in[0];
  const float* W1a = (const float*)d_in[1];  const float* b1a = (const float*)d_in[2];
  const float* g1a = (const float*)d_in[3];  const float* be1a= (const float*)d_in[4];
  const float* W1b = (const float*)d_in[5];  const float* b1b = (const float*)d_in[6];
  const float* g1b = (const float*)d_in[7];  const float* be1b= (const float*)d_in[8];
  const float* W2a = (const float*)d_in[9];  const float* b2a = (const float*)d_in[10];
  const float* g2a = (const float*)d_in[11]; const float* be2a= (const float*)d_in[12];
  const float* W2b = (const float*)d_in[13]; const float* b2b = (const float*)d_in[14];
  const float* g2b = (const float*)d_in[15]; const float* be2b= (const float*)d_in[16];
  const float* W3a = (const float*)d_in[17]; const float* b3a = (const float*)d_in[18];
  const float* g3a = (const float*)d_in[19]; const float* be3a= (const float*)d_in[20];
  const float* W3b = (const float*)d_in[21]; const float* b3b = (const float*)d_in[22];
  const float* g3b = (const float*)d_in[23]; const float* be3b= (const float*)d_in[24];
  const float* fcW = (const float*)d_in[25]; const float* fcb = (const float*)d_in[26];

  float* wsf = (float*)d_ws;
  float* FB2 = wsf;                         // 8*4096*68
  float* FB3 = FB2 + 2228224;               // 8*2048*132
  float* FB4 = FB3 + 2162688;               // 8*1024*256
  float* WAT = FB4 + 2097152;               // 132*256 fp32 c-major
  float* WBT = WAT + 33792;
  float* TBUF= WBT + 33792;                 // 8*4096*64
  float* RED = TBUF + 2097152;
  float* red_s = RED, *red_q = RED + 4096;
  float* SC1 = RED + 8192;  float* SH1 = SC1 + 256;
  float* SC2 = SH1 + 256;   float* SH2 = SC2 + 256;
  int* IDX1 = (int*)(SH2 + 256);
  int* IDX2 = IDX1 + (size_t)8 * 4096 * 32;
  int* IDX3 = IDX2 + (size_t)8 * 2048 * 32;
  u16* H    = (u16*)(IDX3 + (size_t)8 * 1024 * 32); // 67,108,864 f16
  u16* WAH  = H + (size_t)67108864;         // 256*192 f16 max
  u16* WBH  = WAH + 49152;                  // 256*256 f16

  float* out0 = (float*)d_out;
  float* out1 = out0 + 24576;
  float* out2 = out1 + 1048576;
  float* out3 = out2 + 8192;

  zero_red<<<32, 256, 0, stream>>>(RED);

  // ================ Layer 1: C2=3, CM=64, M=4096, N=4096 ================
  knn_kernel<<<dim3(1024, 8), 256, 0, stream>>>(pcd, 4096, 4096, IDX1);
  prep_wa<<<1, 256, 0, stream>>>(W1a, WAT, WBT, 64, 3, 4);
  prep_whalf<<<16, 256, 0, stream>>>(W1b, WBH, 4096);
  conv_a_gemm<3,64,0><<<dim3(64,1,8),256,0,stream>>>(pcd,(size_t)12288,nullptr,WBT,b1a,nullptr,TBUF,nullptr,4096);
  conv_a_gemm<3,64,1><<<dim3(2048,1,8),256,0,stream>>>(pcd,(size_t)12288,IDX1,WAT,nullptr,TBUF,nullptr,H,4096);
  stats_pass<64><<<256,256,0,stream>>>(H,(size_t)8*4096*32,red_s,red_q);
  bn_finalize<<<1,256,0,stream>>>(red_s,red_q,g1a,be1a,SC1,SH1,64,1.f/1048576.f);
  conv_b_mfma<64><<<dim3(2048,8),256,0,stream>>>(H,WBH,b1b,SC1,SH1,4096*32);
  stats_pass<64><<<256,256,0,stream>>>(H,(size_t)8*4096*32,red_s,red_q);
  bn_finalize<<<1,256,0,stream>>>(red_s,red_q,g1b,be1b,SC2,SH2,64,1.f/1048576.f);
  bn_max_k<64><<<dim3(1024,8),256,0,stream>>>(H,SC2,SH2,FB2,68,(size_t)278528,4096);
  append_xyz<<<128, 256, 0, stream>>>(pcd, FB2, 4096, 68, 64);

  // ================ Layer 2: C2=67, CM=128, M=2048, N=4096 ================
  knn_kernel<<<dim3(512, 8), 256, 0, stream>>>(pcd, 4096, 2048, IDX2);
  prep_wa<<<34, 256, 0, stream>>>(W2a, WAT, WBT, 128, 67, 68);
  prep_wah<<<64, 256, 0, stream>>>(W2a, WAH, 128, 67, 128);
  prep_whalf<<<64, 256, 0, stream>>>(W2b, WBH, 16384);
  conv_a_gemm<67,128,0><<<dim3(32,2,8),256,0,stream>>>(FB2,(size_t)278528,nullptr,WBT,b2a,nullptr,TBUF,nullptr,2048);
  conv_a_mfma<128,128><<<dim3(1024,8),256,0,stream>>>(FB2,68,(size_t)278528,IDX2,WAH,TBUF,H,2048);
  stats_pass<128><<<256,256,0,stream>>>(H,(size_t)8*2048*32,red_s,red_q);
  bn_finalize<<<1,256,0,stream>>>(red_s,red_q,g2a,be2a,SC1,SH1,128,1.f/524288.f);
  conv_b_mfma<128><<<dim3(1024,8),256,0,stream>>>(H,WBH,b2b,SC1,SH1,2048*32);
  stats_pass<128><<<256,256,0,stream>>>(H,(size_t)8*2048*32,red_s,red_q);
  bn_finalize<<<1,256,0,stream>>>(red_s,red_q,g2b,be2b,SC2,SH2,128,1.f/524288.f);
  bn_max_k<128><<<dim3(1024,8),256,0,stream>>>(H,SC2,SH2,FB3,132,(size_t)270336,2048);
  append_xyz<<<64, 256, 0, stream>>>(pcd, FB3, 2048, 132, 128);

  // ================ Layer 3: C2=131, CM=256, M=1024, N=2048 ================
  knn_kernel<<<dim3(256, 8), 256, 0, stream>>>(pcd, 2048, 1024, IDX3);
  prep_wa<<<132, 256, 0, stream>>>(W3a, WAT, WBT, 256, 131, 132);
  prep_wah<<<192, 256, 0, stream>>>(W3a, WAH, 256, 131, 192);
  prep_whalf<<<256, 256, 0, stream>>>(W3b, WBH, 65536);
  conv_a_gemm<131,256,0><<<dim3(16,4,8),256,0,stream>>>(FB3,(size_t)270336,nullptr,WBT,b3a,nullptr,TBUF,nullptr,1024);
  conv_a_mfma<256,192><<<dim3(512,8),256,0,stream>>>(FB3,132,(size_t)270336,IDX3,WAH,TBUF,H,1024);
  stats_pass<256><<<256,256,0,stream>>>(H,(size_t)8*1024*32,red_s,red_q);
  bn_finalize<<<1,256,0,stream>>>(red_s,red_q,g3a,be3a,SC1,SH1,256,1.f/262144.f);
  conv_b_mfma<256><<<dim3(512,8),256,0,stream>>>(H,WBH,b3b,SC1,SH1,1024*32);
  stats_pass<256><<<256,256,0,stream>>>(H,(size_t)8*1024*32,red_s,red_q);
  bn_finalize<<<1,256,0,stream>>>(red_s,red_q,g3b,be3b,SC2,SH2,256,1.f/262144.f);
  bn_max_k<256><<<dim3(1024,8),256,0,stream>>>(H,SC2,SH2,FB4,256,(size_t)262144,1024);

  // ================ outputs ================
  fc_out<<<dim3(8, 32), 256, 0, stream>>>(FB4, fcW, fcb, out1, out3);
  out_xyz_idx<<<32, 256, 0, stream>>>(pcd, out0, out2);
}

// Round 5
// 1207.713 us; speedup vs baseline: 15.5017x; 1.7024x over previous
//
#include <hip/hip_runtime.h>
#include <hip/hip_bf16.h>

#define B8 8
#define KNN 32
typedef unsigned short u16;
typedef unsigned int u32;

typedef __attribute__((ext_vector_type(8))) _Float16 half8;
typedef __attribute__((ext_vector_type(4))) float f32x4;

static __device__ __forceinline__ u16 f2h_u(float f) {
  _Float16 h = (_Float16)f; u16 u; __builtin_memcpy(&u, &h, 2); return u;
}
static __device__ __forceinline__ float h2f_u(u16 u) {
  _Float16 h; __builtin_memcpy(&h, &u, 2); return (float)h;
}

// ---------------- KNN: one wave per query, 4-wide scan, bitonic init ----------------
__global__ __launch_bounds__(256) void knn_kernel(const float* __restrict__ pcd,
                                                  int N, int M, int* __restrict__ idxout) {
  __shared__ float4 pts[1024];
  const int t = threadIdx.x;
  const int lane = t & 63, w = t >> 6;
  const int b = blockIdx.y;
  const int m = blockIdx.x * 4 + w;
  const float* base = pcd + (size_t)b * 4096 * 3;
  const float qx = base[m*3], qy = base[m*3+1], qz = base[m*3+2];
  const float ax = -2.f*qx, ay = -2.f*qy, az = -2.f*qz;

  float hd;   // held distance, sorted ascending across lanes (64-long list; lane31 = 32nd best)
  int   hi_;  // held id
  float tau;

  // stage tile 0
  for (int i = t; i < 1024; i += 256) {
    const float* p = base + (size_t)i * 3;
    float x = p[0], y = p[1], z = p[2];
    pts[i] = make_float4(x, y, z, x*x + y*y + z*z);
  }
  __syncthreads();

  // init: bitonic sort of first 64 candidates (with id payload)
  {
    float4 p = pts[lane];
    hd = fmaf(ax, p.x, fmaf(ay, p.y, fmaf(az, p.z, p.w)));
    hi_ = lane;
#pragma unroll
    for (int k = 2; k <= 64; k <<= 1) {
#pragma unroll
      for (int j = k >> 1; j > 0; j >>= 1) {
        float od = __shfl_xor(hd, j);
        int   oi = __shfl_xor(hi_, j);
        bool keepmin = (((lane & j) == 0) == ((lane & k) == 0));
        bool sw = keepmin ? (od < hd) : (od > hd);
        hd  = sw ? od : hd;
        hi_ = sw ? oi : hi_;
      }
    }
    tau = __shfl(hd, 31);
  }

  for (int n0 = 0; n0 < N; n0 += 1024) {
    if (n0) {
      __syncthreads();
      for (int i = t; i < 1024; i += 256) {
        const float* p = base + (size_t)(n0 + i) * 3;
        float x = p[0], y = p[1], z = p[2];
        pts[i] = make_float4(x, y, z, x*x + y*y + z*z);
      }
      __syncthreads();
    }
    for (int c = 0; c < 1024; c += 256) {
      float4 p0 = pts[c + lane];
      float4 p1 = pts[c + 64 + lane];
      float4 p2 = pts[c + 128 + lane];
      float4 p3 = pts[c + 192 + lane];
      float r[4];
      r[0] = fmaf(ax, p0.x, fmaf(ay, p0.y, fmaf(az, p0.z, p0.w)));
      r[1] = fmaf(ax, p1.x, fmaf(ay, p1.y, fmaf(az, p1.z, p1.w)));
      r[2] = fmaf(ax, p2.x, fmaf(ay, p2.y, fmaf(az, p2.z, p2.w)));
      r[3] = fmaf(ax, p3.x, fmaf(ay, p3.y, fmaf(az, p3.z, p3.w)));
      if (n0 == 0 && c == 0) r[0] = 3.4e38f;   // first 64 consumed by init
#pragma unroll
      for (int j = 0; j < 4; ++j) {
        unsigned long long mask = __ballot(r[j] < tau);
        while (mask) {
          int l = __ffsll(mask) - 1;
          mask &= mask - 1;
          float rv = __shfl(r[j], l);
          if (rv < tau) {                       // wave-uniform recheck (tau tightened)
            int pos = __popcll(__ballot(hd <= rv));
            float hs = __shfl_up(hd, 1);
            int   is = __shfl_up(hi_, 1);
            bool ins = (lane == pos), shf = (lane > pos);
            hd  = ins ? rv                     : (shf ? hs : hd);
            hi_ = ins ? (n0 + c + j * 64 + l)  : (shf ? is : hi_);
            tau = __shfl(hd, 31);
          }
        }
      }
    }
  }
  if (lane < KNN) idxout[((size_t)b * M + m) * KNN + lane] = hi_;
}

// ---------------- weight prep ----------------
__global__ void prep_wa(const float* __restrict__ W, float* __restrict__ WAt, float* __restrict__ WBt,
                        int cm, int c2, int kp) {
  int i = blockIdx.x * 256 + threadIdx.x;
  if (i >= kp * cm) return;
  int c = i / cm, o = i - c * cm;
  float w1 = 0.f, w2 = 0.f;
  if (c < c2) { w1 = W[o * 2 * c2 + c]; w2 = W[o * 2 * c2 + c2 + c]; }
  WAt[c * cm + o] = w1;
  WBt[c * cm + o] = w2 - w1;
}
__global__ void prep_wah(const float* __restrict__ W, u16* __restrict__ WH,
                         int cm, int c2, int kpad) {
  int i = blockIdx.x * 256 + threadIdx.x;
  if (i >= cm * kpad) return;
  int o = i / kpad, k = i - o * kpad;
  WH[i] = (k < c2) ? f2h_u(W[o * 2 * c2 + k]) : (u16)0;
}
__global__ void prep_whalf(const float* __restrict__ W, u16* __restrict__ WH, int n) {
  int i = blockIdx.x * 256 + threadIdx.x;
  if (i < n) WH[i] = f2h_u(W[i]);
}

__global__ void zero_red(float* __restrict__ red) {
  int i = blockIdx.x * 256 + threadIdx.x;
  if (i < 8192) red[i] = 0.f;
}

// ---------------- conv_a VALU GEMM (L1 edge + all T-passes) ----------------
template<int C2, int CM, int MODE>
__global__ __launch_bounds__(256) void conv_a_gemm(
    const float* __restrict__ F, size_t fbstride,
    const int* __restrict__ idx,
    const float* __restrict__ Wt,
    const float* __restrict__ bias,
    const float* __restrict__ T,
    float* __restrict__ Tout,
    u16* __restrict__ Hout,
    int M)
{
  constexpr int KP = (C2 + 3) & ~3;
  constexpr int KC = (KP <= 68) ? KP : 44;
  __shared__ float At[64][KC];
  __shared__ float Wts[KC][64];
  __shared__ int ji[64];
  const int t = threadIdx.x;
  const int rt = blockIdx.x, ot = blockIdx.y, b = blockIdx.z;
  const int R0 = rt * 64, oc0 = ot * 64;
  const float* Fb = F + (size_t)b * fbstride;

  if (t < 64) {
    int gr = R0 + t;
    ji[t] = (MODE == 0) ? gr : idx[((size_t)b * M + (gr >> 5)) * KNN + (gr & 31)];
  }

  const int cg = t & 15, rg = t >> 4;
  const int r0 = rg * 4, c0 = cg * 4;
  float acc[4][4];
  if (MODE == 0) {
#pragma unroll
    for (int j = 0; j < 4; ++j) {
      float bv = bias[oc0 + c0 + j];
#pragma unroll
      for (int i = 0; i < 4; ++i) acc[i][j] = bv;
    }
  } else {
#pragma unroll
    for (int i = 0; i < 4; ++i) {
      const float* tp = T + ((size_t)b * M + (size_t)((R0 + r0 + i) >> 5)) * CM + oc0 + c0;
      acc[i][0] = tp[0]; acc[i][1] = tp[1]; acc[i][2] = tp[2]; acc[i][3] = tp[3];
    }
  }
  __syncthreads();

  for (int k0 = 0; k0 < KP; k0 += KC) {
    if (k0) __syncthreads();
    for (int i = t; i < KC * 64; i += 256) {
      int c = i >> 6, o = i & 63;
      Wts[c][o] = Wt[(size_t)(k0 + c) * CM + oc0 + o];
    }
    if constexpr (C2 == 3) {
      for (int i = t; i < 64 * 4; i += 256) {
        int r = i >> 2, c = i & 3;
        At[r][c] = (c < 3) ? Fb[(size_t)ji[r] * 3 + c] : 0.f;
      }
    } else {
      constexpr int C4 = KC / 4;
      for (int i = t; i < 64 * C4; i += 256) {
        int r = i / C4, c4 = i - r * C4;
        *(float4*)&At[r][c4 * 4] = *(const float4*)&Fb[(size_t)ji[r] * KP + k0 + c4 * 4];
      }
    }
    __syncthreads();

#pragma unroll 4
    for (int k = 0; k < KC; ++k) {
      const float4 w4 = *(const float4*)&Wts[k][c0];
      float a0 = At[r0][k], a1 = At[r0+1][k], a2 = At[r0+2][k], a3 = At[r0+3][k];
      acc[0][0]=fmaf(a0,w4.x,acc[0][0]); acc[0][1]=fmaf(a0,w4.y,acc[0][1]);
      acc[0][2]=fmaf(a0,w4.z,acc[0][2]); acc[0][3]=fmaf(a0,w4.w,acc[0][3]);
      acc[1][0]=fmaf(a1,w4.x,acc[1][0]); acc[1][1]=fmaf(a1,w4.y,acc[1][1]);
      acc[1][2]=fmaf(a1,w4.z,acc[1][2]); acc[1][3]=fmaf(a1,w4.w,acc[1][3]);
      acc[2][0]=fmaf(a2,w4.x,acc[2][0]); acc[2][1]=fmaf(a2,w4.y,acc[2][1]);
      acc[2][2]=fmaf(a2,w4.z,acc[2][2]); acc[2][3]=fmaf(a2,w4.w,acc[2][3]);
      acc[3][0]=fmaf(a3,w4.x,acc[3][0]); acc[3][1]=fmaf(a3,w4.y,acc[3][1]);
      acc[3][2]=fmaf(a3,w4.z,acc[3][2]); acc[3][3]=fmaf(a3,w4.w,acc[3][3]);
    }
  }

  if (MODE == 0) {
    float* op = Tout + ((size_t)b * M + R0) * (size_t)CM + oc0;
#pragma unroll
    for (int i = 0; i < 4; ++i) {
      float* p = op + (size_t)(r0 + i) * CM + c0;
      p[0]=acc[i][0]; p[1]=acc[i][1]; p[2]=acc[i][2]; p[3]=acc[i][3];
    }
  } else {
    u16* hp = Hout + ((size_t)b * M * KNN + R0) * (size_t)CM + oc0;
#pragma unroll
    for (int i = 0; i < 4; ++i) {
      ushort4 s;
      s.x = f2h_u(acc[i][0]); s.y = f2h_u(acc[i][1]); s.z = f2h_u(acc[i][2]); s.w = f2h_u(acc[i][3]);
      *(ushort4*)(hp + (size_t)(r0 + i) * CM + c0) = s;
    }
  }
}

// ---------------- conv_a MFMA (layers 2/3 edge pass) ----------------
template<int CM, int KPAD>
__global__ __launch_bounds__(256) void conv_a_mfma(
    const float* __restrict__ F, int fstride, size_t fbstride,
    const int* __restrict__ idx,
    const u16* __restrict__ Wh,
    const float* __restrict__ T,
    u16* __restrict__ Hout,
    int M)
{
  constexpr int FC = CM / 32;
  __shared__ u16 Alds[64][72];
  __shared__ u16 Wlds[CM][72];
  __shared__ int ji[64];
  const int t = threadIdx.x;
  const int lane = t & 63, w = t >> 6;
  const int wr = w >> 1, wc = w & 1;
  const int cl = lane & 15, rq = lane >> 4;
  const int rt = blockIdx.x, b = blockIdx.y;
  const int R0 = rt * 64;
  const float* Fb = F + (size_t)b * fbstride;

  if (t < 64) ji[t] = idx[((size_t)b * M + ((R0 + t) >> 5)) * KNN + ((R0 + t) & 31)];

  f32x4 acc[2][FC];
#pragma unroll
  for (int fr = 0; fr < 2; ++fr)
#pragma unroll
    for (int fc = 0; fc < FC; ++fc) {
      int col = wc * (CM/2) + fc * 16 + cl;
#pragma unroll
      for (int r = 0; r < 4; ++r) {
        int row = R0 + wr*32 + fr*16 + rq*4 + r;
        acc[fr][fc][r] = T[((size_t)b * M + (row >> 5)) * CM + col];
      }
    }
  __syncthreads();

  for (int k0 = 0; k0 < KPAD; k0 += 64) {
    if (k0) __syncthreads();
    for (int i = t; i < 64 * 16; i += 256) {
      int r = i >> 4, seg = i & 15;
      int k = k0 + seg * 4;
      ushort4 s = {0,0,0,0};
      if (k < fstride) {
        float4 v = *(const float4*)&Fb[(size_t)ji[r] * fstride + k];
        s.x = f2h_u(v.x); s.y = f2h_u(v.y); s.z = f2h_u(v.z); s.w = f2h_u(v.w);
      }
      *(ushort4*)&Alds[r][seg * 4] = s;
    }
    for (int i = t; i < CM * 8; i += 256) {
      int o = i >> 3, seg = i & 7;
      *(float4*)&Wlds[o][seg * 8] = *(const float4*)&Wh[(size_t)o * KPAD + k0 + seg * 8];
    }
    __syncthreads();

#pragma unroll
    for (int kk = 0; kk < 2; ++kk) {
      half8 af[2], bf[FC];
#pragma unroll
      for (int fr = 0; fr < 2; ++fr)
        af[fr] = *(const half8*)&Alds[wr*32 + fr*16 + cl][kk*32 + rq*8];
#pragma unroll
      for (int fc = 0; fc < FC; ++fc)
        bf[fc] = *(const half8*)&Wlds[wc*(CM/2) + fc*16 + cl][kk*32 + rq*8];
#pragma unroll
      for (int fr = 0; fr < 2; ++fr)
#pragma unroll
        for (int fc = 0; fc < FC; ++fc)
          acc[fr][fc] = __builtin_amdgcn_mfma_f32_16x16x32_f16(af[fr], bf[fc], acc[fr][fc], 0, 0, 0);
    }
  }

  u16* Hb = Hout + ((size_t)b * (size_t)M * KNN + R0) * CM;
#pragma unroll
  for (int fr = 0; fr < 2; ++fr)
#pragma unroll
    for (int fc = 0; fc < FC; ++fc) {
      int col = wc*(CM/2) + fc*16 + cl;
#pragma unroll
      for (int r = 0; r < 4; ++r) {
        int row = wr*32 + fr*16 + rq*4 + r;
        Hb[(size_t)row * CM + col] = f2h_u(acc[fr][fc][r]);
      }
    }
}

// ---------------- conv_b MFMA, in-place H ----------------
template<int CM>
__global__ __launch_bounds__(256) void conv_b_mfma(
    u16* __restrict__ H,
    const u16* __restrict__ Wh,
    const float* __restrict__ bb,
    const float* __restrict__ sc1, const float* __restrict__ sh1,
    int Mrows)
{
  constexpr int FC = CM / 32;
  __shared__ u16 Alds[64][72];
  __shared__ u16 Wlds[CM][72];
  __shared__ float scs[CM], shs[CM];
  const int t = threadIdx.x;
  const int lane = t & 63, w = t >> 6;
  const int wr = w >> 1, wc = w & 1;
  const int cl = lane & 15, rq = lane >> 4;
  const int rt = blockIdx.x, b = blockIdx.y;
  u16* Hb = H + ((size_t)b * Mrows + (size_t)rt * 64) * CM;

  for (int i = t; i < CM; i += 256) { scs[i] = sc1[i]; shs[i] = sh1[i]; }

  f32x4 acc[2][FC];
#pragma unroll
  for (int fr = 0; fr < 2; ++fr)
#pragma unroll
    for (int fc = 0; fc < FC; ++fc) {
      float bv = bb[wc * (CM/2) + fc * 16 + cl];
#pragma unroll
      for (int r = 0; r < 4; ++r) acc[fr][fc][r] = bv;
    }
  __syncthreads();

  for (int k0 = 0; k0 < CM; k0 += 64) {
    if (k0) __syncthreads();
    for (int i = t; i < 64 * 8; i += 256) {
      int r = i >> 3, seg = i & 7;
      half8 hv = *(const half8*)&Hb[(size_t)r * CM + k0 + seg * 8];
      half8 ov;
#pragma unroll
      for (int j = 0; j < 8; ++j) {
        int c = k0 + seg * 8 + j;
        float v = fmaxf(0.f, fmaf((float)hv[j], scs[c], shs[c]));
        ov[j] = (_Float16)v;
      }
      *(half8*)&Alds[r][seg * 8] = ov;
    }
    for (int i = t; i < CM * 8; i += 256) {
      int o = i >> 3, seg = i & 7;
      *(float4*)&Wlds[o][seg * 8] = *(const float4*)&Wh[(size_t)o * CM + k0 + seg * 8];
    }
    __syncthreads();

#pragma unroll
    for (int kk = 0; kk < 2; ++kk) {
      half8 af[2], bf[FC];
#pragma unroll
      for (int fr = 0; fr < 2; ++fr)
        af[fr] = *(const half8*)&Alds[wr*32 + fr*16 + cl][kk*32 + rq*8];
#pragma unroll
      for (int fc = 0; fc < FC; ++fc)
        bf[fc] = *(const half8*)&Wlds[wc*(CM/2) + fc*16 + cl][kk*32 + rq*8];
#pragma unroll
      for (int fr = 0; fr < 2; ++fr)
#pragma unroll
        for (int fc = 0; fc < FC; ++fc)
          acc[fr][fc] = __builtin_amdgcn_mfma_f32_16x16x32_f16(af[fr], bf[fc], acc[fr][fc], 0, 0, 0);
    }
  }

#pragma unroll
  for (int fr = 0; fr < 2; ++fr)
#pragma unroll
    for (int fc = 0; fc < FC; ++fc) {
      int col = wc*(CM/2) + fc*16 + cl;
#pragma unroll
      for (int r = 0; r < 4; ++r) {
        int row = wr*32 + fr*16 + rq*4 + r;
        Hb[(size_t)row * CM + col] = f2h_u(acc[fr][fc][r]);
      }
    }
}

// ---------------- stats sweep over H (half8 vectorized, padded-LDS tree reduce) ----------------
template<int CM>
__global__ __launch_bounds__(256) void stats_pass(const u16* __restrict__ H, size_t nrows,
                                                  float* __restrict__ red_s, float* __restrict__ red_q) {
  constexpr int CG = CM / 8;        // col-groups of 8
  constexpr int RL = 256 / CG;      // rows handled per block step
  const int t = threadIdx.x;
  const int cg = t % CG, rl = t / CG;
  float s[8], q[8];
#pragma unroll
  for (int j = 0; j < 8; ++j) { s[j] = 0.f; q[j] = 0.f; }
  for (size_t r = (size_t)blockIdx.x * RL + rl; r < nrows; r += (size_t)gridDim.x * RL) {
    half8 hv = *(const half8*)(H + r * CM + cg * 8);
#pragma unroll
    for (int j = 0; j < 8; ++j) {
      float v = (float)hv[j];
      s[j] += v; q[j] += v * v;
    }
  }
  __shared__ float red[256][17];
#pragma unroll
  for (int j = 0; j < 8; ++j) { red[t][j] = s[j]; red[t][8 + j] = q[j]; }
#pragma unroll
  for (int g = RL >> 1; g > 0; g >>= 1) {
    __syncthreads();
    if (rl < g) {
#pragma unroll
      for (int j = 0; j < 16; ++j) red[t][j] += red[t + g * CG][j];
    }
  }
  if (rl == 0) {
    int sh = (blockIdx.x & 15) * 256;
#pragma unroll
    for (int j = 0; j < 8; ++j) {
      atomicAdd(&red_s[sh + cg * 8 + j], red[t][j]);
      atomicAdd(&red_q[sh + cg * 8 + j], red[t][8 + j]);
    }
  }
}

// ---------------- BN finalize ----------------
__global__ void bn_finalize(float* __restrict__ red_s, float* __restrict__ red_q,
                            const float* __restrict__ g, const float* __restrict__ be,
                            float* __restrict__ sc, float* __restrict__ sh,
                            int cm, float invcnt) {
  int o = threadIdx.x;
  if (o < cm) {
    float s = 0.f, q = 0.f;
    for (int i = 0; i < 16; ++i) { s += red_s[i * 256 + o]; q += red_q[i * 256 + o]; }
    float mu  = s * invcnt;
    float var = fmaxf(q * invcnt - mu * mu, 0.f);
    float scv = g[o] * rsqrtf(var + 1e-5f);
    sc[o] = scv;
    sh[o] = fmaf(-mu, scv, be[o]);
  }
  __syncthreads();
  for (int i = threadIdx.x; i < 16 * 256; i += 256) { red_s[i] = 0.f; red_q[i] = 0.f; }
}

// ---------------- bn2 + relu + max over k (half8 vectorized) ----------------
template<int CM>
__global__ __launch_bounds__(256) void bn_max_k(const u16* __restrict__ H,
    const float* __restrict__ sc2, const float* __restrict__ sh2,
    float* __restrict__ fout, int fostride, size_t fobstride, int M) {
  constexpr int CG = CM / 8;
  constexpr int PP = 256 / CG;
  const int t = threadIdx.x;
  const int cg = t % CG, pl = t / CG;
  const int b = blockIdx.y;
  const int m = blockIdx.x * PP + pl;
  const u16* hp = H + ((size_t)b * M + m) * (size_t)KNN * CM + cg * 8;
  float sc[8], sh[8], mx[8];
#pragma unroll
  for (int j = 0; j < 8; ++j) { sc[j] = sc2[cg*8+j]; sh[j] = sh2[cg*8+j]; mx[j] = 0.f; }
#pragma unroll 4
  for (int k = 0; k < KNN; ++k) {
    half8 hv = *(const half8*)(hp + (size_t)k * CM);
#pragma unroll
    for (int j = 0; j < 8; ++j)
      mx[j] = fmaxf(mx[j], fmaf((float)hv[j], sc[j], sh[j]));
  }
  float* op = fout + (size_t)b * fobstride + (size_t)m * fostride + cg * 8;
  *(float4*)op       = make_float4(mx[0], mx[1], mx[2], mx[3]);
  *(float4*)(op + 4) = make_float4(mx[4], mx[5], mx[6], mx[7]);
}

// ---------------- append xyz (+ zero pad col) ----------------
__global__ void append_xyz(const float* __restrict__ pcd, float* __restrict__ fbuf,
                           int nrows, int stride, int coff) {
  int i = blockIdx.x * 256 + threadIdx.x;
  if (i < B8 * nrows) {
    int b = i / nrows, n = i - b * nrows;
    const float* p = pcd + ((size_t)b * 4096 + n) * 3;
    float* dd = fbuf + ((size_t)b * nrows + n) * stride + coff;
    dd[0] = p[0]; dd[1] = p[1]; dd[2] = p[2]; dd[3] = 0.f;
  }
}

// ---------------- final FC + feat transpose ----------------
__global__ __launch_bounds__(256) void fc_out(const float* __restrict__ f4,
                                              const float* __restrict__ fcW, const float* __restrict__ fcb,
                                              float* __restrict__ out1, float* __restrict__ out3) {
  __shared__ float tile[32 * 257];
  const int t = threadIdx.x, b = blockIdx.x, n0 = blockIdx.y * 32;
  for (int i = t; i < 32 * 256; i += 256) {
    int n = i >> 8, c = i & 255;
    tile[n * 257 + c] = f4[((size_t)b * 1024 + n0 + n) * 256 + c];
  }
  __syncthreads();
  const int n = t & 31, og = t >> 5;
#pragma unroll
  for (int ci = 0; ci < 32; ++ci) {
    int c = og * 32 + ci;
    out3[((size_t)b * 256 + c) * 1024 + n0 + n] = tile[n * 257 + c];
  }
#pragma unroll
  for (int oi = 0; oi < 16; ++oi) {
    int o = og * 16 + oi;
    float acc = fcb[o];
    const float* w = fcW + (size_t)o * 256;
#pragma unroll 4
    for (int c = 0; c < 256; ++c) acc = fmaf(tile[n * 257 + c], w[c], acc);
    out1[((size_t)b * 128 + o) * 1024 + n0 + n] = acc;
  }
}

__global__ void out_xyz_idx(const float* __restrict__ pcd, float* __restrict__ out0,
                            float* __restrict__ out2) {
  int i = blockIdx.x * 256 + threadIdx.x;
  if (i < B8 * 1024) {
    int b = i >> 10, n = i & 1023;
    const float* p = pcd + ((size_t)b * 4096 + n) * 3;
    float* o = out0 + (size_t)i * 3;
    o[0] = p[0]; o[1] = p[1]; o[2] = p[2];
    out2[i] = (float)n;
  }
}

// ---------------- host ----------------
extern "C" void kernel_launch(void* const* d_in, const int* in_sizes, int n_in,
                              void* d_out, int out_size, void* d_ws, size_t ws_size,
                              hipStream_t stream) {
  (void)in_sizes; (void)n_in; (void)out_size; (void)ws_size;
  const float* pcd = (const float*)d_in[0];
  const float* W1a = (const float*)d_in[1];  const float* b1a = (const float*)d_in[2];
  const float* g1a = (const float*)d_in[3];  const float* be1a= (const float*)d_in[4];
  const float* W1b = (const float*)d_in[5];  const float* b1b = (const float*)d_in[6];
  const float* g1b = (const float*)d_in[7];  const float* be1b= (const float*)d_in[8];
  const float* W2a = (const float*)d_in[9];  const float* b2a = (const float*)d_in[10];
  const float* g2a = (const float*)d_in[11]; const float* be2a= (const float*)d_in[12];
  const float* W2b = (const float*)d_in[13]; const float* b2b = (const float*)d_in[14];
  const float* g2b = (const float*)d_in[15]; const float* be2b= (const float*)d_in[16];
  const float* W3a = (const float*)d_in[17]; const float* b3a = (const float*)d_in[18];
  const float* g3a = (const float*)d_in[19]; const float* be3a= (const float*)d_in[20];
  const float* W3b = (const float*)d_in[21]; const float* b3b = (const float*)d_in[22];
  const float* g3b = (const float*)d_in[23]; const float* be3b= (const float*)d_in[24];
  const float* fcW = (const float*)d_in[25]; const float* fcb = (const float*)d_in[26];

  float* wsf = (float*)d_ws;
  float* FB2 = wsf;                         // 8*4096*68
  float* FB3 = FB2 + 2228224;               // 8*2048*132
  float* FB4 = FB3 + 2162688;               // 8*1024*256
  float* WAT = FB4 + 2097152;               // 132*256 fp32 c-major
  float* WBT = WAT + 33792;
  float* TBUF= WBT + 33792;                 // 8*4096*64
  float* RED = TBUF + 2097152;
  float* red_s = RED, *red_q = RED + 4096;
  float* SC1 = RED + 8192;  float* SH1 = SC1 + 256;
  float* SC2 = SH1 + 256;   float* SH2 = SC2 + 256;
  int* IDX1 = (int*)(SH2 + 256);
  int* IDX2 = IDX1 + (size_t)8 * 4096 * 32;
  int* IDX3 = IDX2 + (size_t)8 * 2048 * 32;
  u16* H    = (u16*)(IDX3 + (size_t)8 * 1024 * 32); // 67,108,864 f16
  u16* WAH  = H + (size_t)67108864;         // 256*192 f16 max
  u16* WBH  = WAH + 49152;                  // 256*256 f16

  float* out0 = (float*)d_out;
  float* out1 = out0 + 24576;
  float* out2 = out1 + 1048576;
  float* out3 = out2 + 8192;

  zero_red<<<32, 256, 0, stream>>>(RED);

  // ================ Layer 1: C2=3, CM=64, M=4096, N=4096 ================
  knn_kernel<<<dim3(1024, 8), 256, 0, stream>>>(pcd, 4096, 4096, IDX1);
  prep_wa<<<1, 256, 0, stream>>>(W1a, WAT, WBT, 64, 3, 4);
  prep_whalf<<<16, 256, 0, stream>>>(W1b, WBH, 4096);
  conv_a_gemm<3,64,0><<<dim3(64,1,8),256,0,stream>>>(pcd,(size_t)12288,nullptr,WBT,b1a,nullptr,TBUF,nullptr,4096);
  conv_a_gemm<3,64,1><<<dim3(2048,1,8),256,0,stream>>>(pcd,(size_t)12288,IDX1,WAT,nullptr,TBUF,nullptr,H,4096);
  stats_pass<64><<<512,256,0,stream>>>(H,(size_t)8*4096*32,red_s,red_q);
  bn_finalize<<<1,256,0,stream>>>(red_s,red_q,g1a,be1a,SC1,SH1,64,1.f/1048576.f);
  conv_b_mfma<64><<<dim3(2048,8),256,0,stream>>>(H,WBH,b1b,SC1,SH1,4096*32);
  stats_pass<64><<<512,256,0,stream>>>(H,(size_t)8*4096*32,red_s,red_q);
  bn_finalize<<<1,256,0,stream>>>(red_s,red_q,g1b,be1b,SC2,SH2,64,1.f/1048576.f);
  bn_max_k<64><<<dim3(128,8),256,0,stream>>>(H,SC2,SH2,FB2,68,(size_t)278528,4096);
  append_xyz<<<128, 256, 0, stream>>>(pcd, FB2, 4096, 68, 64);

  // ================ Layer 2: C2=67, CM=128, M=2048, N=4096 ================
  knn_kernel<<<dim3(512, 8), 256, 0, stream>>>(pcd, 4096, 2048, IDX2);
  prep_wa<<<34, 256, 0, stream>>>(W2a, WAT, WBT, 128, 67, 68);
  prep_wah<<<64, 256, 0, stream>>>(W2a, WAH, 128, 67, 128);
  prep_whalf<<<64, 256, 0, stream>>>(W2b, WBH, 16384);
  conv_a_gemm<67,128,0><<<dim3(32,2,8),256,0,stream>>>(FB2,(size_t)278528,nullptr,WBT,b2a,nullptr,TBUF,nullptr,2048);
  conv_a_mfma<128,128><<<dim3(1024,8),256,0,stream>>>(FB2,68,(size_t)278528,IDX2,WAH,TBUF,H,2048);
  stats_pass<128><<<512,256,0,stream>>>(H,(size_t)8*2048*32,red_s,red_q);
  bn_finalize<<<1,256,0,stream>>>(red_s,red_q,g2a,be2a,SC1,SH1,128,1.f/524288.f);
  conv_b_mfma<128><<<dim3(1024,8),256,0,stream>>>(H,WBH,b2b,SC1,SH1,2048*32);
  stats_pass<128><<<512,256,0,stream>>>(H,(size_t)8*2048*32,red_s,red_q);
  bn_finalize<<<1,256,0,stream>>>(red_s,red_q,g2b,be2b,SC2,SH2,128,1.f/524288.f);
  bn_max_k<128><<<dim3(128,8),256,0,stream>>>(H,SC2,SH2,FB3,132,(size_t)270336,2048);
  append_xyz<<<64, 256, 0, stream>>>(pcd, FB3, 2048, 132, 128);

  // ================ Layer 3: C2=131, CM=256, M=1024, N=2048 ================
  knn_kernel<<<dim3(256, 8), 256, 0, stream>>>(pcd, 2048, 1024, IDX3);
  prep_wa<<<132, 256, 0, stream>>>(W3a, WAT, WBT, 256, 131, 132);
  prep_wah<<<192, 256, 0, stream>>>(W3a, WAH, 256, 131, 192);
  prep_whalf<<<256, 256, 0, stream>>>(W3b, WBH, 65536);
  conv_a_gemm<131,256,0><<<dim3(16,4,8),256,0,stream>>>(FB3,(size_t)270336,nullptr,WBT,b3a,nullptr,TBUF,nullptr,1024);
  conv_a_mfma<256,192><<<dim3(512,8),256,0,stream>>>(FB3,132,(size_t)270336,IDX3,WAH,TBUF,H,1024);
  stats_pass<256><<<512,256,0,stream>>>(H,(size_t)8*1024*32,red_s,red_q);
  bn_finalize<<<1,256,0,stream>>>(red_s,red_q,g3a,be3a,SC1,SH1,256,1.f/262144.f);
  conv_b_mfma<256><<<dim3(512,8),256,0,stream>>>(H,WBH,b3b,SC1,SH1,1024*32);
  stats_pass<256><<<512,256,0,stream>>>(H,(size_t)8*1024*32,red_s,red_q);
  bn_finalize<<<1,256,0,stream>>>(red_s,red_q,g3b,be3b,SC2,SH2,256,1.f/262144.f);
  bn_max_k<256><<<dim3(128,8),256,0,stream>>>(H,SC2,SH2,FB4,256,(size_t)262144,1024);

  // ================ outputs ================
  fc_out<<<dim3(8, 32), 256, 0, stream>>>(FB4, fcW, fcb, out1, out3);
  out_xyz_idx<<<32, 256, 0, stream>>>(pcd, out0, out2);
}

// Round 6
// 1036.409 us; speedup vs baseline: 18.0639x; 1.1653x over previous
//
#include <hip/hip_runtime.h>
#include <hip/hip_bf16.h>

#define B8 8
#define KNN 32
typedef unsigned short u16;
typedef unsigned int u32;

typedef __attribute__((ext_vector_type(8))) _Float16 half8;
typedef __attribute__((ext_vector_type(4))) float f32x4;

static __device__ __forceinline__ u16 f2h_u(float f) {
  _Float16 h = (_Float16)f; u16 u; __builtin_memcpy(&u, &h, 2); return u;
}
static __device__ __forceinline__ float h2f_u(u16 u) {
  _Float16 h; __builtin_memcpy(&h, &u, 2); return (float)h;
}

// ---------------- KNN: one wave per query, 4-wide scan, bitonic init ----------------
__global__ __launch_bounds__(256) void knn_kernel(const float* __restrict__ pcd,
                                                  int N, int M, int* __restrict__ idxout) {
  __shared__ float4 pts[1024];
  const int t = threadIdx.x;
  const int lane = t & 63, w = t >> 6;
  const int b = blockIdx.y;
  const int m = blockIdx.x * 4 + w;
  const float* base = pcd + (size_t)b * 4096 * 3;
  const float qx = base[m*3], qy = base[m*3+1], qz = base[m*3+2];
  const float ax = -2.f*qx, ay = -2.f*qy, az = -2.f*qz;

  float hd; int hi_; float tau;

  for (int i = t; i < 1024; i += 256) {
    const float* p = base + (size_t)i * 3;
    float x = p[0], y = p[1], z = p[2];
    pts[i] = make_float4(x, y, z, x*x + y*y + z*z);
  }
  __syncthreads();

  {
    float4 p = pts[lane];
    hd = fmaf(ax, p.x, fmaf(ay, p.y, fmaf(az, p.z, p.w)));
    hi_ = lane;
#pragma unroll
    for (int k = 2; k <= 64; k <<= 1) {
#pragma unroll
      for (int j = k >> 1; j > 0; j >>= 1) {
        float od = __shfl_xor(hd, j);
        int   oi = __shfl_xor(hi_, j);
        bool keepmin = (((lane & j) == 0) == ((lane & k) == 0));
        bool sw = keepmin ? (od < hd) : (od > hd);
        hd  = sw ? od : hd;
        hi_ = sw ? oi : hi_;
      }
    }
    tau = __shfl(hd, 31);
  }

  for (int n0 = 0; n0 < N; n0 += 1024) {
    if (n0) {
      __syncthreads();
      for (int i = t; i < 1024; i += 256) {
        const float* p = base + (size_t)(n0 + i) * 3;
        float x = p[0], y = p[1], z = p[2];
        pts[i] = make_float4(x, y, z, x*x + y*y + z*z);
      }
      __syncthreads();
    }
    for (int c = 0; c < 1024; c += 256) {
      float4 p0 = pts[c + lane];
      float4 p1 = pts[c + 64 + lane];
      float4 p2 = pts[c + 128 + lane];
      float4 p3 = pts[c + 192 + lane];
      float r[4];
      r[0] = fmaf(ax, p0.x, fmaf(ay, p0.y, fmaf(az, p0.z, p0.w)));
      r[1] = fmaf(ax, p1.x, fmaf(ay, p1.y, fmaf(az, p1.z, p1.w)));
      r[2] = fmaf(ax, p2.x, fmaf(ay, p2.y, fmaf(az, p2.z, p2.w)));
      r[3] = fmaf(ax, p3.x, fmaf(ay, p3.y, fmaf(az, p3.z, p3.w)));
      if (n0 == 0 && c == 0) r[0] = 3.4e38f;
#pragma unroll
      for (int j = 0; j < 4; ++j) {
        unsigned long long mask = __ballot(r[j] < tau);
        while (mask) {
          int l = __ffsll(mask) - 1;
          mask &= mask - 1;
          float rv = __shfl(r[j], l);
          if (rv < tau) {
            int pos = __popcll(__ballot(hd <= rv));
            float hs = __shfl_up(hd, 1);
            int   is = __shfl_up(hi_, 1);
            bool ins = (lane == pos), shf = (lane > pos);
            hd  = ins ? rv                     : (shf ? hs : hd);
            hi_ = ins ? (n0 + c + j * 64 + l)  : (shf ? is : hi_);
            tau = __shfl(hd, 31);
          }
        }
      }
    }
  }
  if (lane < KNN) idxout[((size_t)b * M + m) * KNN + lane] = hi_;
}

// ---------------- weight prep ----------------
__global__ void prep_wa(const float* __restrict__ W, float* __restrict__ WAt, float* __restrict__ WBt,
                        int cm, int c2, int kp) {
  int i = blockIdx.x * 256 + threadIdx.x;
  if (i >= kp * cm) return;
  int c = i / cm, o = i - c * cm;
  float w1 = 0.f, w2 = 0.f;
  if (c < c2) { w1 = W[o * 2 * c2 + c]; w2 = W[o * 2 * c2 + c2 + c]; }
  WAt[c * cm + o] = w1;
  WBt[c * cm + o] = w2 - w1;
}
__global__ void prep_wah(const float* __restrict__ W, u16* __restrict__ WH,
                         int cm, int c2, int kpad) {
  int i = blockIdx.x * 256 + threadIdx.x;
  if (i >= cm * kpad) return;
  int o = i / kpad, k = i - o * kpad;
  WH[i] = (k < c2) ? f2h_u(W[o * 2 * c2 + k]) : (u16)0;
}
__global__ void prep_whalf(const float* __restrict__ W, u16* __restrict__ WH, int n) {
  int i = blockIdx.x * 256 + threadIdx.x;
  if (i < n) WH[i] = f2h_u(W[i]);
}

__global__ void zero_red(float* __restrict__ red) {
  int i = blockIdx.x * 256 + threadIdx.x;
  if (i < 8192) red[i] = 0.f;
}

// ---------------- conv_a VALU GEMM (L1 edge [+stats] + all T-passes) ----------------
template<int C2, int CM, int MODE>
__global__ __launch_bounds__(256) void conv_a_gemm(
    const float* __restrict__ F, size_t fbstride,
    const int* __restrict__ idx,
    const float* __restrict__ Wt,
    const float* __restrict__ bias,
    const float* __restrict__ T,
    float* __restrict__ Tout,
    u16* __restrict__ Hout,
    float* __restrict__ red_s, float* __restrict__ red_q,
    int M)
{
  constexpr int KP = (C2 + 3) & ~3;
  constexpr int KC = (KP <= 68) ? KP : 44;
  __shared__ float At[64][KC];
  __shared__ float Wts[KC][64];
  __shared__ int ji[64];
  __shared__ float sred[4][64];
  __shared__ float qred[4][64];
  const int t = threadIdx.x;
  const int rt = blockIdx.x, ot = blockIdx.y, b = blockIdx.z;
  const int R0 = rt * 64, oc0 = ot * 64;
  const float* Fb = F + (size_t)b * fbstride;

  if (t < 64) {
    int gr = R0 + t;
    ji[t] = (MODE == 0) ? gr : idx[((size_t)b * M + (gr >> 5)) * KNN + (gr & 31)];
  }

  const int cg = t & 15, rg = t >> 4;
  const int r0 = rg * 4, c0 = cg * 4;
  float acc[4][4];
  if (MODE == 0) {
#pragma unroll
    for (int j = 0; j < 4; ++j) {
      float bv = bias[oc0 + c0 + j];
#pragma unroll
      for (int i = 0; i < 4; ++i) acc[i][j] = bv;
    }
  } else {
#pragma unroll
    for (int i = 0; i < 4; ++i) {
      const float* tp = T + ((size_t)b * M + (size_t)((R0 + r0 + i) >> 5)) * CM + oc0 + c0;
      acc[i][0] = tp[0]; acc[i][1] = tp[1]; acc[i][2] = tp[2]; acc[i][3] = tp[3];
    }
  }
  __syncthreads();

  for (int k0 = 0; k0 < KP; k0 += KC) {
    if (k0) __syncthreads();
    for (int i = t; i < KC * 64; i += 256) {
      int c = i >> 6, o = i & 63;
      Wts[c][o] = Wt[(size_t)(k0 + c) * CM + oc0 + o];
    }
    if constexpr (C2 == 3) {
      for (int i = t; i < 64 * 4; i += 256) {
        int r = i >> 2, c = i & 3;
        At[r][c] = (c < 3) ? Fb[(size_t)ji[r] * 3 + c] : 0.f;
      }
    } else {
      constexpr int C4 = KC / 4;
      for (int i = t; i < 64 * C4; i += 256) {
        int r = i / C4, c4 = i - r * C4;
        *(float4*)&At[r][c4 * 4] = *(const float4*)&Fb[(size_t)ji[r] * KP + k0 + c4 * 4];
      }
    }
    __syncthreads();

#pragma unroll 4
    for (int k = 0; k < KC; ++k) {
      const float4 w4 = *(const float4*)&Wts[k][c0];
      float a0 = At[r0][k], a1 = At[r0+1][k], a2 = At[r0+2][k], a3 = At[r0+3][k];
      acc[0][0]=fmaf(a0,w4.x,acc[0][0]); acc[0][1]=fmaf(a0,w4.y,acc[0][1]);
      acc[0][2]=fmaf(a0,w4.z,acc[0][2]); acc[0][3]=fmaf(a0,w4.w,acc[0][3]);
      acc[1][0]=fmaf(a1,w4.x,acc[1][0]); acc[1][1]=fmaf(a1,w4.y,acc[1][1]);
      acc[1][2]=fmaf(a1,w4.z,acc[1][2]); acc[1][3]=fmaf(a1,w4.w,acc[1][3]);
      acc[2][0]=fmaf(a2,w4.x,acc[2][0]); acc[2][1]=fmaf(a2,w4.y,acc[2][1]);
      acc[2][2]=fmaf(a2,w4.z,acc[2][2]); acc[2][3]=fmaf(a2,w4.w,acc[2][3]);
      acc[3][0]=fmaf(a3,w4.x,acc[3][0]); acc[3][1]=fmaf(a3,w4.y,acc[3][1]);
      acc[3][2]=fmaf(a3,w4.z,acc[3][2]); acc[3][3]=fmaf(a3,w4.w,acc[3][3]);
    }
  }

  if (MODE == 0) {
    float* op = Tout + ((size_t)b * M + R0) * (size_t)CM + oc0;
#pragma unroll
    for (int i = 0; i < 4; ++i) {
      float* p = op + (size_t)(r0 + i) * CM + c0;
      p[0]=acc[i][0]; p[1]=acc[i][1]; p[2]=acc[i][2]; p[3]=acc[i][3];
    }
  } else {
    u16* hp = Hout + ((size_t)b * M * KNN + R0) * (size_t)CM + oc0;
#pragma unroll
    for (int i = 0; i < 4; ++i) {
      ushort4 s;
      s.x = f2h_u(acc[i][0]); s.y = f2h_u(acc[i][1]); s.z = f2h_u(acc[i][2]); s.w = f2h_u(acc[i][3]);
      *(ushort4*)(hp + (size_t)(r0 + i) * CM + c0) = s;
    }
    // fused bn1 stats (gridDim.y == 1 for this mode)
    float cs[4], cq_[4];
#pragma unroll
    for (int j = 0; j < 4; ++j) {
      float s = acc[0][j] + acc[1][j] + acc[2][j] + acc[3][j];
      float q = acc[0][j]*acc[0][j] + acc[1][j]*acc[1][j] + acc[2][j]*acc[2][j] + acc[3][j]*acc[3][j];
      s += __shfl_xor(s, 16); q += __shfl_xor(q, 16);
      s += __shfl_xor(s, 32); q += __shfl_xor(q, 32);
      cs[j] = s; cq_[j] = q;
    }
    const int wv = t >> 6;
    if ((t & 48) == 0) {
#pragma unroll
      for (int j = 0; j < 4; ++j) { sred[wv][c0 + j] = cs[j]; qred[wv][c0 + j] = cq_[j]; }
    }
    __syncthreads();
    if (t < 64) {
      float s = sred[0][t] + sred[1][t] + sred[2][t] + sred[3][t];
      float q = qred[0][t] + qred[1][t] + qred[2][t] + qred[3][t];
      int shdw = (rt & 15) * 256;
      atomicAdd(&red_s[shdw + t], s);
      atomicAdd(&red_q[shdw + t], q);
    }
  }
}

// ---------------- conv_a MFMA (layers 2/3 edge pass) + fused bn1 stats ----------------
template<int CM, int KPAD>
__global__ __launch_bounds__(256) void conv_a_mfma(
    const float* __restrict__ F, int fstride, size_t fbstride,
    const int* __restrict__ idx,
    const u16* __restrict__ Wh,
    const float* __restrict__ T,
    u16* __restrict__ Hout,
    float* __restrict__ red_s, float* __restrict__ red_q,
    int M)
{
  constexpr int FC = CM / 32;
  __shared__ u16 Alds[64][72];
  __shared__ u16 Wlds[CM][72];
  __shared__ int ji[64];
  const int t = threadIdx.x;
  const int lane = t & 63, w = t >> 6;
  const int wr = w >> 1, wc = w & 1;
  const int cl = lane & 15, rq = lane >> 4;
  const int rt = blockIdx.x, b = blockIdx.y;
  const int R0 = rt * 64;
  const float* Fb = F + (size_t)b * fbstride;

  if (t < 64) ji[t] = idx[((size_t)b * M + ((R0 + t) >> 5)) * KNN + ((R0 + t) & 31)];

  f32x4 acc[2][FC];
#pragma unroll
  for (int fr = 0; fr < 2; ++fr)
#pragma unroll
    for (int fc = 0; fc < FC; ++fc) {
      int col = wc * (CM/2) + fc * 16 + cl;
#pragma unroll
      for (int r = 0; r < 4; ++r) {
        int row = R0 + wr*32 + fr*16 + rq*4 + r;
        acc[fr][fc][r] = T[((size_t)b * M + (row >> 5)) * CM + col];
      }
    }
  __syncthreads();

  for (int k0 = 0; k0 < KPAD; k0 += 64) {
    if (k0) __syncthreads();
    for (int i = t; i < 64 * 16; i += 256) {
      int r = i >> 4, seg = i & 15;
      int k = k0 + seg * 4;
      ushort4 s = {0,0,0,0};
      if (k < fstride) {
        float4 v = *(const float4*)&Fb[(size_t)ji[r] * fstride + k];
        s.x = f2h_u(v.x); s.y = f2h_u(v.y); s.z = f2h_u(v.z); s.w = f2h_u(v.w);
      }
      *(ushort4*)&Alds[r][seg * 4] = s;
    }
    for (int i = t; i < CM * 8; i += 256) {
      int o = i >> 3, seg = i & 7;
      *(float4*)&Wlds[o][seg * 8] = *(const float4*)&Wh[(size_t)o * KPAD + k0 + seg * 8];
    }
    __syncthreads();

#pragma unroll
    for (int kk = 0; kk < 2; ++kk) {
      half8 af[2], bf[FC];
#pragma unroll
      for (int fr = 0; fr < 2; ++fr)
        af[fr] = *(const half8*)&Alds[wr*32 + fr*16 + cl][kk*32 + rq*8];
#pragma unroll
      for (int fc = 0; fc < FC; ++fc)
        bf[fc] = *(const half8*)&Wlds[wc*(CM/2) + fc*16 + cl][kk*32 + rq*8];
#pragma unroll
      for (int fr = 0; fr < 2; ++fr)
#pragma unroll
        for (int fc = 0; fc < FC; ++fc)
          acc[fr][fc] = __builtin_amdgcn_mfma_f32_16x16x32_f16(af[fr], bf[fc], acc[fr][fc], 0, 0, 0);
    }
  }

  u16* Hb = Hout + ((size_t)b * (size_t)M * KNN + R0) * CM;
#pragma unroll
  for (int fr = 0; fr < 2; ++fr)
#pragma unroll
    for (int fc = 0; fc < FC; ++fc) {
      int col = wc*(CM/2) + fc*16 + cl;
#pragma unroll
      for (int r = 0; r < 4; ++r) {
        int row = wr*32 + fr*16 + rq*4 + r;
        Hb[(size_t)row * CM + col] = f2h_u(acc[fr][fc][r]);
      }
    }

  // fused bn1 stats (fp32 fragments)
#pragma unroll
  for (int fc = 0; fc < FC; ++fc) {
    float s = 0.f, q = 0.f;
#pragma unroll
    for (int fr = 0; fr < 2; ++fr)
#pragma unroll
      for (int r = 0; r < 4; ++r) {
        float v = acc[fr][fc][r];
        s += v; q += v * v;
      }
    s += __shfl_xor(s, 16); q += __shfl_xor(q, 16);
    s += __shfl_xor(s, 32); q += __shfl_xor(q, 32);
    if (rq == 0) {
      int col = wc*(CM/2) + fc*16 + cl;
      int shdw = (rt & 15) * 256;
      atomicAdd(&red_s[shdw + col], s);
      atomicAdd(&red_q[shdw + col], q);
    }
  }
}

// ---------------- conv_b MFMA fused: reads h1, emits bn2-stats + max_k only ----------------
template<int CM>
__global__ __launch_bounds__(256) void conv_b_fused(
    const u16* __restrict__ H,
    const u16* __restrict__ Wh,
    const float* __restrict__ bb,
    const float* __restrict__ sc1, const float* __restrict__ sh1,
    float* __restrict__ red_s, float* __restrict__ red_q,
    float* __restrict__ hmax,           // [B][Mpts][CM] fp32
    int Mrows)
{
  constexpr int FC = CM / 32;
  __shared__ u16 Alds[64][72];
  __shared__ u16 Wlds[CM][72];
  __shared__ float scs[CM], shs[CM];
  const int t = threadIdx.x;
  const int lane = t & 63, w = t >> 6;
  const int wr = w >> 1, wc = w & 1;
  const int cl = lane & 15, rq = lane >> 4;
  const int rt = blockIdx.x, b = blockIdx.y;
  const u16* Hb = H + ((size_t)b * Mrows + (size_t)rt * 64) * CM;

  for (int i = t; i < CM; i += 256) { scs[i] = sc1[i]; shs[i] = sh1[i]; }

  f32x4 acc[2][FC];
#pragma unroll
  for (int fr = 0; fr < 2; ++fr)
#pragma unroll
    for (int fc = 0; fc < FC; ++fc) {
      float bv = bb[wc * (CM/2) + fc * 16 + cl];
#pragma unroll
      for (int r = 0; r < 4; ++r) acc[fr][fc][r] = bv;
    }
  __syncthreads();

  for (int k0 = 0; k0 < CM; k0 += 64) {
    if (k0) __syncthreads();
    for (int i = t; i < 64 * 8; i += 256) {
      int r = i >> 3, seg = i & 7;
      half8 hv = *(const half8*)&Hb[(size_t)r * CM + k0 + seg * 8];
      half8 ov;
#pragma unroll
      for (int j = 0; j < 8; ++j) {
        int c = k0 + seg * 8 + j;
        float v = fmaxf(0.f, fmaf((float)hv[j], scs[c], shs[c]));
        ov[j] = (_Float16)v;
      }
      *(half8*)&Alds[r][seg * 8] = ov;
    }
    for (int i = t; i < CM * 8; i += 256) {
      int o = i >> 3, seg = i & 7;
      *(float4*)&Wlds[o][seg * 8] = *(const float4*)&Wh[(size_t)o * CM + k0 + seg * 8];
    }
    __syncthreads();

#pragma unroll
    for (int kk = 0; kk < 2; ++kk) {
      half8 af[2], bf[FC];
#pragma unroll
      for (int fr = 0; fr < 2; ++fr)
        af[fr] = *(const half8*)&Alds[wr*32 + fr*16 + cl][kk*32 + rq*8];
#pragma unroll
      for (int fc = 0; fc < FC; ++fc)
        bf[fc] = *(const half8*)&Wlds[wc*(CM/2) + fc*16 + cl][kk*32 + rq*8];
#pragma unroll
      for (int fr = 0; fr < 2; ++fr)
#pragma unroll
        for (int fc = 0; fc < FC; ++fc)
          acc[fr][fc] = __builtin_amdgcn_mfma_f32_16x16x32_f16(af[fr], bf[fc], acc[fr][fc], 0, 0, 0);
    }
  }

  // epilogue: stats (raw h2) + max over k per point; NO h2 write
#pragma unroll
  for (int fc = 0; fc < FC; ++fc) {
    float s = 0.f, q = 0.f, mx = -3.4e38f;
#pragma unroll
    for (int fr = 0; fr < 2; ++fr)
#pragma unroll
      for (int r = 0; r < 4; ++r) {
        float v = acc[fr][fc][r];
        s += v; q += v * v; mx = fmaxf(mx, v);
      }
    s += __shfl_xor(s, 16); q += __shfl_xor(q, 16); mx = fmaxf(mx, __shfl_xor(mx, 16));
    s += __shfl_xor(s, 32); q += __shfl_xor(q, 32); mx = fmaxf(mx, __shfl_xor(mx, 32));
    if (rq == 0) {
      int col = wc*(CM/2) + fc*16 + cl;
      int shdw = (rt & 15) * 256;
      atomicAdd(&red_s[shdw + col], s);
      atomicAdd(&red_q[shdw + col], q);
      hmax[((size_t)b * (Mrows >> 5) + (size_t)(rt * 2 + wr)) * CM + col] = mx;
    }
  }
}

// ---------------- BN finalize ----------------
__global__ void bn_finalize(float* __restrict__ red_s, float* __restrict__ red_q,
                            const float* __restrict__ g, const float* __restrict__ be,
                            float* __restrict__ sc, float* __restrict__ sh,
                            int cm, float invcnt) {
  int o = threadIdx.x;
  if (o < cm) {
    float s = 0.f, q = 0.f;
    for (int i = 0; i < 16; ++i) { s += red_s[i * 256 + o]; q += red_q[i * 256 + o]; }
    float mu  = s * invcnt;
    float var = fmaxf(q * invcnt - mu * mu, 0.f);
    float scv = g[o] * rsqrtf(var + 1e-5f);
    sc[o] = scv;
    sh[o] = fmaf(-mu, scv, be[o]);
  }
  __syncthreads();
  for (int i = threadIdx.x; i < 16 * 256; i += 256) { red_s[i] = 0.f; red_q[i] = 0.f; }
}

// ---------------- bn2 + relu on max values -> feature buffer ----------------
__global__ __launch_bounds__(256) void bnrelu_fb(const float* __restrict__ hm,
    const float* __restrict__ sc2, const float* __restrict__ sh2,
    float* __restrict__ fout, int CM, int fostride, size_t fobstride, int M) {
  int i = blockIdx.x * 256 + threadIdx.x;
  int cq = CM >> 2;
  int total = B8 * M * cq;
  if (i >= total) return;
  int c4 = i % cq; int r = i / cq;
  int b = r / M, m = r - b * M;
  float4 v = *(const float4*)&hm[((size_t)b * M + m) * CM + c4 * 4];
  int c = c4 * 4;
  float4 o;
  o.x = fmaxf(0.f, fmaf(v.x, sc2[c],   sh2[c]));
  o.y = fmaxf(0.f, fmaf(v.y, sc2[c+1], sh2[c+1]));
  o.z = fmaxf(0.f, fmaf(v.z, sc2[c+2], sh2[c+2]));
  o.w = fmaxf(0.f, fmaf(v.w, sc2[c+3], sh2[c+3]));
  *(float4*)&fout[(size_t)b * fobstride + (size_t)m * fostride + c] = o;
}

// ---------------- append xyz (+ zero pad col) ----------------
__global__ void append_xyz(const float* __restrict__ pcd, float* __restrict__ fbuf,
                           int nrows, int stride, int coff) {
  int i = blockIdx.x * 256 + threadIdx.x;
  if (i < B8 * nrows) {
    int b = i / nrows, n = i - b * nrows;
    const float* p = pcd + ((size_t)b * 4096 + n) * 3;
    float* dd = fbuf + ((size_t)b * nrows + n) * stride + coff;
    dd[0] = p[0]; dd[1] = p[1]; dd[2] = p[2]; dd[3] = 0.f;
  }
}

// ---------------- final FC + feat transpose ----------------
__global__ __launch_bounds__(256) void fc_out(const float* __restrict__ f4,
                                              const float* __restrict__ fcW, const float* __restrict__ fcb,
                                              float* __restrict__ out1, float* __restrict__ out3) {
  __shared__ float tile[32 * 257];
  const int t = threadIdx.x, b = blockIdx.x, n0 = blockIdx.y * 32;
  for (int i = t; i < 32 * 256; i += 256) {
    int n = i >> 8, c = i & 255;
    tile[n * 257 + c] = f4[((size_t)b * 1024 + n0 + n) * 256 + c];
  }
  __syncthreads();
  const int n = t & 31, og = t >> 5;
#pragma unroll
  for (int ci = 0; ci < 32; ++ci) {
    int c = og * 32 + ci;
    out3[((size_t)b * 256 + c) * 1024 + n0 + n] = tile[n * 257 + c];
  }
#pragma unroll
  for (int oi = 0; oi < 16; ++oi) {
    int o = og * 16 + oi;
    float acc = fcb[o];
    const float* w = fcW + (size_t)o * 256;
#pragma unroll 4
    for (int c = 0; c < 256; ++c) acc = fmaf(tile[n * 257 + c], w[c], acc);
    out1[((size_t)b * 128 + o) * 1024 + n0 + n] = acc;
  }
}

__global__ void out_xyz_idx(const float* __restrict__ pcd, float* __restrict__ out0,
                            float* __restrict__ out2) {
  int i = blockIdx.x * 256 + threadIdx.x;
  if (i < B8 * 1024) {
    int b = i >> 10, n = i & 1023;
    const float* p = pcd + ((size_t)b * 4096 + n) * 3;
    float* o = out0 + (size_t)i * 3;
    o[0] = p[0]; o[1] = p[1]; o[2] = p[2];
    out2[i] = (float)n;
  }
}

// ---------------- host ----------------
extern "C" void kernel_launch(void* const* d_in, const int* in_sizes, int n_in,
                              void* d_out, int out_size, void* d_ws, size_t ws_size,
                              hipStream_t stream) {
  (void)in_sizes; (void)n_in; (void)out_size; (void)ws_size;
  const float* pcd = (const float*)d_in[0];
  const float* W1a = (const float*)d_in[1];  const float* b1a = (const float*)d_in[2];
  const float* g1a = (const float*)d_in[3];  const float* be1a= (const float*)d_in[4];
  const float* W1b = (const float*)d_in[5];  const float* b1b = (const float*)d_in[6];
  const float* g1b = (const float*)d_in[7];  const float* be1b= (const float*)d_in[8];
  const float* W2a = (const float*)d_in[9];  const float* b2a = (const float*)d_in[10];
  const float* g2a = (const float*)d_in[11]; const float* be2a= (const float*)d_in[12];
  const float* W2b = (const float*)d_in[13]; const float* b2b = (const float*)d_in[14];
  const float* g2b = (const float*)d_in[15]; const float* be2b= (const float*)d_in[16];
  const float* W3a = (const float*)d_in[17]; const float* b3a = (const float*)d_in[18];
  const float* g3a = (const float*)d_in[19]; const float* be3a= (const float*)d_in[20];
  const float* W3b = (const float*)d_in[21]; const float* b3b = (const float*)d_in[22];
  const float* g3b = (const float*)d_in[23]; const float* be3b= (const float*)d_in[24];
  const float* fcW = (const float*)d_in[25]; const float* fcb = (const float*)d_in[26];

  float* wsf = (float*)d_ws;
  float* FB2 = wsf;                         // 8*4096*68
  float* FB3 = FB2 + 2228224;               // 8*2048*132
  float* FB4 = FB3 + 2162688;               // 8*1024*256
  float* WAT = FB4 + 2097152;               // 132*256 fp32 c-major
  float* WBT = WAT + 33792;
  float* TBUF= WBT + 33792;                 // 8*4096*64
  float* RED = TBUF + 2097152;
  float* red_s = RED, *red_q = RED + 4096;
  float* SC1 = RED + 8192;  float* SH1 = SC1 + 256;
  float* SC2 = SH1 + 256;   float* SH2 = SC2 + 256;
  int* IDX1 = (int*)(SH2 + 256);
  int* IDX2 = IDX1 + (size_t)8 * 4096 * 32;
  int* IDX3 = IDX2 + (size_t)8 * 2048 * 32;
  u16* H    = (u16*)(IDX3 + (size_t)8 * 1024 * 32); // 67,108,864 f16
  u16* WAH  = H + (size_t)67108864;         // 256*192 f16 max
  u16* WBH  = WAH + 49152;                  // 256*256 f16
  float* HMAX = (float*)(WBH + 65536);      // 8*4096*64 = 2,097,152 fp32 (all layers)

  float* out0 = (float*)d_out;
  float* out1 = out0 + 24576;
  float* out2 = out1 + 1048576;
  float* out3 = out2 + 8192;

  zero_red<<<32, 256, 0, stream>>>(RED);

  // ================ Layer 1: C2=3, CM=64, M=4096, N=4096 ================
  knn_kernel<<<dim3(1024, 8), 256, 0, stream>>>(pcd, 4096, 4096, IDX1);
  prep_wa<<<1, 256, 0, stream>>>(W1a, WAT, WBT, 64, 3, 4);
  prep_whalf<<<16, 256, 0, stream>>>(W1b, WBH, 4096);
  conv_a_gemm<3,64,0><<<dim3(64,1,8),256,0,stream>>>(pcd,(size_t)12288,nullptr,WBT,b1a,nullptr,TBUF,nullptr,nullptr,nullptr,4096);
  conv_a_gemm<3,64,1><<<dim3(2048,1,8),256,0,stream>>>(pcd,(size_t)12288,IDX1,WAT,nullptr,TBUF,nullptr,H,red_s,red_q,4096);
  bn_finalize<<<1,256,0,stream>>>(red_s,red_q,g1a,be1a,SC1,SH1,64,1.f/1048576.f);
  conv_b_fused<64><<<dim3(2048,8),256,0,stream>>>(H,WBH,b1b,SC1,SH1,red_s,red_q,HMAX,4096*32);
  bn_finalize<<<1,256,0,stream>>>(red_s,red_q,g1b,be1b,SC2,SH2,64,1.f/1048576.f);
  bnrelu_fb<<<2048,256,0,stream>>>(HMAX,SC2,SH2,FB2,64,68,(size_t)278528,4096);
  append_xyz<<<128, 256, 0, stream>>>(pcd, FB2, 4096, 68, 64);

  // ================ Layer 2: C2=67, CM=128, M=2048, N=4096 ================
  knn_kernel<<<dim3(512, 8), 256, 0, stream>>>(pcd, 4096, 2048, IDX2);
  prep_wa<<<34, 256, 0, stream>>>(W2a, WAT, WBT, 128, 67, 68);
  prep_wah<<<64, 256, 0, stream>>>(W2a, WAH, 128, 67, 128);
  prep_whalf<<<64, 256, 0, stream>>>(W2b, WBH, 16384);
  conv_a_gemm<67,128,0><<<dim3(32,2,8),256,0,stream>>>(FB2,(size_t)278528,nullptr,WBT,b2a,nullptr,TBUF,nullptr,nullptr,nullptr,2048);
  conv_a_mfma<128,128><<<dim3(1024,8),256,0,stream>>>(FB2,68,(size_t)278528,IDX2,WAH,TBUF,H,red_s,red_q,2048);
  bn_finalize<<<1,256,0,stream>>>(red_s,red_q,g2a,be2a,SC1,SH1,128,1.f/524288.f);
  conv_b_fused<128><<<dim3(1024,8),256,0,stream>>>(H,WBH,b2b,SC1,SH1,red_s,red_q,HMAX,2048*32);
  bn_finalize<<<1,256,0,stream>>>(red_s,red_q,g2b,be2b,SC2,SH2,128,1.f/524288.f);
  bnrelu_fb<<<2048,256,0,stream>>>(HMAX,SC2,SH2,FB3,128,132,(size_t)270336,2048);
  append_xyz<<<64, 256, 0, stream>>>(pcd, FB3, 2048, 132, 128);

  // ================ Layer 3: C2=131, CM=256, M=1024, N=2048 ================
  knn_kernel<<<dim3(256, 8), 256, 0, stream>>>(pcd, 2048, 1024, IDX3);
  prep_wa<<<132, 256, 0, stream>>>(W3a, WAT, WBT, 256, 131, 132);
  prep_wah<<<192, 256, 0, stream>>>(W3a, WAH, 256, 131, 192);
  prep_whalf<<<256, 256, 0, stream>>>(W3b, WBH, 65536);
  conv_a_gemm<131,256,0><<<dim3(16,4,8),256,0,stream>>>(FB3,(size_t)270336,nullptr,WBT,b3a,nullptr,TBUF,nullptr,nullptr,nullptr,1024);
  conv_a_mfma<256,192><<<dim3(512,8),256,0,stream>>>(FB3,132,(size_t)270336,IDX3,WAH,TBUF,H,red_s,red_q,1024);
  bn_finalize<<<1,256,0,stream>>>(red_s,red_q,g3a,be3a,SC1,SH1,256,1.f/262144.f);
  conv_b_fused<256><<<dim3(512,8),256,0,stream>>>(H,WBH,b3b,SC1,SH1,red_s,red_q,HMAX,1024*32);
  bn_finalize<<<1,256,0,stream>>>(red_s,red_q,g3b,be3b,SC2,SH2,256,1.f/262144.f);
  bnrelu_fb<<<1024,256,0,stream>>>(HMAX,SC2,SH2,FB4,256,256,(size_t)262144,1024);

  // ================ outputs ================
  fc_out<<<dim3(8, 32), 256, 0, stream>>>(FB4, fcW, fcb, out1, out3);
  out_xyz_idx<<<32, 256, 0, stream>>>(pcd, out0, out2);
}

// Round 7
// 960.358 us; speedup vs baseline: 19.4944x; 1.0792x over previous
//
#include <hip/hip_runtime.h>
#include <hip/hip_bf16.h>

#define B8 8
#define KNN 32
typedef unsigned short u16;
typedef unsigned int u32;

typedef __attribute__((ext_vector_type(8))) _Float16 half8;
typedef __attribute__((ext_vector_type(4))) float f32x4;

static __device__ __forceinline__ u16 f2h_u(float f) {
  _Float16 h = (_Float16)f; u16 u; __builtin_memcpy(&u, &h, 2); return u;
}
static __device__ __forceinline__ float h2f_u(u16 u) {
  _Float16 h; __builtin_memcpy(&h, &u, 2); return (float)h;
}

// 64-lane bitonic sort (ascending) with index payload
static __device__ __forceinline__ void bitonic64(float& d, int& i_, int lane) {
#pragma unroll
  for (int k = 2; k <= 64; k <<= 1) {
#pragma unroll
    for (int j = k >> 1; j > 0; j >>= 1) {
      float od = __shfl_xor(d, j);
      int   oi = __shfl_xor(i_, j);
      bool keepmin = (((lane & j) == 0) == ((lane & k) == 0));
      bool sw = keepmin ? (od < d) : (od > d);
      d  = sw ? od : d;
      i_ = sw ? oi : i_;
    }
  }
}

// ---------------- KNN: one wave/query, buffered top-32 with bitonic flush ----------------
__global__ __launch_bounds__(256) void knn_kernel(const float* __restrict__ pcd,
                                                  int N, int M, int* __restrict__ idxout) {
  __shared__ float4 pts[1024];
  __shared__ float bufd[4][32];
  __shared__ int   bufi[4][32];
  const int t = threadIdx.x;
  const int lane = t & 63, w = t >> 6;
  const int b = blockIdx.y;
  const int m = blockIdx.x * 4 + w;
  const float* base = pcd + (size_t)b * 4096 * 3;
  const float qx = base[m*3], qy = base[m*3+1], qz = base[m*3+2];
  const float ax = -2.f*qx, ay = -2.f*qy, az = -2.f*qz;

  float hd; int hi_; float tau;
  int cnt = 0;

  for (int i = t; i < 1024; i += 256) {
    const float* p = base + (size_t)i * 3;
    float x = p[0], y = p[1], z = p[2];
    pts[i] = make_float4(x, y, z, x*x + y*y + z*z);
  }
  __syncthreads();

  // init: sort first 64 candidates; lanes 0..31 = top-32
  {
    float4 p = pts[lane];
    hd = fmaf(ax, p.x, fmaf(ay, p.y, fmaf(az, p.z, p.w)));
    hi_ = lane;
    bitonic64(hd, hi_, lane);
    tau = __shfl(hd, 31);
  }

  for (int n0 = 0; n0 < N; n0 += 1024) {
    if (n0) {
      __syncthreads();
      for (int i = t; i < 1024; i += 256) {
        const float* p = base + (size_t)(n0 + i) * 3;
        float x = p[0], y = p[1], z = p[2];
        pts[i] = make_float4(x, y, z, x*x + y*y + z*z);
      }
      __syncthreads();
    }
    for (int c = 0; c < 1024; c += 256) {
      float4 p0 = pts[c + lane];
      float4 p1 = pts[c + 64 + lane];
      float4 p2 = pts[c + 128 + lane];
      float4 p3 = pts[c + 192 + lane];
      float r[4];
      r[0] = fmaf(ax, p0.x, fmaf(ay, p0.y, fmaf(az, p0.z, p0.w)));
      r[1] = fmaf(ax, p1.x, fmaf(ay, p1.y, fmaf(az, p1.z, p1.w)));
      r[2] = fmaf(ax, p2.x, fmaf(ay, p2.y, fmaf(az, p2.z, p2.w)));
      r[3] = fmaf(ax, p3.x, fmaf(ay, p3.y, fmaf(az, p3.z, p3.w)));
      if (n0 == 0 && c == 0) r[0] = 3.4e38f;   // first 64 consumed by init
#pragma unroll
      for (int j = 0; j < 4; ++j) {
        float rr = r[j];
        int gid = n0 + c + j * 64 + lane;
        bool pass = rr < tau;
        while (__any(pass)) {
          unsigned long long mk = __ballot(pass);
          int before = __popcll(mk & ((1ull << lane) - 1ull));
          int total  = __popcll(mk);
          int room = 32 - cnt;
          if (pass && before < room) {
            bufd[w][cnt + before] = rr;
            bufi[w][cnt + before] = gid;
            pass = false;
          }
          if (total >= room) {
            // buffer full -> flush: sort {list(0..31), buffer(32..63)}
            float bd_; int bi_;
            if (lane >= 32) { bd_ = bufd[w][lane - 32]; bi_ = bufi[w][lane - 32]; }
            else            { bd_ = hd;                 bi_ = hi_; }
            bitonic64(bd_, bi_, lane);
            hd = bd_; hi_ = bi_;
            tau = __shfl(hd, 31);
            cnt = 0;
            pass = pass && (rr < tau);
          } else {
            cnt += total;
          }
        }
      }
    }
  }
  if (cnt > 0) {
    float bd_; int bi_;
    if (lane >= 32) {
      bool v = (lane - 32) < cnt;
      bd_ = v ? bufd[w][lane - 32] : 3.4e38f;
      bi_ = v ? bufi[w][lane - 32] : 0;
    } else { bd_ = hd; bi_ = hi_; }
    bitonic64(bd_, bi_, lane);
    hd = bd_; hi_ = bi_;
  }
  if (lane < KNN) idxout[((size_t)b * M + m) * KNN + lane] = hi_;
}

// ---------------- weight prep ----------------
__global__ void prep_wa(const float* __restrict__ W, float* __restrict__ WAt, float* __restrict__ WBt,
                        int cm, int c2, int kp) {
  int i = blockIdx.x * 256 + threadIdx.x;
  if (i >= kp * cm) return;
  int c = i / cm, o = i - c * cm;
  float w1 = 0.f, w2 = 0.f;
  if (c < c2) { w1 = W[o * 2 * c2 + c]; w2 = W[o * 2 * c2 + c2 + c]; }
  WAt[c * cm + o] = w1;
  WBt[c * cm + o] = w2 - w1;
}
__global__ void prep_wah(const float* __restrict__ W, u16* __restrict__ WH,
                         int cm, int c2, int kpad) {
  int i = blockIdx.x * 256 + threadIdx.x;
  if (i >= cm * kpad) return;
  int o = i / kpad, k = i - o * kpad;
  WH[i] = (k < c2) ? f2h_u(W[o * 2 * c2 + k]) : (u16)0;
}
__global__ void prep_whalf(const float* __restrict__ W, u16* __restrict__ WH, int n) {
  int i = blockIdx.x * 256 + threadIdx.x;
  if (i < n) WH[i] = f2h_u(W[i]);
}

__global__ void zero_red(float* __restrict__ red) {
  int i = blockIdx.x * 256 + threadIdx.x;
  if (i < 8192) red[i] = 0.f;
}

// ---------------- conv_a VALU GEMM (L1 edge [+stats] + all T-passes) ----------------
template<int C2, int CM, int MODE>
__global__ __launch_bounds__(256) void conv_a_gemm(
    const float* __restrict__ F, size_t fbstride,
    const int* __restrict__ idx,
    const float* __restrict__ Wt,
    const float* __restrict__ bias,
    const float* __restrict__ T,
    float* __restrict__ Tout,
    u16* __restrict__ Hout,
    float* __restrict__ red_s, float* __restrict__ red_q,
    int M)
{
  constexpr int KP = (C2 + 3) & ~3;
  constexpr int KC = (KP <= 68) ? KP : 44;
  __shared__ float At[64][KC];
  __shared__ float Wts[KC][64];
  __shared__ int ji[64];
  __shared__ float sred[4][64];
  __shared__ float qred[4][64];
  const int t = threadIdx.x;
  const int rt = blockIdx.x, ot = blockIdx.y, b = blockIdx.z;
  const int R0 = rt * 64, oc0 = ot * 64;
  const float* Fb = F + (size_t)b * fbstride;

  if (t < 64) {
    int gr = R0 + t;
    ji[t] = (MODE == 0) ? gr : idx[((size_t)b * M + (gr >> 5)) * KNN + (gr & 31)];
  }

  const int cg = t & 15, rg = t >> 4;
  const int r0 = rg * 4, c0 = cg * 4;
  float acc[4][4];
  if (MODE == 0) {
#pragma unroll
    for (int j = 0; j < 4; ++j) {
      float bv = bias[oc0 + c0 + j];
#pragma unroll
      for (int i = 0; i < 4; ++i) acc[i][j] = bv;
    }
  } else {
#pragma unroll
    for (int i = 0; i < 4; ++i) {
      const float* tp = T + ((size_t)b * M + (size_t)((R0 + r0 + i) >> 5)) * CM + oc0 + c0;
      acc[i][0] = tp[0]; acc[i][1] = tp[1]; acc[i][2] = tp[2]; acc[i][3] = tp[3];
    }
  }
  __syncthreads();

  for (int k0 = 0; k0 < KP; k0 += KC) {
    if (k0) __syncthreads();
    for (int i = t; i < KC * 64; i += 256) {
      int c = i >> 6, o = i & 63;
      Wts[c][o] = Wt[(size_t)(k0 + c) * CM + oc0 + o];
    }
    if constexpr (C2 == 3) {
      for (int i = t; i < 64 * 4; i += 256) {
        int r = i >> 2, c = i & 3;
        At[r][c] = (c < 3) ? Fb[(size_t)ji[r] * 3 + c] : 0.f;
      }
    } else {
      constexpr int C4 = KC / 4;
      for (int i = t; i < 64 * C4; i += 256) {
        int r = i / C4, c4 = i - r * C4;
        *(float4*)&At[r][c4 * 4] = *(const float4*)&Fb[(size_t)ji[r] * KP + k0 + c4 * 4];
      }
    }
    __syncthreads();

#pragma unroll 4
    for (int k = 0; k < KC; ++k) {
      const float4 w4 = *(const float4*)&Wts[k][c0];
      float a0 = At[r0][k], a1 = At[r0+1][k], a2 = At[r0+2][k], a3 = At[r0+3][k];
      acc[0][0]=fmaf(a0,w4.x,acc[0][0]); acc[0][1]=fmaf(a0,w4.y,acc[0][1]);
      acc[0][2]=fmaf(a0,w4.z,acc[0][2]); acc[0][3]=fmaf(a0,w4.w,acc[0][3]);
      acc[1][0]=fmaf(a1,w4.x,acc[1][0]); acc[1][1]=fmaf(a1,w4.y,acc[1][1]);
      acc[1][2]=fmaf(a1,w4.z,acc[1][2]); acc[1][3]=fmaf(a1,w4.w,acc[1][3]);
      acc[2][0]=fmaf(a2,w4.x,acc[2][0]); acc[2][1]=fmaf(a2,w4.y,acc[2][1]);
      acc[2][2]=fmaf(a2,w4.z,acc[2][2]); acc[2][3]=fmaf(a2,w4.w,acc[2][3]);
      acc[3][0]=fmaf(a3,w4.x,acc[3][0]); acc[3][1]=fmaf(a3,w4.y,acc[3][1]);
      acc[3][2]=fmaf(a3,w4.z,acc[3][2]); acc[3][3]=fmaf(a3,w4.w,acc[3][3]);
    }
  }

  if (MODE == 0) {
    float* op = Tout + ((size_t)b * M + R0) * (size_t)CM + oc0;
#pragma unroll
    for (int i = 0; i < 4; ++i) {
      float* p = op + (size_t)(r0 + i) * CM + c0;
      p[0]=acc[i][0]; p[1]=acc[i][1]; p[2]=acc[i][2]; p[3]=acc[i][3];
    }
  } else {
    u16* hp = Hout + ((size_t)b * M * KNN + R0) * (size_t)CM + oc0;
#pragma unroll
    for (int i = 0; i < 4; ++i) {
      ushort4 s;
      s.x = f2h_u(acc[i][0]); s.y = f2h_u(acc[i][1]); s.z = f2h_u(acc[i][2]); s.w = f2h_u(acc[i][3]);
      *(ushort4*)(hp + (size_t)(r0 + i) * CM + c0) = s;
    }
    float cs[4], cq_[4];
#pragma unroll
    for (int j = 0; j < 4; ++j) {
      float s = acc[0][j] + acc[1][j] + acc[2][j] + acc[3][j];
      float q = acc[0][j]*acc[0][j] + acc[1][j]*acc[1][j] + acc[2][j]*acc[2][j] + acc[3][j]*acc[3][j];
      s += __shfl_xor(s, 16); q += __shfl_xor(q, 16);
      s += __shfl_xor(s, 32); q += __shfl_xor(q, 32);
      cs[j] = s; cq_[j] = q;
    }
    const int wv = t >> 6;
    if ((t & 48) == 0) {
#pragma unroll
      for (int j = 0; j < 4; ++j) { sred[wv][c0 + j] = cs[j]; qred[wv][c0 + j] = cq_[j]; }
    }
    __syncthreads();
    if (t < 64) {
      float s = sred[0][t] + sred[1][t] + sred[2][t] + sred[3][t];
      float q = qred[0][t] + qred[1][t] + qred[2][t] + qred[3][t];
      int shdw = (rt & 15) * 256;
      atomicAdd(&red_s[shdw + t], s);
      atomicAdd(&red_q[shdw + t], q);
    }
  }
}

// ---------------- conv_a MFMA (layers 2/3 edge pass) + fused bn1 stats ----------------
template<int CM, int KPAD>
__global__ __launch_bounds__(256) void conv_a_mfma(
    const float* __restrict__ F, int fstride, size_t fbstride,
    const int* __restrict__ idx,
    const u16* __restrict__ Wh,
    const float* __restrict__ T,
    u16* __restrict__ Hout,
    float* __restrict__ red_s, float* __restrict__ red_q,
    int M)
{
  constexpr int FC = CM / 32;
  __shared__ u16 Alds[64][72];
  __shared__ u16 Wlds[CM][72];
  __shared__ int ji[64];
  const int t = threadIdx.x;
  const int lane = t & 63, w = t >> 6;
  const int wr = w >> 1, wc = w & 1;
  const int cl = lane & 15, rq = lane >> 4;
  const int rt = blockIdx.x, b = blockIdx.y;
  const int R0 = rt * 64;
  const float* Fb = F + (size_t)b * fbstride;

  if (t < 64) ji[t] = idx[((size_t)b * M + ((R0 + t) >> 5)) * KNN + ((R0 + t) & 31)];

  f32x4 acc[2][FC];
#pragma unroll
  for (int fr = 0; fr < 2; ++fr)
#pragma unroll
    for (int fc = 0; fc < FC; ++fc) {
      int col = wc * (CM/2) + fc * 16 + cl;
#pragma unroll
      for (int r = 0; r < 4; ++r) {
        int row = R0 + wr*32 + fr*16 + rq*4 + r;
        acc[fr][fc][r] = T[((size_t)b * M + (row >> 5)) * CM + col];
      }
    }
  __syncthreads();

  for (int k0 = 0; k0 < KPAD; k0 += 64) {
    if (k0) __syncthreads();
    for (int i = t; i < 64 * 16; i += 256) {
      int r = i >> 4, seg = i & 15;
      int k = k0 + seg * 4;
      ushort4 s = {0,0,0,0};
      if (k < fstride) {
        float4 v = *(const float4*)&Fb[(size_t)ji[r] * fstride + k];
        s.x = f2h_u(v.x); s.y = f2h_u(v.y); s.z = f2h_u(v.z); s.w = f2h_u(v.w);
      }
      *(ushort4*)&Alds[r][seg * 4] = s;
    }
    for (int i = t; i < CM * 8; i += 256) {
      int o = i >> 3, seg = i & 7;
      *(float4*)&Wlds[o][seg * 8] = *(const float4*)&Wh[(size_t)o * KPAD + k0 + seg * 8];
    }
    __syncthreads();

#pragma unroll
    for (int kk = 0; kk < 2; ++kk) {
      half8 af[2], bf[FC];
#pragma unroll
      for (int fr = 0; fr < 2; ++fr)
        af[fr] = *(const half8*)&Alds[wr*32 + fr*16 + cl][kk*32 + rq*8];
#pragma unroll
      for (int fc = 0; fc < FC; ++fc)
        bf[fc] = *(const half8*)&Wlds[wc*(CM/2) + fc*16 + cl][kk*32 + rq*8];
#pragma unroll
      for (int fr = 0; fr < 2; ++fr)
#pragma unroll
        for (int fc = 0; fc < FC; ++fc)
          acc[fr][fc] = __builtin_amdgcn_mfma_f32_16x16x32_f16(af[fr], bf[fc], acc[fr][fc], 0, 0, 0);
    }
  }

  u16* Hb = Hout + ((size_t)b * (size_t)M * KNN + R0) * CM;
#pragma unroll
  for (int fr = 0; fr < 2; ++fr)
#pragma unroll
    for (int fc = 0; fc < FC; ++fc) {
      int col = wc*(CM/2) + fc*16 + cl;
#pragma unroll
      for (int r = 0; r < 4; ++r) {
        int row = wr*32 + fr*16 + rq*4 + r;
        Hb[(size_t)row * CM + col] = f2h_u(acc[fr][fc][r]);
      }
    }

#pragma unroll
  for (int fc = 0; fc < FC; ++fc) {
    float s = 0.f, q = 0.f;
#pragma unroll
    for (int fr = 0; fr < 2; ++fr)
#pragma unroll
      for (int r = 0; r < 4; ++r) {
        float v = acc[fr][fc][r];
        s += v; q += v * v;
      }
    s += __shfl_xor(s, 16); q += __shfl_xor(q, 16);
    s += __shfl_xor(s, 32); q += __shfl_xor(q, 32);
    if (rq == 0) {
      int col = wc*(CM/2) + fc*16 + cl;
      int shdw = (rt & 15) * 256;
      atomicAdd(&red_s[shdw + col], s);
      atomicAdd(&red_q[shdw + col], q);
    }
  }
}

// ---------------- conv_b MFMA fused: reads h1, emits bn2-stats + max_k only ----------------
template<int CM>
__global__ __launch_bounds__(256) void conv_b_fused(
    const u16* __restrict__ H,
    const u16* __restrict__ Wh,
    const float* __restrict__ bb,
    const float* __restrict__ sc1, const float* __restrict__ sh1,
    float* __restrict__ red_s, float* __restrict__ red_q,
    float* __restrict__ hmax,
    int Mrows)
{
  constexpr int FC = CM / 32;
  __shared__ u16 Alds[64][72];
  __shared__ u16 Wlds[CM][72];
  __shared__ float scs[CM], shs[CM];
  const int t = threadIdx.x;
  const int lane = t & 63, w = t >> 6;
  const int wr = w >> 1, wc = w & 1;
  const int cl = lane & 15, rq = lane >> 4;
  const int rt = blockIdx.x, b = blockIdx.y;
  const u16* Hb = H + ((size_t)b * Mrows + (size_t)rt * 64) * CM;

  for (int i = t; i < CM; i += 256) { scs[i] = sc1[i]; shs[i] = sh1[i]; }

  f32x4 acc[2][FC];
#pragma unroll
  for (int fr = 0; fr < 2; ++fr)
#pragma unroll
    for (int fc = 0; fc < FC; ++fc) {
      float bv = bb[wc * (CM/2) + fc * 16 + cl];
#pragma unroll
      for (int r = 0; r < 4; ++r) acc[fr][fc][r] = bv;
    }
  __syncthreads();

  for (int k0 = 0; k0 < CM; k0 += 64) {
    if (k0) __syncthreads();
    for (int i = t; i < 64 * 8; i += 256) {
      int r = i >> 3, seg = i & 7;
      half8 hv = *(const half8*)&Hb[(size_t)r * CM + k0 + seg * 8];
      half8 ov;
#pragma unroll
      for (int j = 0; j < 8; ++j) {
        int c = k0 + seg * 8 + j;
        float v = fmaxf(0.f, fmaf((float)hv[j], scs[c], shs[c]));
        ov[j] = (_Float16)v;
      }
      *(half8*)&Alds[r][seg * 8] = ov;
    }
    for (int i = t; i < CM * 8; i += 256) {
      int o = i >> 3, seg = i & 7;
      *(float4*)&Wlds[o][seg * 8] = *(const float4*)&Wh[(size_t)o * CM + k0 + seg * 8];
    }
    __syncthreads();

#pragma unroll
    for (int kk = 0; kk < 2; ++kk) {
      half8 af[2], bf[FC];
#pragma unroll
      for (int fr = 0; fr < 2; ++fr)
        af[fr] = *(const half8*)&Alds[wr*32 + fr*16 + cl][kk*32 + rq*8];
#pragma unroll
      for (int fc = 0; fc < FC; ++fc)
        bf[fc] = *(const half8*)&Wlds[wc*(CM/2) + fc*16 + cl][kk*32 + rq*8];
#pragma unroll
      for (int fr = 0; fr < 2; ++fr)
#pragma unroll
        for (int fc = 0; fc < FC; ++fc)
          acc[fr][fc] = __builtin_amdgcn_mfma_f32_16x16x32_f16(af[fr], bf[fc], acc[fr][fc], 0, 0, 0);
    }
  }

#pragma unroll
  for (int fc = 0; fc < FC; ++fc) {
    float s = 0.f, q = 0.f, mx = -3.4e38f;
#pragma unroll
    for (int fr = 0; fr < 2; ++fr)
#pragma unroll
      for (int r = 0; r < 4; ++r) {
        float v = acc[fr][fc][r];
        s += v; q += v * v; mx = fmaxf(mx, v);
      }
    s += __shfl_xor(s, 16); q += __shfl_xor(q, 16); mx = fmaxf(mx, __shfl_xor(mx, 16));
    s += __shfl_xor(s, 32); q += __shfl_xor(q, 32); mx = fmaxf(mx, __shfl_xor(mx, 32));
    if (rq == 0) {
      int col = wc*(CM/2) + fc*16 + cl;
      int shdw = (rt & 15) * 256;
      atomicAdd(&red_s[shdw + col], s);
      atomicAdd(&red_q[shdw + col], q);
      hmax[((size_t)b * (Mrows >> 5) + (size_t)(rt * 2 + wr)) * CM + col] = mx;
    }
  }
}

// ---------------- BN finalize ----------------
__global__ void bn_finalize(float* __restrict__ red_s, float* __restrict__ red_q,
                            const float* __restrict__ g, const float* __restrict__ be,
                            float* __restrict__ sc, float* __restrict__ sh,
                            int cm, float invcnt) {
  int o = threadIdx.x;
  if (o < cm) {
    float s = 0.f, q = 0.f;
    for (int i = 0; i < 16; ++i) { s += red_s[i * 256 + o]; q += red_q[i * 256 + o]; }
    float mu  = s * invcnt;
    float var = fmaxf(q * invcnt - mu * mu, 0.f);
    float scv = g[o] * rsqrtf(var + 1e-5f);
    sc[o] = scv;
    sh[o] = fmaf(-mu, scv, be[o]);
  }
  __syncthreads();
  for (int i = threadIdx.x; i < 16 * 256; i += 256) { red_s[i] = 0.f; red_q[i] = 0.f; }
}

// ---------------- bn2 + relu on max values -> feature buffer ----------------
__global__ __launch_bounds__(256) void bnrelu_fb(const float* __restrict__ hm,
    const float* __restrict__ sc2, const float* __restrict__ sh2,
    float* __restrict__ fout, int CM, int fostride, size_t fobstride, int M) {
  int i = blockIdx.x * 256 + threadIdx.x;
  int cq = CM >> 2;
  int total = B8 * M * cq;
  if (i >= total) return;
  int c4 = i % cq; int r = i / cq;
  int b = r / M, m = r - b * M;
  float4 v = *(const float4*)&hm[((size_t)b * M + m) * CM + c4 * 4];
  int c = c4 * 4;
  float4 o;
  o.x = fmaxf(0.f, fmaf(v.x, sc2[c],   sh2[c]));
  o.y = fmaxf(0.f, fmaf(v.y, sc2[c+1], sh2[c+1]));
  o.z = fmaxf(0.f, fmaf(v.z, sc2[c+2], sh2[c+2]));
  o.w = fmaxf(0.f, fmaf(v.w, sc2[c+3], sh2[c+3]));
  *(float4*)&fout[(size_t)b * fobstride + (size_t)m * fostride + c] = o;
}

// ---------------- append xyz (+ zero pad col) ----------------
__global__ void append_xyz(const float* __restrict__ pcd, float* __restrict__ fbuf,
                           int nrows, int stride, int coff) {
  int i = blockIdx.x * 256 + threadIdx.x;
  if (i < B8 * nrows) {
    int b = i / nrows, n = i - b * nrows;
    const float* p = pcd + ((size_t)b * 4096 + n) * 3;
    float* dd = fbuf + ((size_t)b * nrows + n) * stride + coff;
    dd[0] = p[0]; dd[1] = p[1]; dd[2] = p[2]; dd[3] = 0.f;
  }
}

// ---------------- final FC + feat transpose ----------------
__global__ __launch_bounds__(256) void fc_out(const float* __restrict__ f4,
                                              const float* __restrict__ fcW, const float* __restrict__ fcb,
                                              float* __restrict__ out1, float* __restrict__ out3) {
  __shared__ float tile[32 * 257];
  const int t = threadIdx.x, b = blockIdx.x, n0 = blockIdx.y * 32;
  for (int i = t; i < 32 * 256; i += 256) {
    int n = i >> 8, c = i & 255;
    tile[n * 257 + c] = f4[((size_t)b * 1024 + n0 + n) * 256 + c];
  }
  __syncthreads();
  const int n = t & 31, og = t >> 5;
#pragma unroll
  for (int ci = 0; ci < 32; ++ci) {
    int c = og * 32 + ci;
    out3[((size_t)b * 256 + c) * 1024 + n0 + n] = tile[n * 257 + c];
  }
#pragma unroll
  for (int oi = 0; oi < 16; ++oi) {
    int o = og * 16 + oi;
    float acc = fcb[o];
    const float* w = fcW + (size_t)o * 256;
#pragma unroll 4
    for (int c = 0; c < 256; ++c) acc = fmaf(tile[n * 257 + c], w[c], acc);
    out1[((size_t)b * 128 + o) * 1024 + n0 + n] = acc;
  }
}

__global__ void out_xyz_idx(const float* __restrict__ pcd, float* __restrict__ out0,
                            float* __restrict__ out2) {
  int i = blockIdx.x * 256 + threadIdx.x;
  if (i < B8 * 1024) {
    int b = i >> 10, n = i & 1023;
    const float* p = pcd + ((size_t)b * 4096 + n) * 3;
    float* o = out0 + (size_t)i * 3;
    o[0] = p[0]; o[1] = p[1]; o[2] = p[2];
    out2[i] = (float)n;
  }
}

// ---------------- host ----------------
extern "C" void kernel_launch(void* const* d_in, const int* in_sizes, int n_in,
                              void* d_out, int out_size, void* d_ws, size_t ws_size,
                              hipStream_t stream) {
  (void)in_sizes; (void)n_in; (void)out_size; (void)ws_size;
  const float* pcd = (const float*)d_in[0];
  const float* W1a = (const float*)d_in[1];  const float* b1a = (const float*)d_in[2];
  const float* g1a = (const float*)d_in[3];  const float* be1a= (const float*)d_in[4];
  const float* W1b = (const float*)d_in[5];  const float* b1b = (const float*)d_in[6];
  const float* g1b = (const float*)d_in[7];  const float* be1b= (const float*)d_in[8];
  const float* W2a = (const float*)d_in[9];  const float* b2a = (const float*)d_in[10];
  const float* g2a = (const float*)d_in[11]; const float* be2a= (const float*)d_in[12];
  const float* W2b = (const float*)d_in[13]; const float* b2b = (const float*)d_in[14];
  const float* g2b = (const float*)d_in[15]; const float* be2b= (const float*)d_in[16];
  const float* W3a = (const float*)d_in[17]; const float* b3a = (const float*)d_in[18];
  const float* g3a = (const float*)d_in[19]; const float* be3a= (const float*)d_in[20];
  const float* W3b = (const float*)d_in[21]; const float* b3b = (const float*)d_in[22];
  const float* g3b = (const float*)d_in[23]; const float* be3b= (const float*)d_in[24];
  const float* fcW = (const float*)d_in[25]; const float* fcb = (const float*)d_in[26];

  float* wsf = (float*)d_ws;
  float* FB2 = wsf;                         // 8*4096*68
  float* FB3 = FB2 + 2228224;               // 8*2048*132
  float* FB4 = FB3 + 2162688;               // 8*1024*256
  float* WAT = FB4 + 2097152;               // 132*256 fp32 c-major
  float* WBT = WAT + 33792;
  float* TBUF= WBT + 33792;                 // 8*4096*64
  float* RED = TBUF + 2097152;
  float* red_s = RED, *red_q = RED + 4096;
  float* SC1 = RED + 8192;  float* SH1 = SC1 + 256;
  float* SC2 = SH1 + 256;   float* SH2 = SC2 + 256;
  int* IDX1 = (int*)(SH2 + 256);
  int* IDX2 = IDX1 + (size_t)8 * 4096 * 32;
  int* IDX3 = IDX2 + (size_t)8 * 2048 * 32;
  u16* H    = (u16*)(IDX3 + (size_t)8 * 1024 * 32); // 67,108,864 f16
  u16* WAH  = H + (size_t)67108864;
  u16* WBH  = WAH + 49152;
  float* HMAX = (float*)(WBH + 65536);      // 8*4096*64 fp32

  float* out0 = (float*)d_out;
  float* out1 = out0 + 24576;
  float* out2 = out1 + 1048576;
  float* out3 = out2 + 8192;

  zero_red<<<32, 256, 0, stream>>>(RED);

  // ================ Layer 1: C2=3, CM=64, M=4096, N=4096 ================
  knn_kernel<<<dim3(1024, 8), 256, 0, stream>>>(pcd, 4096, 4096, IDX1);
  prep_wa<<<1, 256, 0, stream>>>(W1a, WAT, WBT, 64, 3, 4);
  prep_whalf<<<16, 256, 0, stream>>>(W1b, WBH, 4096);
  conv_a_gemm<3,64,0><<<dim3(64,1,8),256,0,stream>>>(pcd,(size_t)12288,nullptr,WBT,b1a,nullptr,TBUF,nullptr,nullptr,nullptr,4096);
  conv_a_gemm<3,64,1><<<dim3(2048,1,8),256,0,stream>>>(pcd,(size_t)12288,IDX1,WAT,nullptr,TBUF,nullptr,H,red_s,red_q,4096);
  bn_finalize<<<1,256,0,stream>>>(red_s,red_q,g1a,be1a,SC1,SH1,64,1.f/1048576.f);
  conv_b_fused<64><<<dim3(2048,8),256,0,stream>>>(H,WBH,b1b,SC1,SH1,red_s,red_q,HMAX,4096*32);
  bn_finalize<<<1,256,0,stream>>>(red_s,red_q,g1b,be1b,SC2,SH2,64,1.f/1048576.f);
  bnrelu_fb<<<2048,256,0,stream>>>(HMAX,SC2,SH2,FB2,64,68,(size_t)278528,4096);
  append_xyz<<<128, 256, 0, stream>>>(pcd, FB2, 4096, 68, 64);

  // ================ Layer 2: C2=67, CM=128, M=2048, N=4096 ================
  knn_kernel<<<dim3(512, 8), 256, 0, stream>>>(pcd, 4096, 2048, IDX2);
  prep_wa<<<34, 256, 0, stream>>>(W2a, WAT, WBT, 128, 67, 68);
  prep_wah<<<64, 256, 0, stream>>>(W2a, WAH, 128, 67, 128);
  prep_whalf<<<64, 256, 0, stream>>>(W2b, WBH, 16384);
  conv_a_gemm<67,128,0><<<dim3(32,2,8),256,0,stream>>>(FB2,(size_t)278528,nullptr,WBT,b2a,nullptr,TBUF,nullptr,nullptr,nullptr,2048);
  conv_a_mfma<128,128><<<dim3(1024,8),256,0,stream>>>(FB2,68,(size_t)278528,IDX2,WAH,TBUF,H,red_s,red_q,2048);
  bn_finalize<<<1,256,0,stream>>>(red_s,red_q,g2a,be2a,SC1,SH1,128,1.f/524288.f);
  conv_b_fused<128><<<dim3(1024,8),256,0,stream>>>(H,WBH,b2b,SC1,SH1,red_s,red_q,HMAX,2048*32);
  bn_finalize<<<1,256,0,stream>>>(red_s,red_q,g2b,be2b,SC2,SH2,128,1.f/524288.f);
  bnrelu_fb<<<2048,256,0,stream>>>(HMAX,SC2,SH2,FB3,128,132,(size_t)270336,2048);
  append_xyz<<<64, 256, 0, stream>>>(pcd, FB3, 2048, 132, 128);

  // ================ Layer 3: C2=131, CM=256, M=1024, N=2048 ================
  knn_kernel<<<dim3(256, 8), 256, 0, stream>>>(pcd, 2048, 1024, IDX3);
  prep_wa<<<132, 256, 0, stream>>>(W3a, WAT, WBT, 256, 131, 132);
  prep_wah<<<192, 256, 0, stream>>>(W3a, WAH, 256, 131, 192);
  prep_whalf<<<256, 256, 0, stream>>>(W3b, WBH, 65536);
  conv_a_gemm<131,256,0><<<dim3(16,4,8),256,0,stream>>>(FB3,(size_t)270336,nullptr,WBT,b3a,nullptr,TBUF,nullptr,nullptr,nullptr,1024);
  conv_a_mfma<256,192><<<dim3(512,8),256,0,stream>>>(FB3,132,(size_t)270336,IDX3,WAH,TBUF,H,red_s,red_q,1024);
  bn_finalize<<<1,256,0,stream>>>(red_s,red_q,g3a,be3a,SC1,SH1,256,1.f/262144.f);
  conv_b_fused<256><<<dim3(512,8),256,0,stream>>>(H,WBH,b3b,SC1,SH1,red_s,red_q,HMAX,1024*32);
  bn_finalize<<<1,256,0,stream>>>(red_s,red_q,g3b,be3b,SC2,SH2,256,1.f/262144.f);
  bnrelu_fb<<<2048,256,0,stream>>>(HMAX,SC2,SH2,FB4,256,256,(size_t)262144,1024);

  // ================ outputs ================
  fc_out<<<dim3(8, 32), 256, 0, stream>>>(FB4, fcW, fcb, out1, out3);
  out_xyz_idx<<<32, 256, 0, stream>>>(pcd, out0, out2);
}

// Round 8
// 872.691 us; speedup vs baseline: 21.4528x; 1.1005x over previous
//
#include <hip/hip_runtime.h>
#include <hip/hip_bf16.h>

#define B8 8
#define KNN 32
typedef unsigned short u16;
typedef unsigned int u32;
typedef unsigned long long u64;

typedef __attribute__((ext_vector_type(8))) _Float16 half8;
typedef __attribute__((ext_vector_type(4))) float f32x4;

static __device__ __forceinline__ u16 f2h_u(float f) {
  _Float16 h = (_Float16)f; u16 u; __builtin_memcpy(&u, &h, 2); return u;
}

// monotonic (distance, id) -> u64 key
static __device__ __forceinline__ u64 enc_key(float d, int id) {
  u32 u = __float_as_uint(d);
  u = (d >= 0.f) ? (u | 0x80000000u) : ~u;
  return ((u64)u << 32) | (u32)id;
}
static __device__ __forceinline__ float dec_val(u64 k) {
  u32 u = (u32)(k >> 32);
  u = (u & 0x80000000u) ? (u & 0x7fffffffu) : ~u;
  return __uint_as_float(u);
}

// rank-redistribute 64 keys (one per lane) -> sorted across lanes; sets tau = 32nd
static __device__ __forceinline__ u64 rank64(u64 mk, int lane, u64* slk, u64* outk, float& tau) {
  slk[lane] = mk;
  int r = 0;
#pragma unroll 16
  for (int j = 0; j < 64; ++j) r += (slk[j] < mk) ? 1 : 0;
  outk[r] = mk;
  u64 res = outk[lane];
  tau = dec_val(outk[31]);
  return res;
}

// ---------------- KNN: one wave/query, rank-sort flush ----------------
__global__ __launch_bounds__(256) void knn_kernel(const float* __restrict__ pcd,
                                                  int N, int M, int* __restrict__ idxout) {
  __shared__ float4 pts[1024];
  __shared__ u64 bufk[4][32];
  __shared__ u64 slk[4][64];
  __shared__ u64 outk[4][64];
  const int t = threadIdx.x;
  const int lane = t & 63, w = t >> 6;
  const int b = blockIdx.y;
  const int m = blockIdx.x * 4 + w;
  const float* base = pcd + (size_t)b * 4096 * 3;
  const float qx = base[m*3], qy = base[m*3+1], qz = base[m*3+2];
  const float ax = -2.f*qx, ay = -2.f*qy, az = -2.f*qz;

  u64 heldk;      // sorted keys across lanes (lanes 0..31 = current top-32)
  float tau;
  int cnt = 0;

  for (int i = t; i < 1024; i += 256) {
    const float* p = base + (size_t)i * 3;
    float x = p[0], y = p[1], z = p[2];
    pts[i] = make_float4(x, y, z, x*x + y*y + z*z);
  }
  __syncthreads();

  // init: rank-sort first 64 candidates
  {
    float4 p = pts[lane];
    float r0 = fmaf(ax, p.x, fmaf(ay, p.y, fmaf(az, p.z, p.w)));
    heldk = rank64(enc_key(r0, lane), lane, slk[w], outk[w], tau);
  }

  for (int n0 = 0; n0 < N; n0 += 1024) {
    if (n0) {
      __syncthreads();
      for (int i = t; i < 1024; i += 256) {
        const float* p = base + (size_t)(n0 + i) * 3;
        float x = p[0], y = p[1], z = p[2];
        pts[i] = make_float4(x, y, z, x*x + y*y + z*z);
      }
      __syncthreads();
    }
    for (int c = 0; c < 1024; c += 256) {
      float4 p0 = pts[c + lane];
      float4 p1 = pts[c + 64 + lane];
      float4 p2 = pts[c + 128 + lane];
      float4 p3 = pts[c + 192 + lane];
      float r[4];
      r[0] = fmaf(ax, p0.x, fmaf(ay, p0.y, fmaf(az, p0.z, p0.w)));
      r[1] = fmaf(ax, p1.x, fmaf(ay, p1.y, fmaf(az, p1.z, p1.w)));
      r[2] = fmaf(ax, p2.x, fmaf(ay, p2.y, fmaf(az, p2.z, p2.w)));
      r[3] = fmaf(ax, p3.x, fmaf(ay, p3.y, fmaf(az, p3.z, p3.w)));
      if (n0 == 0 && c == 0) r[0] = 3.4e38f;   // first 64 consumed by init
      float rmn = fminf(fminf(r[0], r[1]), fminf(r[2], r[3]));
      if (!__any(rmn < tau)) continue;
#pragma unroll
      for (int j = 0; j < 4; ++j) {
        float rr = r[j];
        if (!__any(rr < tau)) continue;
        int gid = n0 + c + j * 64 + lane;
        bool pass = rr < tau;
        while (__any(pass)) {
          u64 mk_ = __ballot(pass);
          int before = __popcll(mk_ & ((1ull << lane) - 1ull));
          int total  = __popcll(mk_);
          int room = 32 - cnt;
          if (pass && before < room) {
            bufk[w][cnt + before] = enc_key(rr, gid);
            pass = false;
          }
          if (total >= room) {
            u64 mk = (lane < 32) ? heldk : bufk[w][lane - 32];
            heldk = rank64(mk, lane, slk[w], outk[w], tau);
            cnt = 0;
            pass = pass && (rr < tau);
          } else {
            cnt += total;
          }
        }
      }
    }
  }
  if (cnt > 0) {
    int bl = lane - 32;
    u64 mk = (lane < 32) ? heldk
             : ((bl < cnt) ? bufk[w][bl]
                           : ((0xFFFFFFFFull << 32) | (0xFFFFFF00u | (u32)lane)));
    heldk = rank64(mk, lane, slk[w], outk[w], tau);
  }
  if (lane < KNN) idxout[((size_t)b * M + m) * KNN + lane] = (int)(u32)(heldk & 0xFFFFFFFFu);
}

// ---------------- prep_all: all weight transforms + RED zero in one launch ----------------
__global__ void prep_all(
    const float* __restrict__ W1a, const float* __restrict__ W1b,
    const float* __restrict__ W2a, const float* __restrict__ W2b,
    const float* __restrict__ W3a, const float* __restrict__ W3b,
    float* __restrict__ RED,
    float* __restrict__ WAT1, float* __restrict__ WBT1, u16* __restrict__ WBH1,
    float* __restrict__ WBT2, u16* __restrict__ WAH2, u16* __restrict__ WBH2,
    float* __restrict__ WBT3, u16* __restrict__ WAH3, u16* __restrict__ WBH3)
{
  int i0 = blockIdx.x * 256 + threadIdx.x;
  int NT = gridDim.x * 256;
  for (int i = i0; i < 8192; i += NT) RED[i] = 0.f;
  for (int i = i0; i < 256; i += NT) {          // L1 conv_a: [4][64]
    int c = i >> 6, o = i & 63;
    float w1 = (c < 3) ? W1a[o*6 + c] : 0.f;
    float w2 = (c < 3) ? W1a[o*6 + 3 + c] : 0.f;
    WAT1[i] = w1; WBT1[i] = w2 - w1;
  }
  for (int i = i0; i < 4096; i += NT) WBH1[i] = f2h_u(W1b[i]);
  for (int i = i0; i < 68*128; i += NT) {       // L2 T-pass B: [68][128]
    int c = i >> 7, o = i & 127;
    float w1 = 0.f, w2 = 0.f;
    if (c < 67) { w1 = W2a[o*134 + c]; w2 = W2a[o*134 + 67 + c]; }
    WBT2[i] = w2 - w1;
  }
  for (int i = i0; i < 128*128; i += NT) {      // L2 edge A f16: [128][128]
    int o = i >> 7, k = i & 127;
    WAH2[i] = (k < 67) ? f2h_u(W2a[o*134 + k]) : (u16)0;
  }
  for (int i = i0; i < 16384; i += NT) WBH2[i] = f2h_u(W2b[i]);
  for (int i = i0; i < 132*256; i += NT) {      // L3 T-pass B: [132][256]
    int c = i >> 8, o = i & 255;
    float w1 = 0.f, w2 = 0.f;
    if (c < 131) { w1 = W3a[o*262 + c]; w2 = W3a[o*262 + 131 + c]; }
    WBT3[i] = w2 - w1;
  }
  for (int i = i0; i < 256*192; i += NT) {      // L3 edge A f16: [256][192]
    int o = i / 192, k = i - o * 192;
    WAH3[i] = (k < 131) ? f2h_u(W3a[o*262 + k]) : (u16)0;
  }
  for (int i = i0; i < 65536; i += NT) WBH3[i] = f2h_u(W3b[i]);
}

// ---------------- conv_a VALU GEMM: MODE 0 = T-pass; MODE 1 = L1 edge stats-only ----------------
template<int C2, int CM, int MODE>
__global__ __launch_bounds__(256) void conv_a_gemm(
    const float* __restrict__ F, size_t fbstride,
    const int* __restrict__ idx,
    const float* __restrict__ Wt,
    const float* __restrict__ bias,
    const float* __restrict__ T,
    float* __restrict__ Tout,
    float* __restrict__ red_s, float* __restrict__ red_q,
    int M)
{
  constexpr int KP = (C2 + 3) & ~3;
  constexpr int KC = (KP <= 68) ? KP : 44;
  __shared__ float At[64][KC];
  __shared__ float Wts[KC][64];
  __shared__ int ji[64];
  __shared__ float sred[4][64];
  __shared__ float qred[4][64];
  const int t = threadIdx.x;
  const int rt = blockIdx.x, ot = blockIdx.y, b = blockIdx.z;
  const int R0 = rt * 64, oc0 = ot * 64;
  const float* Fb = F + (size_t)b * fbstride;

  if (t < 64) {
    int gr = R0 + t;
    ji[t] = (MODE == 0) ? gr : idx[((size_t)b * M + (gr >> 5)) * KNN + (gr & 31)];
  }

  const int cg = t & 15, rg = t >> 4;
  const int r0 = rg * 4, c0 = cg * 4;
  float acc[4][4];
  if (MODE == 0) {
#pragma unroll
    for (int j = 0; j < 4; ++j) {
      float bv = bias[oc0 + c0 + j];
#pragma unroll
      for (int i = 0; i < 4; ++i) acc[i][j] = bv;
    }
  } else {
#pragma unroll
    for (int i = 0; i < 4; ++i) {
      const float* tp = T + ((size_t)b * M + (size_t)((R0 + r0 + i) >> 5)) * CM + oc0 + c0;
      acc[i][0] = tp[0]; acc[i][1] = tp[1]; acc[i][2] = tp[2]; acc[i][3] = tp[3];
    }
  }
  __syncthreads();

  for (int k0 = 0; k0 < KP; k0 += KC) {
    if (k0) __syncthreads();
    for (int i = t; i < KC * 64; i += 256) {
      int c = i >> 6, o = i & 63;
      Wts[c][o] = Wt[(size_t)(k0 + c) * CM + oc0 + o];
    }
    if constexpr (C2 == 3) {
      for (int i = t; i < 64 * 4; i += 256) {
        int r = i >> 2, c = i & 3;
        At[r][c] = (c < 3) ? Fb[(size_t)ji[r] * 3 + c] : 0.f;
      }
    } else {
      constexpr int C4 = KC / 4;
      for (int i = t; i < 64 * C4; i += 256) {
        int r = i / C4, c4 = i - r * C4;
        *(float4*)&At[r][c4 * 4] = *(const float4*)&Fb[(size_t)ji[r] * KP + k0 + c4 * 4];
      }
    }
    __syncthreads();

#pragma unroll 4
    for (int k = 0; k < KC; ++k) {
      const float4 w4 = *(const float4*)&Wts[k][c0];
      float a0 = At[r0][k], a1 = At[r0+1][k], a2 = At[r0+2][k], a3 = At[r0+3][k];
      acc[0][0]=fmaf(a0,w4.x,acc[0][0]); acc[0][1]=fmaf(a0,w4.y,acc[0][1]);
      acc[0][2]=fmaf(a0,w4.z,acc[0][2]); acc[0][3]=fmaf(a0,w4.w,acc[0][3]);
      acc[1][0]=fmaf(a1,w4.x,acc[1][0]); acc[1][1]=fmaf(a1,w4.y,acc[1][1]);
      acc[1][2]=fmaf(a1,w4.z,acc[1][2]); acc[1][3]=fmaf(a1,w4.w,acc[1][3]);
      acc[2][0]=fmaf(a2,w4.x,acc[2][0]); acc[2][1]=fmaf(a2,w4.y,acc[2][1]);
      acc[2][2]=fmaf(a2,w4.z,acc[2][2]); acc[2][3]=fmaf(a2,w4.w,acc[2][3]);
      acc[3][0]=fmaf(a3,w4.x,acc[3][0]); acc[3][1]=fmaf(a3,w4.y,acc[3][1]);
      acc[3][2]=fmaf(a3,w4.z,acc[3][2]); acc[3][3]=fmaf(a3,w4.w,acc[3][3]);
    }
  }

  if (MODE == 0) {
    float* op = Tout + ((size_t)b * M + R0) * (size_t)CM + oc0;
#pragma unroll
    for (int i = 0; i < 4; ++i) {
      float* p = op + (size_t)(r0 + i) * CM + c0;
      p[0]=acc[i][0]; p[1]=acc[i][1]; p[2]=acc[i][2]; p[3]=acc[i][3];
    }
  } else {
    // stats only — no H write
    float cs[4], cq_[4];
#pragma unroll
    for (int j = 0; j < 4; ++j) {
      float s = acc[0][j] + acc[1][j] + acc[2][j] + acc[3][j];
      float q = acc[0][j]*acc[0][j] + acc[1][j]*acc[1][j] + acc[2][j]*acc[2][j] + acc[3][j]*acc[3][j];
      s += __shfl_xor(s, 16); q += __shfl_xor(q, 16);
      s += __shfl_xor(s, 32); q += __shfl_xor(q, 32);
      cs[j] = s; cq_[j] = q;
    }
    const int wv = t >> 6;
    if ((t & 48) == 0) {
#pragma unroll
      for (int j = 0; j < 4; ++j) { sred[wv][c0 + j] = cs[j]; qred[wv][c0 + j] = cq_[j]; }
    }
    __syncthreads();
    if (t < 64) {
      float s = sred[0][t] + sred[1][t] + sred[2][t] + sred[3][t];
      float q = qred[0][t] + qred[1][t] + qred[2][t] + qred[3][t];
      int shdw = (rt & 15) * 256;
      atomicAdd(&red_s[shdw + t], s);
      atomicAdd(&red_q[shdw + t], q);
    }
  }
}

// ---------------- l1_convb: recompute h1 from xyz, bn1+relu, MFMA vs Wb, stats2+max ----------------
__global__ __launch_bounds__(256) void l1_convb(
    const float* __restrict__ pcd,
    const int* __restrict__ idx,
    const float* __restrict__ WAT,     // [4][64] fp32 c-major
    const float* __restrict__ T,       // [b][4096][64] fp32
    const u16* __restrict__ Wbh,       // [64][64] f16
    const float* __restrict__ bb,
    const float* __restrict__ sc1, const float* __restrict__ sh1,
    float* __restrict__ red_s, float* __restrict__ red_q,
    float* __restrict__ hmax)
{
  __shared__ u16 Alds[64][72];
  __shared__ u16 Wlds[64][72];
  __shared__ float xyzs[64][4];
  __shared__ float was[3][64];
  __shared__ float scs[64], shs[64];
  __shared__ int ji[64];
  const int t = threadIdx.x;
  const int lane = t & 63, w = t >> 6;
  const int wr = w >> 1, wc = w & 1;
  const int cl = lane & 15, rq = lane >> 4;
  const int rt = blockIdx.x, b = blockIdx.y;
  const int R0 = rt * 64;
  const float* pb = pcd + (size_t)b * 12288;

  if (t < 64) ji[t] = idx[((size_t)b * 4096 + ((R0 + t) >> 5)) * KNN + ((R0 + t) & 31)];
  if (t < 192) was[t / 64][t & 63] = WAT[t];
  if (t >= 192) { int c = t - 192; scs[c] = sc1[c]; shs[c] = sh1[c]; }
  if (t >= 192) { /* pad */ }
  for (int i = t; i < 64 * 8; i += 256) {
    int o = i >> 3, seg = i & 7;
    *(float4*)&Wlds[o][seg * 8] = *(const float4*)&Wbh[(size_t)o * 64 + seg * 8];
  }
  __syncthreads();
  if (t < 64) {
    const float* p = pb + (size_t)ji[t] * 3;
    xyzs[t][0] = p[0]; xyzs[t][1] = p[1]; xyzs[t][2] = p[2]; xyzs[t][3] = 0.f;
  }
  if (t < 64) { scs[t] = sc1[t]; shs[t] = sh1[t]; }   // ensure full coverage
  __syncthreads();

  // h1' = relu(bn1(T + xyz·WA)) -> f16 LDS
  for (int i = t; i < 64 * 8; i += 256) {
    int r = i >> 3, seg = i & 7;
    float px = xyzs[r][0], py = xyzs[r][1], pz = xyzs[r][2];
    const float* Tm = T + ((size_t)b * 4096 + (size_t)((R0 + r) >> 5)) * 64;
    half8 ov;
#pragma unroll
    for (int j2 = 0; j2 < 8; ++j2) {
      int c = seg * 8 + j2;
      float h = Tm[c];
      h = fmaf(px, was[0][c], h);
      h = fmaf(py, was[1][c], h);
      h = fmaf(pz, was[2][c], h);
      ov[j2] = (_Float16)fmaxf(0.f, fmaf(h, scs[c], shs[c]));
    }
    *(half8*)&Alds[r][seg * 8] = ov;
  }
  __syncthreads();

  f32x4 acc[2][2];
#pragma unroll
  for (int fr = 0; fr < 2; ++fr)
#pragma unroll
    for (int fc = 0; fc < 2; ++fc) {
      float bv = bb[wc * 32 + fc * 16 + cl];
#pragma unroll
      for (int r = 0; r < 4; ++r) acc[fr][fc][r] = bv;
    }

#pragma unroll
  for (int kk = 0; kk < 2; ++kk) {
    half8 af[2], bf[2];
#pragma unroll
    for (int fr = 0; fr < 2; ++fr)
      af[fr] = *(const half8*)&Alds[wr*32 + fr*16 + cl][kk*32 + rq*8];
#pragma unroll
    for (int fc = 0; fc < 2; ++fc)
      bf[fc] = *(const half8*)&Wlds[wc*32 + fc*16 + cl][kk*32 + rq*8];
#pragma unroll
    for (int fr = 0; fr < 2; ++fr)
#pragma unroll
      for (int fc = 0; fc < 2; ++fc)
        acc[fr][fc] = __builtin_amdgcn_mfma_f32_16x16x32_f16(af[fr], bf[fc], acc[fr][fc], 0, 0, 0);
  }

#pragma unroll
  for (int fc = 0; fc < 2; ++fc) {
    float s = 0.f, q = 0.f, mx = -3.4e38f;
#pragma unroll
    for (int fr = 0; fr < 2; ++fr)
#pragma unroll
      for (int r = 0; r < 4; ++r) {
        float v = acc[fr][fc][r];
        s += v; q += v * v; mx = fmaxf(mx, v);
      }
    s += __shfl_xor(s, 16); q += __shfl_xor(q, 16); mx = fmaxf(mx, __shfl_xor(mx, 16));
    s += __shfl_xor(s, 32); q += __shfl_xor(q, 32); mx = fmaxf(mx, __shfl_xor(mx, 32));
    if (rq == 0) {
      int col = wc * 32 + fc * 16 + cl;
      int shdw = (rt & 15) * 256;
      atomicAdd(&red_s[shdw + col], s);
      atomicAdd(&red_q[shdw + col], q);
      hmax[((size_t)b * 4096 + (size_t)(rt * 2 + wr)) * 64 + col] = mx;
    }
  }
}

// ---------------- conv_a MFMA (layers 2/3 edge pass) + fused bn1 stats ----------------
template<int CM, int KPAD>
__global__ __launch_bounds__(256) void conv_a_mfma(
    const float* __restrict__ F, int fstride, size_t fbstride,
    const int* __restrict__ idx,
    const u16* __restrict__ Wh,
    const float* __restrict__ T,
    u16* __restrict__ Hout,
    float* __restrict__ red_s, float* __restrict__ red_q,
    int M)
{
  constexpr int FC = CM / 32;
  __shared__ u16 Alds[64][72];
  __shared__ u16 Wlds[CM][72];
  __shared__ int ji[64];
  const int t = threadIdx.x;
  const int lane = t & 63, w = t >> 6;
  const int wr = w >> 1, wc = w & 1;
  const int cl = lane & 15, rq = lane >> 4;
  const int rt = blockIdx.x, b = blockIdx.y;
  const int R0 = rt * 64;
  const float* Fb = F + (size_t)b * fbstride;

  if (t < 64) ji[t] = idx[((size_t)b * M + ((R0 + t) >> 5)) * KNN + ((R0 + t) & 31)];

  f32x4 acc[2][FC];
#pragma unroll
  for (int fr = 0; fr < 2; ++fr)
#pragma unroll
    for (int fc = 0; fc < FC; ++fc) {
      int col = wc * (CM/2) + fc * 16 + cl;
#pragma unroll
      for (int r = 0; r < 4; ++r) {
        int row = R0 + wr*32 + fr*16 + rq*4 + r;
        acc[fr][fc][r] = T[((size_t)b * M + (row >> 5)) * CM + col];
      }
    }
  __syncthreads();

  for (int k0 = 0; k0 < KPAD; k0 += 64) {
    if (k0) __syncthreads();
    for (int i = t; i < 64 * 16; i += 256) {
      int r = i >> 4, seg = i & 15;
      int k = k0 + seg * 4;
      ushort4 s = {0,0,0,0};
      if (k < fstride) {
        float4 v = *(const float4*)&Fb[(size_t)ji[r] * fstride + k];
        s.x = f2h_u(v.x); s.y = f2h_u(v.y); s.z = f2h_u(v.z); s.w = f2h_u(v.w);
      }
      *(ushort4*)&Alds[r][seg * 4] = s;
    }
    for (int i = t; i < CM * 8; i += 256) {
      int o = i >> 3, seg = i & 7;
      *(float4*)&Wlds[o][seg * 8] = *(const float4*)&Wh[(size_t)o * KPAD + k0 + seg * 8];
    }
    __syncthreads();

#pragma unroll
    for (int kk = 0; kk < 2; ++kk) {
      half8 af[2], bf[FC];
#pragma unroll
      for (int fr = 0; fr < 2; ++fr)
        af[fr] = *(const half8*)&Alds[wr*32 + fr*16 + cl][kk*32 + rq*8];
#pragma unroll
      for (int fc = 0; fc < FC; ++fc)
        bf[fc] = *(const half8*)&Wlds[wc*(CM/2) + fc*16 + cl][kk*32 + rq*8];
#pragma unroll
      for (int fr = 0; fr < 2; ++fr)
#pragma unroll
        for (int fc = 0; fc < FC; ++fc)
          acc[fr][fc] = __builtin_amdgcn_mfma_f32_16x16x32_f16(af[fr], bf[fc], acc[fr][fc], 0, 0, 0);
    }
  }

  u16* Hb = Hout + ((size_t)b * (size_t)M * KNN + R0) * CM;
#pragma unroll
  for (int fr = 0; fr < 2; ++fr)
#pragma unroll
    for (int fc = 0; fc < FC; ++fc) {
      int col = wc*(CM/2) + fc*16 + cl;
#pragma unroll
      for (int r = 0; r < 4; ++r) {
        int row = wr*32 + fr*16 + rq*4 + r;
        Hb[(size_t)row * CM + col] = f2h_u(acc[fr][fc][r]);
      }
    }

#pragma unroll
  for (int fc = 0; fc < FC; ++fc) {
    float s = 0.f, q = 0.f;
#pragma unroll
    for (int fr = 0; fr < 2; ++fr)
#pragma unroll
      for (int r = 0; r < 4; ++r) {
        float v = acc[fr][fc][r];
        s += v; q += v * v;
      }
    s += __shfl_xor(s, 16); q += __shfl_xor(q, 16);
    s += __shfl_xor(s, 32); q += __shfl_xor(q, 32);
    if (rq == 0) {
      int col = wc*(CM/2) + fc*16 + cl;
      int shdw = (rt & 15) * 256;
      atomicAdd(&red_s[shdw + col], s);
      atomicAdd(&red_q[shdw + col], q);
    }
  }
}

// ---------------- conv_b MFMA fused: reads h1, emits bn2-stats + max_k only ----------------
template<int CM>
__global__ __launch_bounds__(256) void conv_b_fused(
    const u16* __restrict__ H,
    const u16* __restrict__ Wh,
    const float* __restrict__ bb,
    const float* __restrict__ sc1, const float* __restrict__ sh1,
    float* __restrict__ red_s, float* __restrict__ red_q,
    float* __restrict__ hmax,
    int Mrows)
{
  constexpr int FC = CM / 32;
  __shared__ u16 Alds[64][72];
  __shared__ u16 Wlds[CM][72];
  __shared__ float scs[CM], shs[CM];
  const int t = threadIdx.x;
  const int lane = t & 63, w = t >> 6;
  const int wr = w >> 1, wc = w & 1;
  const int cl = lane & 15, rq = lane >> 4;
  const int rt = blockIdx.x, b = blockIdx.y;
  const u16* Hb = H + ((size_t)b * Mrows + (size_t)rt * 64) * CM;

  for (int i = t; i < CM; i += 256) { scs[i] = sc1[i]; shs[i] = sh1[i]; }

  f32x4 acc[2][FC];
#pragma unroll
  for (int fr = 0; fr < 2; ++fr)
#pragma unroll
    for (int fc = 0; fc < FC; ++fc) {
      float bv = bb[wc * (CM/2) + fc * 16 + cl];
#pragma unroll
      for (int r = 0; r < 4; ++r) acc[fr][fc][r] = bv;
    }
  __syncthreads();

  for (int k0 = 0; k0 < CM; k0 += 64) {
    if (k0) __syncthreads();
    for (int i = t; i < 64 * 8; i += 256) {
      int r = i >> 3, seg = i & 7;
      half8 hv = *(const half8*)&Hb[(size_t)r * CM + k0 + seg * 8];
      half8 ov;
#pragma unroll
      for (int j = 0; j < 8; ++j) {
        int c = k0 + seg * 8 + j;
        float v = fmaxf(0.f, fmaf((float)hv[j], scs[c], shs[c]));
        ov[j] = (_Float16)v;
      }
      *(half8*)&Alds[r][seg * 8] = ov;
    }
    for (int i = t; i < CM * 8; i += 256) {
      int o = i >> 3, seg = i & 7;
      *(float4*)&Wlds[o][seg * 8] = *(const float4*)&Wh[(size_t)o * CM + k0 + seg * 8];
    }
    __syncthreads();

#pragma unroll
    for (int kk = 0; kk < 2; ++kk) {
      half8 af[2], bf[FC];
#pragma unroll
      for (int fr = 0; fr < 2; ++fr)
        af[fr] = *(const half8*)&Alds[wr*32 + fr*16 + cl][kk*32 + rq*8];
#pragma unroll
      for (int fc = 0; fc < FC; ++fc)
        bf[fc] = *(const half8*)&Wlds[wc*(CM/2) + fc*16 + cl][kk*32 + rq*8];
#pragma unroll
      for (int fr = 0; fr < 2; ++fr)
#pragma unroll
        for (int fc = 0; fc < FC; ++fc)
          acc[fr][fc] = __builtin_amdgcn_mfma_f32_16x16x32_f16(af[fr], bf[fc], acc[fr][fc], 0, 0, 0);
    }
  }

#pragma unroll
  for (int fc = 0; fc < FC; ++fc) {
    float s = 0.f, q = 0.f, mx = -3.4e38f;
#pragma unroll
    for (int fr = 0; fr < 2; ++fr)
#pragma unroll
      for (int r = 0; r < 4; ++r) {
        float v = acc[fr][fc][r];
        s += v; q += v * v; mx = fmaxf(mx, v);
      }
    s += __shfl_xor(s, 16); q += __shfl_xor(q, 16); mx = fmaxf(mx, __shfl_xor(mx, 16));
    s += __shfl_xor(s, 32); q += __shfl_xor(q, 32); mx = fmaxf(mx, __shfl_xor(mx, 32));
    if (rq == 0) {
      int col = wc*(CM/2) + fc*16 + cl;
      int shdw = (rt & 15) * 256;
      atomicAdd(&red_s[shdw + col], s);
      atomicAdd(&red_q[shdw + col], q);
      hmax[((size_t)b * (Mrows >> 5) + (size_t)(rt * 2 + wr)) * CM + col] = mx;
    }
  }
}

// ---------------- BN finalize ----------------
__global__ void bn_finalize(float* __restrict__ red_s, float* __restrict__ red_q,
                            const float* __restrict__ g, const float* __restrict__ be,
                            float* __restrict__ sc, float* __restrict__ sh,
                            int cm, float invcnt) {
  int o = threadIdx.x;
  if (o < cm) {
    float s = 0.f, q = 0.f;
    for (int i = 0; i < 16; ++i) { s += red_s[i * 256 + o]; q += red_q[i * 256 + o]; }
    float mu  = s * invcnt;
    float var = fmaxf(q * invcnt - mu * mu, 0.f);
    float scv = g[o] * rsqrtf(var + 1e-5f);
    sc[o] = scv;
    sh[o] = fmaf(-mu, scv, be[o]);
  }
  __syncthreads();
  for (int i = threadIdx.x; i < 16 * 256; i += 256) { red_s[i] = 0.f; red_q[i] = 0.f; }
}

// ---------------- bn2 + relu on max values -> feature buffer ----------------
__global__ __launch_bounds__(256) void bnrelu_fb(const float* __restrict__ hm,
    const float* __restrict__ sc2, const float* __restrict__ sh2,
    float* __restrict__ fout, int CM, int fostride, size_t fobstride, int M) {
  int i = blockIdx.x * 256 + threadIdx.x;
  int cq = CM >> 2;
  int total = B8 * M * cq;
  if (i >= total) return;
  int c4 = i % cq; int r = i / cq;
  int b = r / M, m = r - b * M;
  float4 v = *(const float4*)&hm[((size_t)b * M + m) * CM + c4 * 4];
  int c = c4 * 4;
  float4 o;
  o.x = fmaxf(0.f, fmaf(v.x, sc2[c],   sh2[c]));
  o.y = fmaxf(0.f, fmaf(v.y, sc2[c+1], sh2[c+1]));
  o.z = fmaxf(0.f, fmaf(v.z, sc2[c+2], sh2[c+2]));
  o.w = fmaxf(0.f, fmaf(v.w, sc2[c+3], sh2[c+3]));
  *(float4*)&fout[(size_t)b * fobstride + (size_t)m * fostride + c] = o;
}

// ---------------- append xyz (+ zero pad col) ----------------
__global__ void append_xyz(const float* __restrict__ pcd, float* __restrict__ fbuf,
                           int nrows, int stride, int coff) {
  int i = blockIdx.x * 256 + threadIdx.x;
  if (i < B8 * nrows) {
    int b = i / nrows, n = i - b * nrows;
    const float* p = pcd + ((size_t)b * 4096 + n) * 3;
    float* dd = fbuf + ((size_t)b * nrows + n) * stride + coff;
    dd[0] = p[0]; dd[1] = p[1]; dd[2] = p[2]; dd[3] = 0.f;
  }
}

// ---------------- final FC + feat transpose ----------------
__global__ __launch_bounds__(256) void fc_out(const float* __restrict__ f4,
                                              const float* __restrict__ fcW, const float* __restrict__ fcb,
                                              float* __restrict__ out1, float* __restrict__ out3) {
  __shared__ float tile[32 * 257];
  const int t = threadIdx.x, b = blockIdx.x, n0 = blockIdx.y * 32;
  for (int i = t; i < 32 * 256; i += 256) {
    int n = i >> 8, c = i & 255;
    tile[n * 257 + c] = f4[((size_t)b * 1024 + n0 + n) * 256 + c];
  }
  __syncthreads();
  const int n = t & 31, og = t >> 5;
#pragma unroll
  for (int ci = 0; ci < 32; ++ci) {
    int c = og * 32 + ci;
    out3[((size_t)b * 256 + c) * 1024 + n0 + n] = tile[n * 257 + c];
  }
#pragma unroll
  for (int oi = 0; oi < 16; ++oi) {
    int o = og * 16 + oi;
    float acc = fcb[o];
    const float* w = fcW + (size_t)o * 256;
#pragma unroll 4
    for (int c = 0; c < 256; ++c) acc = fmaf(tile[n * 257 + c], w[c], acc);
    out1[((size_t)b * 128 + o) * 1024 + n0 + n] = acc;
  }
}

__global__ void out_xyz_idx(const float* __restrict__ pcd, float* __restrict__ out0,
                            float* __restrict__ out2) {
  int i = blockIdx.x * 256 + threadIdx.x;
  if (i < B8 * 1024) {
    int b = i >> 10, n = i & 1023;
    const float* p = pcd + ((size_t)b * 4096 + n) * 3;
    float* o = out0 + (size_t)i * 3;
    o[0] = p[0]; o[1] = p[1]; o[2] = p[2];
    out2[i] = (float)n;
  }
}

// ---------------- host ----------------
extern "C" void kernel_launch(void* const* d_in, const int* in_sizes, int n_in,
                              void* d_out, int out_size, void* d_ws, size_t ws_size,
                              hipStream_t stream) {
  (void)in_sizes; (void)n_in; (void)out_size; (void)ws_size;
  const float* pcd = (const float*)d_in[0];
  const float* W1a = (const float*)d_in[1];  const float* b1a = (const float*)d_in[2];
  const float* g1a = (const float*)d_in[3];  const float* be1a= (const float*)d_in[4];
  const float* W1b = (const float*)d_in[5];  const float* b1b = (const float*)d_in[6];
  const float* g1b = (const float*)d_in[7];  const float* be1b= (const float*)d_in[8];
  const float* W2a = (const float*)d_in[9];  const float* b2a = (const float*)d_in[10];
  const float* g2a = (const float*)d_in[11]; const float* be2a= (const float*)d_in[12];
  const float* W2b = (const float*)d_in[13]; const float* b2b = (const float*)d_in[14];
  const float* g2b = (const float*)d_in[15]; const float* be2b= (const float*)d_in[16];
  const float* W3a = (const float*)d_in[17]; const float* b3a = (const float*)d_in[18];
  const float* g3a = (const float*)d_in[19]; const float* be3a= (const float*)d_in[20];
  const float* W3b = (const float*)d_in[21]; const float* b3b = (const float*)d_in[22];
  const float* g3b = (const float*)d_in[23]; const float* be3b= (const float*)d_in[24];
  const float* fcW = (const float*)d_in[25]; const float* fcb = (const float*)d_in[26];

  float* wsf = (float*)d_ws;
  float* FB2 = wsf;                         // 8*4096*68
  float* FB3 = FB2 + 2228224;               // 8*2048*132
  float* FB4 = FB3 + 2162688;               // 8*1024*256
  float* TBUF= FB4 + 2097152;               // 8*4096*64
  float* RED = TBUF + 2097152;              // 8192
  float* red_s = RED, *red_q = RED + 4096;
  float* SC1 = RED + 8192;  float* SH1 = SC1 + 256;
  float* SC2 = SH1 + 256;   float* SH2 = SC2 + 256;
  float* WAT1 = SH2 + 256;                  // 256
  float* WBT1 = WAT1 + 256;                 // 256
  float* WBT2 = WBT1 + 256;                 // 8704
  float* WBT3 = WBT2 + 8704;                // 33792
  float* HMAX = WBT3 + 33792;               // 8*4096*64 = 2,097,152
  int* IDX1 = (int*)(HMAX + 2097152);       // 8*4096*32
  int* IDX2 = IDX1 + (size_t)8 * 4096 * 32;
  int* IDX3 = IDX2 + (size_t)8 * 2048 * 32;
  u16* H    = (u16*)(IDX3 + (size_t)8 * 1024 * 32); // 67,108,864 f16 (L2/L3)
  u16* WBH1 = H + (size_t)67108864;         // 4096
  u16* WAH2 = WBH1 + 4096;                  // 16384
  u16* WBH2 = WAH2 + 16384;                 // 16384
  u16* WAH3 = WBH2 + 16384;                 // 49152
  u16* WBH3 = WAH3 + 49152;                 // 65536

  float* out0 = (float*)d_out;
  float* out1 = out0 + 24576;
  float* out2 = out1 + 1048576;
  float* out3 = out2 + 8192;

  prep_all<<<64, 256, 0, stream>>>(W1a, W1b, W2a, W2b, W3a, W3b, RED,
                                   WAT1, WBT1, WBH1, WBT2, WAH2, WBH2, WBT3, WAH3, WBH3);

  // ================ Layer 1: C2=3, CM=64, M=4096, N=4096 ================
  knn_kernel<<<dim3(1024, 8), 256, 0, stream>>>(pcd, 4096, 4096, IDX1);
  conv_a_gemm<3,64,0><<<dim3(64,1,8),256,0,stream>>>(pcd,(size_t)12288,nullptr,WBT1,b1a,nullptr,TBUF,nullptr,nullptr,4096);
  conv_a_gemm<3,64,1><<<dim3(2048,1,8),256,0,stream>>>(pcd,(size_t)12288,IDX1,WAT1,nullptr,TBUF,nullptr,red_s,red_q,4096);
  bn_finalize<<<1,256,0,stream>>>(red_s,red_q,g1a,be1a,SC1,SH1,64,1.f/1048576.f);
  l1_convb<<<dim3(2048,8),256,0,stream>>>(pcd,IDX1,WAT1,TBUF,WBH1,b1b,SC1,SH1,red_s,red_q,HMAX);
  bn_finalize<<<1,256,0,stream>>>(red_s,red_q,g1b,be1b,SC2,SH2,64,1.f/1048576.f);
  bnrelu_fb<<<2048,256,0,stream>>>(HMAX,SC2,SH2,FB2,64,68,(size_t)278528,4096);
  append_xyz<<<128, 256, 0, stream>>>(pcd, FB2, 4096, 68, 64);

  // ================ Layer 2: C2=67, CM=128, M=2048, N=4096 ================
  knn_kernel<<<dim3(512, 8), 256, 0, stream>>>(pcd, 4096, 2048, IDX2);
  conv_a_gemm<67,128,0><<<dim3(32,2,8),256,0,stream>>>(FB2,(size_t)278528,nullptr,WBT2,b2a,nullptr,TBUF,nullptr,nullptr,2048);
  conv_a_mfma<128,128><<<dim3(1024,8),256,0,stream>>>(FB2,68,(size_t)278528,IDX2,WAH2,TBUF,H,red_s,red_q,2048);
  bn_finalize<<<1,256,0,stream>>>(red_s,red_q,g2a,be2a,SC1,SH1,128,1.f/524288.f);
  conv_b_fused<128><<<dim3(1024,8),256,0,stream>>>(H,WBH2,b2b,SC1,SH1,red_s,red_q,HMAX,2048*32);
  bn_finalize<<<1,256,0,stream>>>(red_s,red_q,g2b,be2b,SC2,SH2,128,1.f/524288.f);
  bnrelu_fb<<<2048,256,0,stream>>>(HMAX,SC2,SH2,FB3,128,132,(size_t)270336,2048);
  append_xyz<<<64, 256, 0, stream>>>(pcd, FB3, 2048, 132, 128);

  // ================ Layer 3: C2=131, CM=256, M=1024, N=2048 ================
  knn_kernel<<<dim3(256, 8), 256, 0, stream>>>(pcd, 2048, 1024, IDX3);
  conv_a_gemm<131,256,0><<<dim3(16,4,8),256,0,stream>>>(FB3,(size_t)270336,nullptr,WBT3,b3a,nullptr,TBUF,nullptr,nullptr,1024);
  conv_a_mfma<256,192><<<dim3(512,8),256,0,stream>>>(FB3,132,(size_t)270336,IDX3,WAH3,TBUF,H,red_s,red_q,1024);
  bn_finalize<<<1,256,0,stream>>>(red_s,red_q,g3a,be3a,SC1,SH1,256,1.f/262144.f);
  conv_b_fused<256><<<dim3(512,8),256,0,stream>>>(H,WBH3,b3b,SC1,SH1,red_s,red_q,HMAX,1024*32);
  bn_finalize<<<1,256,0,stream>>>(red_s,red_q,g3b,be3b,SC2,SH2,256,1.f/262144.f);
  bnrelu_fb<<<2048,256,0,stream>>>(HMAX,SC2,SH2,FB4,256,256,(size_t)262144,1024);

  // ================ outputs ================
  fc_out<<<dim3(8, 32), 256, 0, stream>>>(FB4, fcW, fcb, out1, out3);
  out_xyz_idx<<<32, 256, 0, stream>>>(pcd, out0, out2);
}